// Round 1
// baseline (1270.510 us; speedup 1.0000x reference)
//
#include <hip/hip_runtime.h>

#define B_    4
#define S_    128
#define BERT_ 768
#define C_    49
#define C1_   50
#define M_    288
#define HP_   25
#define WP_   144
#define NOUT_ 300

// ------------------------------------------------------------------
// helper: 16-step inner product on 64x64 tile, 4x4 micro-tile/thread
// ------------------------------------------------------------------
__device__ __forceinline__ void mm16(const float (*As)[68], const float (*Bs)[68],
                                     int tx, int ty, float acc[4][4]) {
#pragma unroll
  for (int kk = 0; kk < 16; ++kk) {
    float4 av = *reinterpret_cast<const float4*>(&As[kk][ty * 4]);
    float4 bv = *reinterpret_cast<const float4*>(&Bs[kk][tx * 4]);
    float a[4] = {av.x, av.y, av.z, av.w};
    float b[4] = {bv.x, bv.y, bv.z, bv.w};
#pragma unroll
    for (int u = 0; u < 4; ++u)
#pragma unroll
      for (int v = 0; v < 4; ++v)
        acc[u][v] = fmaf(a[u], b[v], acc[u][v]);
  }
}

// ------------------------------------------------------------------
// generic strided f32 GEMM: Out[b,i,j] = sum_k A[b,i,k]*Bm[b,k,j] (+bias[j])
// ------------------------------------------------------------------
__global__ __launch_bounds__(256) void gemm_generic(
    const float* __restrict__ A, const float* __restrict__ Bm,
    const float* __restrict__ bias, float* __restrict__ Out,
    int Mr, int Nc, int K,
    long aB, long aI, long aK,
    long bB, long bK, long bJ,
    long oB, long oI, long oJ)
{
  const int bz = blockIdx.z;
  const int i0 = blockIdx.y * 64, j0 = blockIdx.x * 64;
  __shared__ float As[16][68];
  __shared__ float Bs[16][68];
  const int tid = threadIdx.x;
  const int tx = tid & 15, ty = tid >> 4;
  float acc[4][4] = {};
  const float* Ab = A + (long)bz * aB;
  const float* Bb = Bm + (long)bz * bB;
  for (int k0 = 0; k0 < K; k0 += 16) {
    for (int e = tid; e < 64 * 16; e += 256) {
      int i = e >> 4, k = e & 15;
      int gi = i0 + i, gk = k0 + k;
      As[k][i] = (gi < Mr && gk < K) ? Ab[(long)gi * aI + (long)gk * aK] : 0.f;
    }
    for (int e = tid; e < 16 * 64; e += 256) {
      int k = e >> 6, j = e & 63;
      int gj = j0 + j, gk = k0 + k;
      Bs[k][j] = (gj < Nc && gk < K) ? Bb[(long)gk * bK + (long)gj * bJ] : 0.f;
    }
    __syncthreads();
    mm16(As, Bs, tx, ty, acc);
    __syncthreads();
  }
#pragma unroll
  for (int u = 0; u < 4; ++u) {
    int gi = i0 + ty * 4 + u;
    if (gi >= Mr) continue;
#pragma unroll
    for (int v = 0; v < 4; ++v) {
      int gj = j0 + tx * 4 + v;
      if (gj >= Nc) continue;
      float r = acc[u][v];
      if (bias) r += bias[gj];
      Out[(long)bz * oB + (long)gi * oI + (long)gj * oJ] = r;
    }
  }
}

// ------------------------------------------------------------------
// w1s[m]=sum_c weight1[m,c], w2s likewise
// ------------------------------------------------------------------
__global__ void wsum_kernel(const float* __restrict__ w1, const float* __restrict__ w2,
                            float* __restrict__ w1s, float* __restrict__ w2s)
{
  int m = blockIdx.x * 64 + threadIdx.x;
  if (m >= M_) return;
  float a = 0.f, b = 0.f;
  for (int c = 0; c < C1_; ++c) { a += w1[m * C1_ + c]; b += w2[m * C1_ + c]; }
  w1s[m] = a; w2s[m] = b;
}

// ------------------------------------------------------------------
// ebbar[b,m] = mean_s eb[b,s,m]
// ------------------------------------------------------------------
__global__ void ebbar_kernel(const float* __restrict__ eb, float* __restrict__ ebb)
{
  int b = blockIdx.x;
  for (int m = threadIdx.x; m < M_; m += blockDim.x) {
    float s = 0.f;
    for (int t = 0; t < S_; ++t) s += eb[((long)(b * S_ + t)) * M_ + m];
    ebb[b * M_ + m] = s * (1.f / (float)S_);
  }
}

// ------------------------------------------------------------------
// fused per-(b,s): E = sentinel + sum_j mem;  score_j = ebbar . ext_mem_j;
// mask, two softmaxes, 0.7/0.3 mix, top-5 threshold, final att softmax.
// ------------------------------------------------------------------
__global__ __launch_bounds__(256) void score_kernel(
    const float* __restrict__ mem, const float* __restrict__ sentinel,
    const float* __restrict__ ebbar, const float* __restrict__ cw,
    const int* __restrict__ ml, float* __restrict__ E, float* __restrict__ att)
{
  const int s = blockIdx.x, b = blockIdx.y;
  const int tid = threadIdx.x, wave = tid >> 6, lane = tid & 63;
  __shared__ float sEb[M_];
  __shared__ float sE[4][M_];
  __shared__ float sScore[C1_];
  for (int m = tid; m < M_; m += 256) sEb[m] = ebbar[b * M_ + m];
  __syncthreads();

  const float* base = mem + ((long)(b * S_ + s)) * C_ * M_;
  float Ereg[5] = {0.f, 0.f, 0.f, 0.f, 0.f};
  for (int jj = wave; jj < C_; jj += 4) {
    const float* row = base + (long)jj * M_;
    float d = 0.f;
#pragma unroll
    for (int q = 0; q < 5; ++q) {
      int m = lane + q * 64;
      if (m < M_) { float v = row[m]; Ereg[q] += v; d = fmaf(v, sEb[m], d); }
    }
#pragma unroll
    for (int off = 32; off; off >>= 1) d += __shfl_down(d, off, 64);
    if (lane == 0) sScore[jj + 1] = d;
  }
#pragma unroll
  for (int q = 0; q < 5; ++q) { int m = lane + q * 64; if (m < M_) sE[wave][m] = Ereg[q]; }
  __syncthreads();

  if (wave == 0) {
    float d0 = 0.f;
    for (int m = lane; m < M_; m += 64) d0 = fmaf(sentinel[m], sEb[m], d0);
#pragma unroll
    for (int off = 32; off; off >>= 1) d0 += __shfl_down(d0, off, 64);
    if (lane == 0) sScore[0] = d0;
  }
  for (int m = tid; m < M_; m += 256)
    E[((long)(b * S_ + s)) * M_ + m] = sentinel[m] + sE[0][m] + sE[1][m] + sE[2][m] + sE[3][m];
  __syncthreads();

  if (wave == 0) {
    const int mlv = ml[b * S_ + s];
    float sc = (lane < C1_) ? sScore[lane] : 0.f;
    if (lane < C1_ && mlv < lane) sc -= 1e6f;
    // softmax over masked score
    float mx = (lane < C1_) ? sc : -3.0e38f;
#pragma unroll
    for (int off = 32; off; off >>= 1) mx = fmaxf(mx, __shfl_xor(mx, off, 64));
    float e1 = (lane < C1_) ? __expf(sc - mx) : 0.f;
    float s1 = e1;
#pragma unroll
    for (int off = 32; off; off >>= 1) s1 += __shfl_xor(s1, off, 64);
    float p1 = e1 / s1;
    // softmax over [0, cn_concept_weights]
    float cv = 0.f;
    if (lane >= 1 && lane < C1_) cv = cw[((long)(b * S_ + s)) * C_ + lane - 1];
    float mx2 = (lane < C1_) ? cv : -3.0e38f;
#pragma unroll
    for (int off = 32; off; off >>= 1) mx2 = fmaxf(mx2, __shfl_xor(mx2, off, 64));
    float e2 = (lane < C1_) ? __expf(cv - mx2) : 0.f;
    float s2 = e2;
#pragma unroll
    for (int off = 32; off; off >>= 1) s2 += __shfl_xor(s2, off, 64);
    float p2 = e2 / s2;
    float scm = 0.7f * p1 + 0.3f * p2;
    // top-5 threshold via 5 argmax extractions
    bool active = (lane < C1_);
    float thr = 0.f;
    for (int r = 0; r < 5; ++r) {
      float v = active ? scm : -3.0e38f;
      int idx = lane;
#pragma unroll
      for (int off = 32; off; off >>= 1) {
        float ov = __shfl_xor(v, off, 64);
        int oi = __shfl_xor(idx, off, 64);
        if (ov > v || (ov == v && oi < idx)) { v = ov; idx = oi; }
      }
      thr = v;
      if (lane == idx) active = false;
    }
    float kept = (lane < C1_ && scm >= thr) ? scm : 0.f;
    float mx3 = (lane < C1_) ? kept : -3.0e38f;
#pragma unroll
    for (int off = 32; off; off >>= 1) mx3 = fmaxf(mx3, __shfl_xor(mx3, off, 64));
    float e3 = (lane < C1_) ? __expf(kept - mx3) : 0.f;
    float s3 = e3;
#pragma unroll
    for (int off = 32; off; off >>= 1) s3 += __shfl_xor(s3, off, 64);
    if (lane < C1_) att[((long)(b * S_ + s)) * C1_ + lane] = e3 / s3;
  }
}

// ------------------------------------------------------------------
// G[b,s,n] = sum_m E[m]*exp(tanh(w1s[m]*E[n]+w2s[m]*t2[n])) / sum_m exp(...)
// ------------------------------------------------------------------
__global__ __launch_bounds__(256) void g_kernel(
    const float* __restrict__ E, const float* __restrict__ t2,
    const float* __restrict__ w1s, const float* __restrict__ w2s,
    float* __restrict__ G)
{
  const int s = blockIdx.x, b = blockIdx.y;
  __shared__ float sE[M_], s1[M_], s2[M_];
  const int tid = threadIdx.x;
  const long base = (long)(b * S_ + s) * M_;
  for (int m = tid; m < M_; m += 256) { sE[m] = E[base + m]; s1[m] = w1s[m]; s2[m] = w2s[m]; }
  __syncthreads();
  for (int n = tid; n < M_; n += 256) {
    float a = sE[n];          // t1 == E
    float c = t2[base + n];
    float num = 0.f, den = 0.f;
#pragma unroll 4
    for (int m = 0; m < M_; ++m) {
      float z = fmaf(s1[m], a, s2[m] * c);
      float u = __expf(2.f * z);
      float th = 1.f - 2.f / (u + 1.f);    // tanh(z), saturates correctly at +-1
      float e = __expf(th);
      num = fmaf(sE[m], e, num);
      den += e;
    }
    G[base + n] = num / den;
  }
}

// ------------------------------------------------------------------
// conv1 stage A: AW[o,h,i,dw] = sum_dh w1[o,i,dh,dw]*att[b,i,h+dh-2]
// ------------------------------------------------------------------
__global__ void conv1_aw(const float* __restrict__ att, const float* __restrict__ w1,
                         float* __restrict__ AW, int b)
{
  int idx = blockIdx.x * 256 + threadIdx.x;
  if (idx >= 128 * C1_ * 128 * 5) return;
  int dw = idx % 5; int t = idx / 5;
  int i = t % 128; t /= 128;
  int h = t % C1_; int o = t / C1_;
  const float* wrow = w1 + ((long)(o * 128 + i) * 5) * 5 + dw;  // stride 5 over dh
  const float* arow = att + (long)(b * 128 + i) * C1_;
  float s = 0.f;
#pragma unroll
  for (int dh = 0; dh < 5; ++dh) {
    int hh = h + dh - 2;
    if (hh >= 0 && hh < C1_) s = fmaf(wrow[dh * 5], arow[hh], s);
  }
  AW[idx] = s;
}

// ------------------------------------------------------------------
// conv1 stage B (per b,h GEMM): y1[o,w] = relu(b1[o] + sum_{i,dw} AW[o,h,i,dw]*G[b,i,w+dw-2])
// grid: (5 w-tiles, 2 o-tiles, 50 h)
// ------------------------------------------------------------------
__global__ __launch_bounds__(256) void conv1_gemm(
    const float* __restrict__ AW, const float* __restrict__ G,
    const float* __restrict__ b1, float* __restrict__ y1, int b)
{
  const int h = blockIdx.z;
  const int o0 = blockIdx.y * 64, w0 = blockIdx.x * 64;
  __shared__ float As[16][68];
  __shared__ float Bs[16][68];
  const int tid = threadIdx.x, tx = tid & 15, ty = tid >> 4;
  float acc[4][4] = {};
  const float* Gb = G + (long)b * 128 * M_;
  for (int k0 = 0; k0 < 640; k0 += 16) {
    for (int e = tid; e < 1024; e += 256) {
      int r = e >> 4, k = e & 15;
      As[k][r] = AW[(long)((o0 + r) * C1_ + h) * 640 + k0 + k];
    }
    for (int e = tid; e < 1024; e += 256) {
      int k = e >> 6, c = e & 63;
      int kk = k0 + k; int i = kk / 5, dw = kk % 5;
      int w = w0 + c + dw - 2;
      Bs[k][c] = (w >= 0 && w < M_) ? Gb[(long)i * M_ + w] : 0.f;
    }
    __syncthreads();
    mm16(As, Bs, tx, ty, acc);
    __syncthreads();
  }
#pragma unroll
  for (int u = 0; u < 4; ++u) {
    int o = o0 + ty * 4 + u;
#pragma unroll
    for (int v = 0; v < 4; ++v) {
      int w = w0 + tx * 4 + v;
      if (w < M_)
        y1[((long)(b * 128 + o) * C1_ + h) * M_ + w] = fmaxf(acc[u][v] + b1[o], 0.f);
    }
  }
}

// ------------------------------------------------------------------
// 2x2 maxpool: y1[b,i,50,288] -> x2[b,i,25,144]
// ------------------------------------------------------------------
__global__ void pool_kernel(const float* __restrict__ y1, float* __restrict__ x2)
{
  int idx = blockIdx.x * 256 + threadIdx.x;
  if (idx >= B_ * S_ * HP_ * WP_) return;
  int wp = idx % WP_; int t = idx / WP_;
  int hp = t % HP_; t /= HP_;              // t = b*128+i
  const float* p = y1 + ((long)t * C1_ + 2 * hp) * M_ + 2 * wp;
  x2[idx] = fmaxf(fmaxf(p[0], p[1]), fmaxf(p[M_], p[M_ + 1]));
}

// ------------------------------------------------------------------
// conv2 as im2col GEMM: K=3200 (i,dh,dw), N=3600 (hp,wp), M=128 per b
// grid: (57 n-tiles, 2 o-tiles, 4 b)
// ------------------------------------------------------------------
__global__ __launch_bounds__(256) void conv2_gemm(
    const float* __restrict__ x2, const float* __restrict__ w2,
    const float* __restrict__ b2, float* __restrict__ y2)
{
  const int b = blockIdx.z;
  const int o0 = blockIdx.y * 64, n0 = blockIdx.x * 64;
  __shared__ float As[16][68];
  __shared__ float Bs[16][68];
  const int tid = threadIdx.x, tx = tid & 15, ty = tid >> 4;
  float acc[4][4] = {};
  const float* x2b = x2 + (long)b * 128 * HP_ * WP_;
  for (int k0 = 0; k0 < 3200; k0 += 16) {
    for (int e = tid; e < 1024; e += 256) {
      int r = e >> 4, k = e & 15;
      As[k][r] = w2[(long)(o0 + r) * 3200 + k0 + k];
    }
    for (int e = tid; e < 1024; e += 256) {
      int k = e >> 6, c = e & 63;
      int kk = k0 + k;
      int i = kk / 25, t = kk % 25, dh = t / 5, dw = t % 5;
      int n = n0 + c;
      float v = 0.f;
      if (n < HP_ * WP_) {
        int hp = n / WP_ + dh - 2, wp = n % WP_ + dw - 2;
        if (hp >= 0 && hp < HP_ && wp >= 0 && wp < WP_)
          v = x2b[((long)i * HP_ + hp) * WP_ + wp];
      }
      Bs[k][c] = v;
    }
    __syncthreads();
    mm16(As, Bs, tx, ty, acc);
    __syncthreads();
  }
#pragma unroll
  for (int u = 0; u < 4; ++u) {
    int o = o0 + ty * 4 + u;
#pragma unroll
    for (int v = 0; v < 4; ++v) {
      int n = n0 + tx * 4 + v;
      if (n < HP_ * WP_)
        y2[((long)(b * 128 + o)) * (HP_ * WP_) + n] = fmaxf(acc[u][v] + b2[o], 0.f);
    }
  }
}

// ------------------------------------------------------------------
// LayerNorm over last dim (144), in place. 1 wave per row.
// ------------------------------------------------------------------
__global__ __launch_bounds__(64) void ln_kernel(float* __restrict__ y2,
                                                const float* __restrict__ g,
                                                const float* __restrict__ bb)
{
  float* p = y2 + (long)blockIdx.x * WP_;
  const int lane = threadIdx.x;
  float v[3]; float s = 0.f, ss = 0.f;
#pragma unroll
  for (int q = 0; q < 3; ++q) {
    int wp = lane + q * 64;
    float x = (wp < WP_) ? p[wp] : 0.f;
    v[q] = x; s += x; ss = fmaf(x, x, ss);
  }
#pragma unroll
  for (int off = 32; off; off >>= 1) { s += __shfl_xor(s, off, 64); ss += __shfl_xor(ss, off, 64); }
  float mu = s * (1.f / (float)WP_);
  float var = ss * (1.f / (float)WP_) - mu * mu;
  float inv = rsqrtf(var + 1e-5f);
#pragma unroll
  for (int q = 0; q < 3; ++q) {
    int wp = lane + q * 64;
    if (wp < WP_) p[wp] = (v[q] - mu) * inv * g[wp] + bb[wp];
  }
}

// ------------------------------------------------------------------
// z[b,i,wp] = mean_hp y2ln
// ------------------------------------------------------------------
__global__ void meanhp_kernel(const float* __restrict__ y2, float* __restrict__ z)
{
  int idx = blockIdx.x * 256 + threadIdx.x;
  if (idx >= B_ * S_ * WP_) return;
  int wp = idx % WP_; int t = idx / WP_;
  const float* p = y2 + (long)t * HP_ * WP_ + wp;
  float s = 0.f;
  for (int hp = 0; hp < HP_; ++hp) s += p[hp * WP_];
  z[idx] = s * (1.f / (float)HP_);
}

// ------------------------------------------------------------------
// output mask: out *= (mem_length > 0), only if ignore flag set
// ------------------------------------------------------------------
__global__ void maskout_kernel(float* __restrict__ out, const int* __restrict__ ml,
                               const int* __restrict__ ign)
{
  int idx = blockIdx.x * 256 + threadIdx.x;
  if (idx >= B_ * S_ * NOUT_) return;
  if (ign[0] == 0) return;
  if (ml[idx / NOUT_] <= 0) out[idx] = 0.f;
}

// ------------------------------------------------------------------
extern "C" void kernel_launch(void* const* d_in, const int* in_sizes, int n_in,
                              void* d_out, int out_size, void* d_ws, size_t ws_size,
                              hipStream_t stream)
{
  const float* bert = (const float*)d_in[0];
  const float* mem  = (const float*)d_in[1];
  const int*   ml   = (const int*)d_in[2];
  const float* cw   = (const float*)d_in[3];
  const int*   ign  = (const int*)d_in[4];
  const float* W1   = (const float*)d_in[6];
  const float* b1l  = (const float*)d_in[7];
  const float* sent = (const float*)d_in[8];
  const float* w1m  = (const float*)d_in[9];
  const float* w2m  = (const float*)d_in[10];
  const float* c1w  = (const float*)d_in[11];
  const float* c1b  = (const float*)d_in[12];
  const float* c2w  = (const float*)d_in[13];
  const float* c2b  = (const float*)d_in[14];
  const float* lng  = (const float*)d_in[15];
  const float* lnb  = (const float*)d_in[16];
  const float* Wo   = (const float*)d_in[17];
  const float* bo   = (const float*)d_in[18];
  float* out = (float*)d_out;

  float* ws   = (float*)d_ws;
  float* eb   = ws;                   // 147456
  float* ebb  = eb + 147456;          // 1152
  float* E    = ebb + 1152;           // 147456
  float* P    = E + 147456;           // 331776
  float* t2   = P + 331776;           // 147456
  float* attb = t2 + 147456;          // 25600
  float* G    = attb + 25600;         // 147456
  float* w1s  = G + 147456;           // 288
  float* w2s  = w1s + 288;            // 288
  float* AW   = w2s + 288;            // 4096000 (per-b reuse)
  float* y1   = AW + 4096000;         // 7372800
  float* x2   = y1 + 7372800;         // 1843200
  float* z    = x2 + 1843200;         // 73728
  // total ~14.33M floats = 57.3 MB

  dim3 blk(256);

  wsum_kernel<<<dim3(5), dim3(64), 0, stream>>>(w1m, w2m, w1s, w2s);

  // eb = bert @ W_lin1^T + b_lin1   [512 x 288], K=768
  gemm_generic<<<dim3(5, 8, 1), blk, 0, stream>>>(
      bert, W1, b1l, eb, 512, 288, 768,
      0L, 768L, 1L, 0L, 1L, 768L, 0L, 288L, 1L);

  ebbar_kernel<<<dim3(4), dim3(256), 0, stream>>>(eb, ebb);

  score_kernel<<<dim3(S_, B_), blk, 0, stream>>>(mem, sent, ebb, cw, ml, E, attb);

  // P_b = eb_b^T @ eb_b   [288 x 288], K=128, batch 4
  gemm_generic<<<dim3(5, 5, 4), blk, 0, stream>>>(
      eb, eb, (const float*)nullptr, P, 288, 288, 128,
      (long)S_ * M_, 1L, (long)M_, (long)S_ * M_, (long)M_, 1L, (long)M_ * M_, (long)M_, 1L);

  // t2 = E @ P   [128 x 288], K=288, batch 4
  gemm_generic<<<dim3(5, 2, 4), blk, 0, stream>>>(
      E, P, (const float*)nullptr, t2, 128, 288, 288,
      (long)S_ * M_, (long)M_, 1L, (long)M_ * M_, (long)M_, 1L, (long)S_ * M_, (long)M_, 1L);

  g_kernel<<<dim3(S_, B_), blk, 0, stream>>>(E, t2, w1s, w2s, G);

  for (int b = 0; b < B_; ++b) {
    conv1_aw<<<dim3(16000), blk, 0, stream>>>(attb, c1w, AW, b);
    conv1_gemm<<<dim3(5, 2, C1_), blk, 0, stream>>>(AW, G, c1b, y1, b);
  }

  pool_kernel<<<dim3((B_ * S_ * HP_ * WP_ + 255) / 256), blk, 0, stream>>>(y1, x2);

  float* y2 = y1;  // reuse (y1 no longer needed)
  conv2_gemm<<<dim3(57, 2, 4), blk, 0, stream>>>(x2, c2w, c2b, y2);

  ln_kernel<<<dim3(B_ * S_ * HP_), dim3(64), 0, stream>>>(y2, lng, lnb);

  meanhp_kernel<<<dim3((B_ * S_ * WP_ + 255) / 256), blk, 0, stream>>>(y2, z);

  // out = z @ W_out^T + b_out   [512 x 300], K=144
  gemm_generic<<<dim3(5, 8, 1), blk, 0, stream>>>(
      z, Wo, bo, out, 512, 300, 144,
      0L, 144L, 1L, 0L, 1L, 144L, 0L, 300L, 1L);

  maskout_kernel<<<dim3((B_ * S_ * NOUT_ + 255) / 256), blk, 0, stream>>>(out, ml, ign);
}

// Round 3
// 974.461 us; speedup vs baseline: 1.3038x; 1.3038x over previous
//
#include <hip/hip_runtime.h>

#define B_    4
#define S_    128
#define BERT_ 768
#define C_    49
#define C1_   50
#define M_    288
#define HP_   25
#define WP_   144
#define NOUT_ 300

typedef short bf16x8 __attribute__((ext_vector_type(8)));
typedef float f32x4 __attribute__((ext_vector_type(4)));

static __device__ __forceinline__ short f2bf(float f) {
  unsigned u = __float_as_uint(f);
  unsigned r = (u + 0x7fffu + ((u >> 16) & 1u)) >> 16;
  return (short)r;
}
static __device__ __forceinline__ float bf2f(short v) {
  return __uint_as_float(((unsigned)(unsigned short)v) << 16);
}

// ------------------------------------------------------------------
// f32 fallback GEMM (small ops: eb, P, t2, out)
// ------------------------------------------------------------------
__device__ __forceinline__ void mm16(const float (*As)[68], const float (*Bs)[68],
                                     int tx, int ty, float acc[4][4]) {
#pragma unroll
  for (int kk = 0; kk < 16; ++kk) {
    float4 av = *reinterpret_cast<const float4*>(&As[kk][ty * 4]);
    float4 bv = *reinterpret_cast<const float4*>(&Bs[kk][tx * 4]);
    float a[4] = {av.x, av.y, av.z, av.w};
    float b[4] = {bv.x, bv.y, bv.z, bv.w};
#pragma unroll
    for (int u = 0; u < 4; ++u)
#pragma unroll
      for (int v = 0; v < 4; ++v)
        acc[u][v] = fmaf(a[u], b[v], acc[u][v]);
  }
}

__global__ __launch_bounds__(256) void gemm_generic(
    const float* __restrict__ A, const float* __restrict__ Bm,
    const float* __restrict__ bias, float* __restrict__ Out,
    int Mr, int Nc, int K,
    long aB, long aI, long aK,
    long bB, long bK, long bJ,
    long oB, long oI, long oJ)
{
  const int bz = blockIdx.z;
  const int i0 = blockIdx.y * 64, j0 = blockIdx.x * 64;
  __shared__ float As[16][68];
  __shared__ float Bs[16][68];
  const int tid = threadIdx.x;
  const int tx = tid & 15, ty = tid >> 4;
  float acc[4][4] = {};
  const float* Ab = A + (long)bz * aB;
  const float* Bb = Bm + (long)bz * bB;
  for (int k0 = 0; k0 < K; k0 += 16) {
    for (int e = tid; e < 64 * 16; e += 256) {
      int i = e >> 4, k = e & 15;
      int gi = i0 + i, gk = k0 + k;
      As[k][i] = (gi < Mr && gk < K) ? Ab[(long)gi * aI + (long)gk * aK] : 0.f;
    }
    for (int e = tid; e < 16 * 64; e += 256) {
      int k = e >> 6, j = e & 63;
      int gj = j0 + j, gk = k0 + k;
      Bs[k][j] = (gj < Nc && gk < K) ? Bb[(long)gk * bK + (long)gj * bJ] : 0.f;
    }
    __syncthreads();
    mm16(As, Bs, tx, ty, acc);
    __syncthreads();
  }
#pragma unroll
  for (int u = 0; u < 4; ++u) {
    int gi = i0 + ty * 4 + u;
    if (gi >= Mr) continue;
#pragma unroll
    for (int v = 0; v < 4; ++v) {
      int gj = j0 + tx * 4 + v;
      if (gj >= Nc) continue;
      float r = acc[u][v];
      if (bias) r += bias[gj];
      Out[(long)bz * oB + (long)gi * oI + (long)gj * oJ] = r;
    }
  }
}

// ------------------------------------------------------------------
__global__ void wsum_kernel(const float* __restrict__ w1, const float* __restrict__ w2,
                            float* __restrict__ w1s, float* __restrict__ w2s)
{
  int m = blockIdx.x * 64 + threadIdx.x;
  if (m >= M_) return;
  float a = 0.f, b = 0.f;
  for (int c = 0; c < C1_; ++c) { a += w1[m * C1_ + c]; b += w2[m * C1_ + c]; }
  w1s[m] = a; w2s[m] = b;
}

__global__ void ebbar_kernel(const float* __restrict__ eb, float* __restrict__ ebb)
{
  int b = blockIdx.x;
  for (int m = threadIdx.x; m < M_; m += blockDim.x) {
    float s = 0.f;
    for (int t = 0; t < S_; ++t) s += eb[((long)(b * S_ + t)) * M_ + m];
    ebb[b * M_ + m] = s * (1.f / (float)S_);
  }
}

// ------------------------------------------------------------------
// fused per-(b,s): E, scores, softmaxes, top-5, att
// ------------------------------------------------------------------
__global__ __launch_bounds__(256) void score_kernel(
    const float* __restrict__ mem, const float* __restrict__ sentinel,
    const float* __restrict__ ebbar, const float* __restrict__ cw,
    const int* __restrict__ ml, float* __restrict__ E, float* __restrict__ att)
{
  const int s = blockIdx.x, b = blockIdx.y;
  const int tid = threadIdx.x, wave = tid >> 6, lane = tid & 63;
  __shared__ float sEb[M_];
  __shared__ float sE[4][M_];
  __shared__ float sScore[C1_];
  for (int m = tid; m < M_; m += 256) sEb[m] = ebbar[b * M_ + m];
  __syncthreads();

  const float* base = mem + ((long)(b * S_ + s)) * C_ * M_;
  float Ereg[5] = {0.f, 0.f, 0.f, 0.f, 0.f};
  for (int jj = wave; jj < C_; jj += 4) {
    const float* row = base + (long)jj * M_;
    float d = 0.f;
#pragma unroll
    for (int q = 0; q < 5; ++q) {
      int m = lane + q * 64;
      if (m < M_) { float v = row[m]; Ereg[q] += v; d = fmaf(v, sEb[m], d); }
    }
#pragma unroll
    for (int off = 32; off; off >>= 1) d += __shfl_down(d, off, 64);
    if (lane == 0) sScore[jj + 1] = d;
  }
#pragma unroll
  for (int q = 0; q < 5; ++q) { int m = lane + q * 64; if (m < M_) sE[wave][m] = Ereg[q]; }
  __syncthreads();

  if (wave == 0) {
    float d0 = 0.f;
    for (int m = lane; m < M_; m += 64) d0 = fmaf(sentinel[m], sEb[m], d0);
#pragma unroll
    for (int off = 32; off; off >>= 1) d0 += __shfl_down(d0, off, 64);
    if (lane == 0) sScore[0] = d0;
  }
  for (int m = tid; m < M_; m += 256)
    E[((long)(b * S_ + s)) * M_ + m] = sentinel[m] + sE[0][m] + sE[1][m] + sE[2][m] + sE[3][m];
  __syncthreads();

  if (wave == 0) {
    const int mlv = ml[b * S_ + s];
    float sc = (lane < C1_) ? sScore[lane] : 0.f;
    if (lane < C1_ && mlv < lane) sc -= 1e6f;
    float mx = (lane < C1_) ? sc : -3.0e38f;
#pragma unroll
    for (int off = 32; off; off >>= 1) mx = fmaxf(mx, __shfl_xor(mx, off, 64));
    float e1 = (lane < C1_) ? __expf(sc - mx) : 0.f;
    float s1 = e1;
#pragma unroll
    for (int off = 32; off; off >>= 1) s1 += __shfl_xor(s1, off, 64);
    float p1 = e1 / s1;
    float cv = 0.f;
    if (lane >= 1 && lane < C1_) cv = cw[((long)(b * S_ + s)) * C_ + lane - 1];
    float mx2 = (lane < C1_) ? cv : -3.0e38f;
#pragma unroll
    for (int off = 32; off; off >>= 1) mx2 = fmaxf(mx2, __shfl_xor(mx2, off, 64));
    float e2 = (lane < C1_) ? __expf(cv - mx2) : 0.f;
    float s2 = e2;
#pragma unroll
    for (int off = 32; off; off >>= 1) s2 += __shfl_xor(s2, off, 64);
    float p2 = e2 / s2;
    float scm = 0.7f * p1 + 0.3f * p2;
    bool active = (lane < C1_);
    float thr = 0.f;
    for (int r = 0; r < 5; ++r) {
      float v = active ? scm : -3.0e38f;
      int idx = lane;
#pragma unroll
      for (int off = 32; off; off >>= 1) {
        float ov = __shfl_xor(v, off, 64);
        int oi = __shfl_xor(idx, off, 64);
        if (ov > v || (ov == v && oi < idx)) { v = ov; idx = oi; }
      }
      thr = v;
      if (lane == idx) active = false;
    }
    float kept = (lane < C1_ && scm >= thr) ? scm : 0.f;
    float mx3 = (lane < C1_) ? kept : -3.0e38f;
#pragma unroll
    for (int off = 32; off; off >>= 1) mx3 = fmaxf(mx3, __shfl_xor(mx3, off, 64));
    float e3 = (lane < C1_) ? __expf(kept - mx3) : 0.f;
    float s3 = e3;
#pragma unroll
    for (int off = 32; off; off >>= 1) s3 += __shfl_xor(s3, off, 64);
    if (lane < C1_) att[((long)(b * S_ + s)) * C1_ + lane] = e3 / s3;
  }
}

// ------------------------------------------------------------------
// G[b,s,n] -> bf16 into padded Gp[b*128+s][292] at col 2+n
// ------------------------------------------------------------------
__global__ __launch_bounds__(256) void g_kernel(
    const float* __restrict__ E, const float* __restrict__ t2,
    const float* __restrict__ w1s, const float* __restrict__ w2s,
    short* __restrict__ Gp)
{
  const int s = blockIdx.x, b = blockIdx.y;
  __shared__ float sE[M_], s1[M_], s2[M_];
  const int tid = threadIdx.x;
  const long base = (long)(b * S_ + s) * M_;
  for (int m = tid; m < M_; m += 256) { sE[m] = E[base + m]; s1[m] = w1s[m]; s2[m] = w2s[m]; }
  __syncthreads();
  for (int n = tid; n < M_; n += 256) {
    float a = sE[n];
    float c = t2[base + n];
    float num = 0.f, den = 0.f;
#pragma unroll 4
    for (int m = 0; m < M_; ++m) {
      float z = fmaf(s1[m], a, s2[m] * c);
      float u = __expf(2.f * z);
      float th = 1.f - 2.f / (u + 1.f);
      float e = __expf(th);
      num = fmaf(sE[m], e, num);
      den += e;
    }
    Gp[(long)(b * S_ + s) * 292 + 2 + n] = f2bf(num / den);
  }
}

// ------------------------------------------------------------------
// AWp[(o*50+h)*640 + dw*128 + i] = bf16( sum_dh w1[o,i,dh,dw]*att[b,i,h+dh-2] )
// ------------------------------------------------------------------
__global__ void conv1_aw_bf(const float* __restrict__ att, const float* __restrict__ w1,
                            short* __restrict__ AWp, int b)
{
  int idx = blockIdx.x * 256 + threadIdx.x;
  if (idx >= 128 * C1_ * 640) return;
  int i = idx & 127;
  int r = idx >> 7;          // (o*50+h)*5 + dw
  int dw = r % 5;  r /= 5;
  int h = r % C1_; int o = r / C1_;
  const float* wrow = w1 + ((long)(o * 128 + i) * 5) * 5 + dw;
  const float* arow = att + (long)(b * 128 + i) * C1_;
  float s = 0.f;
#pragma unroll
  for (int dh = 0; dh < 5; ++dh) {
    int hh = h + dh - 2;
    if (hh >= 0 && hh < C1_) s = fmaf(wrow[dh * 5], arow[hh], s);
  }
  AWp[idx] = f2bf(s);
}

// ------------------------------------------------------------------
// conv1 MFMA: per (b fixed, h, w-tile) GEMM  y1[o,w] over K=640 (dw,i)
// BM=128, BN=48; 4 waves: 32 rows x 48 cols each (M_rep=2, N_rep=3)
// ------------------------------------------------------------------
__global__ __launch_bounds__(256) void conv1_mfma(
    const short* __restrict__ AWp, const short* __restrict__ Gp,
    const float* __restrict__ bias1, short* __restrict__ y1bf, int b)
{
  const int h = blockIdx.y;
  const int w0 = blockIdx.x * 48;
  __shared__ __attribute__((aligned(16))) short As[128][72];
  __shared__ __attribute__((aligned(16))) short Bs[48][72];
  const int tid = threadIdx.x;
  const int wave = tid >> 6, lane = tid & 63;
  const int lr = lane & 15, kq = (lane >> 4) * 8;
  f32x4 acc[2][3] = {};
  const short* Gb = Gp + (long)b * 128 * 292;

  for (int cc = 0; cc < 10; ++cc) {
    const int dw = cc >> 1, i0g = (cc & 1) * 64;
    for (int e = tid; e < 1024; e += 256) {
      int o = e >> 3, k8 = e & 7;
      *(bf16x8*)&As[o][k8 * 8] =
          *(const bf16x8*)&AWp[((long)o * C1_ + h) * 640 + cc * 64 + k8 * 8];
    }
    for (int e = tid; e < 3072; e += 256) {
      int c = e % 48, k = e / 48;
      Bs[c][k] = Gb[(long)(i0g + k) * 292 + w0 + c + dw];   // 2 + (w+dw-2)
    }
    __syncthreads();
#pragma unroll
    for (int ks = 0; ks < 2; ++ks) {
      bf16x8 a0 = *(const bf16x8*)&As[wave * 32 + lr][ks * 32 + kq];
      bf16x8 a1 = *(const bf16x8*)&As[wave * 32 + 16 + lr][ks * 32 + kq];
      bf16x8 bb0 = *(const bf16x8*)&Bs[lr][ks * 32 + kq];
      bf16x8 bb1 = *(const bf16x8*)&Bs[16 + lr][ks * 32 + kq];
      bf16x8 bb2 = *(const bf16x8*)&Bs[32 + lr][ks * 32 + kq];
      acc[0][0] = __builtin_amdgcn_mfma_f32_16x16x32_bf16(a0, bb0, acc[0][0], 0, 0, 0);
      acc[0][1] = __builtin_amdgcn_mfma_f32_16x16x32_bf16(a0, bb1, acc[0][1], 0, 0, 0);
      acc[0][2] = __builtin_amdgcn_mfma_f32_16x16x32_bf16(a0, bb2, acc[0][2], 0, 0, 0);
      acc[1][0] = __builtin_amdgcn_mfma_f32_16x16x32_bf16(a1, bb0, acc[1][0], 0, 0, 0);
      acc[1][1] = __builtin_amdgcn_mfma_f32_16x16x32_bf16(a1, bb1, acc[1][1], 0, 0, 0);
      acc[1][2] = __builtin_amdgcn_mfma_f32_16x16x32_bf16(a1, bb2, acc[1][2], 0, 0, 0);
    }
    __syncthreads();
  }
  const int dro = (lane >> 4) * 4;
#pragma unroll
  for (int mi = 0; mi < 2; ++mi) {
    int o = wave * 32 + mi * 16 + dro;
#pragma unroll
    for (int ni = 0; ni < 3; ++ni) {
      int w = w0 + ni * 16 + lr;
#pragma unroll
      for (int r = 0; r < 4; ++r) {
        float v = fmaxf(acc[mi][ni][r] + bias1[o + r], 0.f);
        y1bf[(((long)b * 128 + o + r) * C1_ + h) * M_ + w] = f2bf(v);
      }
    }
  }
}

// ------------------------------------------------------------------
// 2x2 maxpool on bf16 y1 -> padded x2p[(b*128+ch)*29+hp+2][wp+2]
// ------------------------------------------------------------------
__global__ void pool_bf(const short* __restrict__ y1bf, short* __restrict__ x2p)
{
  int idx = blockIdx.x * 256 + threadIdx.x;
  if (idx >= B_ * S_ * HP_ * WP_) return;
  int wp = idx % WP_; int t = idx / WP_;
  int hp = t % HP_; t /= HP_;
  const short* p = y1bf + ((long)t * C1_ + 2 * hp) * M_ + 2 * wp;
  float m = fmaxf(fmaxf(bf2f(p[0]), bf2f(p[1])), fmaxf(bf2f(p[M_]), bf2f(p[M_ + 1])));
  x2p[((long)t * 29 + hp + 2) * 148 + wp + 2] = f2bf(m);
}

// ------------------------------------------------------------------
// w2p[o*3200 + t*128 + i] = bf16(w2[o,i,t])
// ------------------------------------------------------------------
__global__ void w2perm_kernel(const float* __restrict__ w2, short* __restrict__ w2p)
{
  int idx = blockIdx.x * 256 + threadIdx.x;
  if (idx >= 128 * 3200) return;
  int i = idx & 127; int r = idx >> 7; int t = r % 25; int o = r / 25;
  w2p[idx] = f2bf(w2[((long)o * 128 + i) * 25 + t]);
}

// ------------------------------------------------------------------
// conv2 MFMA: per (b, o-tile 64, hp, w-tile 48) over K=3200 (tap,i)
// BM=64, BN=48; 4 waves: 16 rows x 48 cols each (M_rep=1, N_rep=3)
// ------------------------------------------------------------------
__global__ __launch_bounds__(256) void conv2_mfma(
    const short* __restrict__ w2p, const short* __restrict__ x2p,
    const float* __restrict__ b2, float* __restrict__ y2)
{
  const int b = blockIdx.z;
  const int o0 = blockIdx.y * 64;
  const int hp = blockIdx.x / 3, w0 = (blockIdx.x % 3) * 48;
  __shared__ __attribute__((aligned(16))) short As[64][72];
  __shared__ __attribute__((aligned(16))) short Bs[48][72];
  const int tid = threadIdx.x;
  const int wave = tid >> 6, lane = tid & 63;
  const int lr = lane & 15, kq = (lane >> 4) * 8;
  f32x4 acc[3] = {};
  const short* x2b = x2p + (long)b * 128 * 29 * 148;

  for (int cc = 0; cc < 50; ++cc) {
    const int t = cc >> 1, i0g = (cc & 1) * 64;
    const int dh = t / 5, dw = t % 5;
    for (int e = tid; e < 512; e += 256) {
      int o = e >> 3, k8 = e & 7;
      *(bf16x8*)&As[o][k8 * 8] =
          *(const bf16x8*)&w2p[(long)(o0 + o) * 3200 + cc * 64 + k8 * 8];
    }
    for (int e = tid; e < 3072; e += 256) {
      int c = e % 48, k = e / 48;
      Bs[c][k] = x2b[((long)(i0g + k) * 29 + hp + dh) * 148 + w0 + c + dw];
    }
    __syncthreads();
#pragma unroll
    for (int ks = 0; ks < 2; ++ks) {
      bf16x8 a0 = *(const bf16x8*)&As[wave * 16 + lr][ks * 32 + kq];
      bf16x8 bb0 = *(const bf16x8*)&Bs[lr][ks * 32 + kq];
      bf16x8 bb1 = *(const bf16x8*)&Bs[16 + lr][ks * 32 + kq];
      bf16x8 bb2 = *(const bf16x8*)&Bs[32 + lr][ks * 32 + kq];
      acc[0] = __builtin_amdgcn_mfma_f32_16x16x32_bf16(a0, bb0, acc[0], 0, 0, 0);
      acc[1] = __builtin_amdgcn_mfma_f32_16x16x32_bf16(a0, bb1, acc[1], 0, 0, 0);
      acc[2] = __builtin_amdgcn_mfma_f32_16x16x32_bf16(a0, bb2, acc[2], 0, 0, 0);
    }
    __syncthreads();
  }
  const int dro = (lane >> 4) * 4;
#pragma unroll
  for (int ni = 0; ni < 3; ++ni) {
#pragma unroll
    for (int r = 0; r < 4; ++r) {
      int o = o0 + wave * 16 + dro + r;
      y2[((long)(b * 128) + o) * 3600 + hp * WP_ + w0 + ni * 16 + lr] =
          fmaxf(acc[ni][r] + b2[o], 0.f);
    }
  }
}

// ------------------------------------------------------------------
__global__ __launch_bounds__(64) void ln_kernel(float* __restrict__ y2,
                                                const float* __restrict__ g,
                                                const float* __restrict__ bb)
{
  float* p = y2 + (long)blockIdx.x * WP_;
  const int lane = threadIdx.x;
  float v[3]; float s = 0.f, ss = 0.f;
#pragma unroll
  for (int q = 0; q < 3; ++q) {
    int wp = lane + q * 64;
    float x = (wp < WP_) ? p[wp] : 0.f;
    v[q] = x; s += x; ss = fmaf(x, x, ss);
  }
#pragma unroll
  for (int off = 32; off; off >>= 1) { s += __shfl_xor(s, off, 64); ss += __shfl_xor(ss, off, 64); }
  float mu = s * (1.f / (float)WP_);
  float var = ss * (1.f / (float)WP_) - mu * mu;
  float inv = rsqrtf(var + 1e-5f);
#pragma unroll
  for (int q = 0; q < 3; ++q) {
    int wp = lane + q * 64;
    if (wp < WP_) p[wp] = (v[q] - mu) * inv * g[wp] + bb[wp];
  }
}

__global__ void meanhp_kernel(const float* __restrict__ y2, float* __restrict__ z)
{
  int idx = blockIdx.x * 256 + threadIdx.x;
  if (idx >= B_ * S_ * WP_) return;
  int wp = idx % WP_; int t = idx / WP_;
  const float* p = y2 + (long)t * HP_ * WP_ + wp;
  float s = 0.f;
  for (int hp = 0; hp < HP_; ++hp) s += p[hp * WP_];
  z[idx] = s * (1.f / (float)HP_);
}

__global__ void maskout_kernel(float* __restrict__ out, const int* __restrict__ ml,
                               const int* __restrict__ ign)
{
  int idx = blockIdx.x * 256 + threadIdx.x;
  if (idx >= B_ * S_ * NOUT_) return;
  if (ign[0] == 0) return;
  if (ml[idx / NOUT_] <= 0) out[idx] = 0.f;
}

// ------------------------------------------------------------------
extern "C" void kernel_launch(void* const* d_in, const int* in_sizes, int n_in,
                              void* d_out, int out_size, void* d_ws, size_t ws_size,
                              hipStream_t stream)
{
  const float* bert = (const float*)d_in[0];
  const float* mem  = (const float*)d_in[1];
  const int*   ml   = (const int*)d_in[2];
  const float* cw   = (const float*)d_in[3];
  const int*   ign  = (const int*)d_in[4];
  const float* W1   = (const float*)d_in[6];
  const float* b1l  = (const float*)d_in[7];
  const float* sent = (const float*)d_in[8];
  const float* w1m  = (const float*)d_in[9];
  const float* w2m  = (const float*)d_in[10];
  const float* c1w  = (const float*)d_in[11];
  const float* c1b  = (const float*)d_in[12];
  const float* c2w  = (const float*)d_in[13];
  const float* c2b  = (const float*)d_in[14];
  const float* lng  = (const float*)d_in[15];
  const float* lnb  = (const float*)d_in[16];
  const float* Wo   = (const float*)d_in[17];
  const float* bo   = (const float*)d_in[18];
  float* out = (float*)d_out;

  float* ws   = (float*)d_ws;
  float* eb   = ws;                   // 147456
  float* ebb  = eb + 147456;          // 1152
  float* E    = ebb + 1152;           // 147456
  float* P    = E + 147456;           // 331776
  float* t2   = P + 331776;           // 147456
  float* attb = t2 + 147456;          // 25600
  float* w1s  = attb + 25600;         // 288
  float* w2s  = w1s + 288;            // 288
  float* z    = w2s + 288;            // 73728
  float* y2   = z + 73728;            // 1843200
  short* Gp   = (short*)(y2 + 1843200);   // 149504
  short* AWp  = Gp + 149504;              // 4096000 (per-b reuse)
  short* y1bf = AWp + 4096000;            // 7372800
  short* x2p  = y1bf + 7372800;           // 2197504 = 512*29*148  (FIXED: was 2196992)
  short* w2p  = x2p + 2197504;            // 409600
  // total ~39.4 MB

  dim3 blk(256);

  // zero padded halos (interiors fully rewritten each call)
  hipMemsetAsync(Gp, 0, (size_t)149504 * 2, stream);
  hipMemsetAsync(x2p, 0, (size_t)2197504 * 2, stream);

  wsum_kernel<<<dim3(5), dim3(64), 0, stream>>>(w1m, w2m, w1s, w2s);
  w2perm_kernel<<<dim3((128 * 3200 + 255) / 256), blk, 0, stream>>>(c2w, w2p);

  // eb = bert @ W_lin1^T + b_lin1   [512 x 288], K=768
  gemm_generic<<<dim3(5, 8, 1), blk, 0, stream>>>(
      bert, W1, b1l, eb, 512, 288, 768,
      0L, 768L, 1L, 0L, 1L, 768L, 0L, 288L, 1L);

  ebbar_kernel<<<dim3(4), dim3(256), 0, stream>>>(eb, ebb);

  score_kernel<<<dim3(S_, B_), blk, 0, stream>>>(mem, sent, ebb, cw, ml, E, attb);

  // P_b = eb_b^T @ eb_b   [288 x 288], K=128, batch 4
  gemm_generic<<<dim3(5, 5, 4), blk, 0, stream>>>(
      eb, eb, (const float*)nullptr, P, 288, 288, 128,
      (long)S_ * M_, 1L, (long)M_, (long)S_ * M_, (long)M_, 1L, (long)M_ * M_, (long)M_, 1L);

  // t2 = E @ P   [128 x 288], K=288, batch 4
  gemm_generic<<<dim3(5, 2, 4), blk, 0, stream>>>(
      E, P, (const float*)nullptr, t2, 128, 288, 288,
      (long)S_ * M_, (long)M_, 1L, (long)M_ * M_, (long)M_, 1L, (long)S_ * M_, (long)M_, 1L);

  g_kernel<<<dim3(S_, B_), blk, 0, stream>>>(E, t2, w1s, w2s, Gp);

  for (int b = 0; b < B_; ++b) {
    conv1_aw_bf<<<dim3((128 * C1_ * 640 + 255) / 256), blk, 0, stream>>>(attb, c1w, AWp, b);
    conv1_mfma<<<dim3(6, C1_, 1), blk, 0, stream>>>(AWp, Gp, c1b, y1bf, b);
  }

  pool_bf<<<dim3((B_ * S_ * HP_ * WP_ + 255) / 256), blk, 0, stream>>>(y1bf, x2p);

  conv2_mfma<<<dim3(75, 2, 4), blk, 0, stream>>>(w2p, x2p, c2b, y2);

  ln_kernel<<<dim3(B_ * S_ * HP_), dim3(64), 0, stream>>>(y2, lng, lnb);

  meanhp_kernel<<<dim3((B_ * S_ * WP_ + 255) / 256), blk, 0, stream>>>(y2, z);

  // out = z @ W_out^T + b_out   [512 x 300], K=144
  gemm_generic<<<dim3(5, 8, 1), blk, 0, stream>>>(
      z, Wo, bo, out, 512, 300, 144,
      0L, 144L, 1L, 0L, 1L, 144L, 0L, 300L, 1L);

  maskout_kernel<<<dim3((B_ * S_ * NOUT_ + 255) / 256), blk, 0, stream>>>(out, ml, ign);
}

// Round 4
// 486.390 us; speedup vs baseline: 2.6121x; 2.0035x over previous
//
#include <hip/hip_runtime.h>

#define B_    4
#define S_    128
#define BERT_ 768
#define C_    49
#define C1_   50
#define M_    288
#define HP_   25
#define WP_   144
#define NOUT_ 300

typedef short bf16x8 __attribute__((ext_vector_type(8)));
typedef short short4v __attribute__((ext_vector_type(4)));
typedef float f32x4 __attribute__((ext_vector_type(4)));

static __device__ __forceinline__ short f2bf(float f) {
  unsigned u = __float_as_uint(f);
  unsigned r = (u + 0x7fffu + ((u >> 16) & 1u)) >> 16;
  return (short)r;
}
static __device__ __forceinline__ float bf2f(short v) {
  return __uint_as_float(((unsigned)(unsigned short)v) << 16);
}
// pack 2 f32 -> u32 of 2 bf16 (RNE), single HW instr on gfx950
static __device__ __forceinline__ unsigned cvt_pk_bf16(float lo, float hi) {
  unsigned r;
  asm("v_cvt_pk_bf16_f32 %0, %1, %2" : "=v"(r) : "v"(lo), "v"(hi));
  return r;
}

// ------------------------------------------------------------------
// f32 fallback GEMM (small ops: eb, P, t2, out)
// ------------------------------------------------------------------
__device__ __forceinline__ void mm16(const float (*As)[68], const float (*Bs)[68],
                                     int tx, int ty, float acc[4][4]) {
#pragma unroll
  for (int kk = 0; kk < 16; ++kk) {
    float4 av = *reinterpret_cast<const float4*>(&As[kk][ty * 4]);
    float4 bv = *reinterpret_cast<const float4*>(&Bs[kk][tx * 4]);
    float a[4] = {av.x, av.y, av.z, av.w};
    float b[4] = {bv.x, bv.y, bv.z, bv.w};
#pragma unroll
    for (int u = 0; u < 4; ++u)
#pragma unroll
      for (int v = 0; v < 4; ++v)
        acc[u][v] = fmaf(a[u], b[v], acc[u][v]);
  }
}

__global__ __launch_bounds__(256) void gemm_generic(
    const float* __restrict__ A, const float* __restrict__ Bm,
    const float* __restrict__ bias, float* __restrict__ Out,
    int Mr, int Nc, int K,
    long aB, long aI, long aK,
    long bB, long bK, long bJ,
    long oB, long oI, long oJ)
{
  const int bz = blockIdx.z;
  const int i0 = blockIdx.y * 64, j0 = blockIdx.x * 64;
  __shared__ float As[16][68];
  __shared__ float Bs[16][68];
  const int tid = threadIdx.x;
  const int tx = tid & 15, ty = tid >> 4;
  float acc[4][4] = {};
  const float* Ab = A + (long)bz * aB;
  const float* Bb = Bm + (long)bz * bB;
  for (int k0 = 0; k0 < K; k0 += 16) {
    for (int e = tid; e < 64 * 16; e += 256) {
      int i = e >> 4, k = e & 15;
      int gi = i0 + i, gk = k0 + k;
      As[k][i] = (gi < Mr && gk < K) ? Ab[(long)gi * aI + (long)gk * aK] : 0.f;
    }
    for (int e = tid; e < 16 * 64; e += 256) {
      int k = e >> 6, j = e & 63;
      int gj = j0 + j, gk = k0 + k;
      Bs[k][j] = (gj < Nc && gk < K) ? Bb[(long)gk * bK + (long)gj * bJ] : 0.f;
    }
    __syncthreads();
    mm16(As, Bs, tx, ty, acc);
    __syncthreads();
  }
#pragma unroll
  for (int u = 0; u < 4; ++u) {
    int gi = i0 + ty * 4 + u;
    if (gi >= Mr) continue;
#pragma unroll
    for (int v = 0; v < 4; ++v) {
      int gj = j0 + tx * 4 + v;
      if (gj >= Nc) continue;
      float r = acc[u][v];
      if (bias) r += bias[gj];
      Out[(long)bz * oB + (long)gi * oI + (long)gj * oJ] = r;
    }
  }
}

// ------------------------------------------------------------------
__global__ void wsum_kernel(const float* __restrict__ w1, const float* __restrict__ w2,
                            float* __restrict__ w1s, float* __restrict__ w2s)
{
  int m = blockIdx.x * 64 + threadIdx.x;
  if (m >= M_) return;
  float a = 0.f, b = 0.f;
  for (int c = 0; c < C1_; ++c) { a += w1[m * C1_ + c]; b += w2[m * C1_ + c]; }
  w1s[m] = a; w2s[m] = b;
}

__global__ void ebbar_kernel(const float* __restrict__ eb, float* __restrict__ ebb)
{
  int b = blockIdx.x;
  for (int m = threadIdx.x; m < M_; m += blockDim.x) {
    float s = 0.f;
    for (int t = 0; t < S_; ++t) s += eb[((long)(b * S_ + t)) * M_ + m];
    ebb[b * M_ + m] = s * (1.f / (float)S_);
  }
}

// ------------------------------------------------------------------
// wp[(tap)*128*128 + o*128 + i] = bf16(w[(o*128+i)*25 + tap]),  tap = dh*5+dw
// ------------------------------------------------------------------
__global__ void wperm_kernel(const float* __restrict__ w, short* __restrict__ wp)
{
  int idx = blockIdx.x * 256 + threadIdx.x;
  if (idx >= 25 * 128 * 128) return;
  int i = idx & 127;
  int o = (idx >> 7) & 127;
  int tap = idx >> 14;
  wp[idx] = f2bf(w[((long)(o * 128 + i)) * 25 + tap]);
}

// ------------------------------------------------------------------
// fused per-(b,s): E, scores, softmaxes, top-5, att -> attTp (padded, transposed)
// attTp[b][j+2][s] (54 rows of 128)
// ------------------------------------------------------------------
__global__ __launch_bounds__(256) void score_kernel(
    const float* __restrict__ mem, const float* __restrict__ sentinel,
    const float* __restrict__ ebbar, const float* __restrict__ cw,
    const int* __restrict__ ml, float* __restrict__ E, float* __restrict__ attTp)
{
  const int s = blockIdx.x, b = blockIdx.y;
  const int tid = threadIdx.x, wave = tid >> 6, lane = tid & 63;
  __shared__ float sEb[M_];
  __shared__ float sE[4][M_];
  __shared__ float sScore[C1_];
  for (int m = tid; m < M_; m += 256) sEb[m] = ebbar[b * M_ + m];
  __syncthreads();

  const float* base = mem + ((long)(b * S_ + s)) * C_ * M_;
  float Ereg[5] = {0.f, 0.f, 0.f, 0.f, 0.f};
  for (int jj = wave; jj < C_; jj += 4) {
    const float* row = base + (long)jj * M_;
    float d = 0.f;
#pragma unroll
    for (int q = 0; q < 5; ++q) {
      int m = lane + q * 64;
      if (m < M_) { float v = row[m]; Ereg[q] += v; d = fmaf(v, sEb[m], d); }
    }
#pragma unroll
    for (int off = 32; off; off >>= 1) d += __shfl_down(d, off, 64);
    if (lane == 0) sScore[jj + 1] = d;
  }
#pragma unroll
  for (int q = 0; q < 5; ++q) { int m = lane + q * 64; if (m < M_) sE[wave][m] = Ereg[q]; }
  __syncthreads();

  if (wave == 0) {
    float d0 = 0.f;
    for (int m = lane; m < M_; m += 64) d0 = fmaf(sentinel[m], sEb[m], d0);
#pragma unroll
    for (int off = 32; off; off >>= 1) d0 += __shfl_down(d0, off, 64);
    if (lane == 0) sScore[0] = d0;
  }
  for (int m = tid; m < M_; m += 256)
    E[((long)(b * S_ + s)) * M_ + m] = sentinel[m] + sE[0][m] + sE[1][m] + sE[2][m] + sE[3][m];
  __syncthreads();

  if (wave == 0) {
    const int mlv = ml[b * S_ + s];
    float sc = (lane < C1_) ? sScore[lane] : 0.f;
    if (lane < C1_ && mlv < lane) sc -= 1e6f;
    float mx = (lane < C1_) ? sc : -3.0e38f;
#pragma unroll
    for (int off = 32; off; off >>= 1) mx = fmaxf(mx, __shfl_xor(mx, off, 64));
    float e1 = (lane < C1_) ? __expf(sc - mx) : 0.f;
    float s1 = e1;
#pragma unroll
    for (int off = 32; off; off >>= 1) s1 += __shfl_xor(s1, off, 64);
    float p1 = e1 / s1;
    float cv = 0.f;
    if (lane >= 1 && lane < C1_) cv = cw[((long)(b * S_ + s)) * C_ + lane - 1];
    float mx2 = (lane < C1_) ? cv : -3.0e38f;
#pragma unroll
    for (int off = 32; off; off >>= 1) mx2 = fmaxf(mx2, __shfl_xor(mx2, off, 64));
    float e2 = (lane < C1_) ? __expf(cv - mx2) : 0.f;
    float s2 = e2;
#pragma unroll
    for (int off = 32; off; off >>= 1) s2 += __shfl_xor(s2, off, 64);
    float p2 = e2 / s2;
    float scm = 0.7f * p1 + 0.3f * p2;
    bool active = (lane < C1_);
    float thr = 0.f;
    for (int r = 0; r < 5; ++r) {
      float v = active ? scm : -3.0e38f;
      int idx = lane;
#pragma unroll
      for (int off = 32; off; off >>= 1) {
        float ov = __shfl_xor(v, off, 64);
        int oi = __shfl_xor(idx, off, 64);
        if (ov > v || (ov == v && oi < idx)) { v = ov; idx = oi; }
      }
      thr = v;
      if (lane == idx) active = false;
    }
    float kept = (lane < C1_ && scm >= thr) ? scm : 0.f;
    float mx3 = (lane < C1_) ? kept : -3.0e38f;
#pragma unroll
    for (int off = 32; off; off >>= 1) mx3 = fmaxf(mx3, __shfl_xor(mx3, off, 64));
    float e3 = (lane < C1_) ? __expf(kept - mx3) : 0.f;
    float s3 = e3;
#pragma unroll
    for (int off = 32; off; off >>= 1) s3 += __shfl_xor(s3, off, 64);
    if (lane < C1_) attTp[((long)(b * 54) + lane + 2) * 128 + s] = e3 / s3;
  }
}

// ------------------------------------------------------------------
// G[b,s,n] -> bf16 transposed into Gt[b][n+2][s]  (292 rows x 128)
// ------------------------------------------------------------------
__global__ __launch_bounds__(256) void g_kernel(
    const float* __restrict__ E, const float* __restrict__ t2,
    const float* __restrict__ w1s, const float* __restrict__ w2s,
    short* __restrict__ Gt)
{
  const int s = blockIdx.x, b = blockIdx.y;
  __shared__ float sE[M_], s1[M_], s2[M_];
  const int tid = threadIdx.x;
  const long base = (long)(b * S_ + s) * M_;
  for (int m = tid; m < M_; m += 256) { sE[m] = E[base + m]; s1[m] = w1s[m]; s2[m] = w2s[m]; }
  __syncthreads();
  for (int n = tid; n < M_; n += 256) {
    float a = sE[n];
    float c = t2[base + n];
    float num = 0.f, den = 0.f;
#pragma unroll 4
    for (int m = 0; m < M_; ++m) {
      float z = fmaf(s1[m], a, s2[m] * c);
      float u = __expf(2.f * z);
      float th = 1.f - 2.f / (u + 1.f);
      float e = __expf(th);
      num = fmaf(sE[m], e, num);
      den += e;
    }
    Gt[((long)(b * 292) + 2 + n) * 128 + s] = f2bf(num / den);
  }
}

// ------------------------------------------------------------------
// Unified tap-GEMM conv (MFMA 16x16x32 bf16), XOR-swizzled LDS.
// C1 (conv1): act=Gt[4][292][128], attp=attTp[4][54][128]; out y1t[b][h][w][o] bf16
// C2 (conv2): act=x2t[4][29][148][128];                    out y2[b][o][hp][wp] f32
// grid: (w-tiles, hrows, b*2+otile); BM=64 o, BN=144, K=128 ch (2 halves of 64)
// ------------------------------------------------------------------
template<bool C1>
__global__ __launch_bounds__(256) void conv_tap(
    const short* __restrict__ wperm,
    const short* __restrict__ act,
    const float* __restrict__ attp,
    const float* __restrict__ bias,
    short* __restrict__ y1t,
    float* __restrict__ y2)
{
  const int bz = blockIdx.z;
  const int b = bz >> 1, o0 = (bz & 1) * 64;
  const int hrow = blockIdx.y;                // C1: h 0..49 ; C2: hp 0..24
  const int w0 = blockIdx.x * 144;            // C1: 0/144 ; C2: 0
  __shared__ __attribute__((aligned(16))) short Bs[148 * 64];
  __shared__ __attribute__((aligned(16))) short As[5 * 64 * 64];
  const int tid = threadIdx.x;
  const int wave = tid >> 6, lane = tid & 63;
  const int lr = lane & 15, kqc = lane >> 4;  // k-chunk sub-index 0..3
  f32x4 acc[9] = {};

  for (int kh = 0; kh < 2; ++kh) {
    for (int dh = 0; dh < 5; ++dh) {
      __syncthreads();
      // ---- stage A: 5 taps (this dh), rows o0..o0+63, ch kh*64..+63
      if constexpr (C1) {
        const float* attrow = attp + ((long)(b * 54) + hrow + dh) * 128 + kh * 64;
        for (int u = tid; u < 2560; u += 256) {
          int dw = u >> 9, rem = u & 511;
          int o = rem >> 3, c = rem & 7;
          bf16x8 wv = *(const bf16x8*)&wperm[(((long)(dh * 5 + dw) * 128) + o0 + o) * 128 + kh * 64 + c * 8];
          float4 f0 = *(const float4*)&attrow[c * 8];
          float4 f1 = *(const float4*)&attrow[c * 8 + 4];
          unsigned q0 = cvt_pk_bf16(bf2f(wv[0]) * f0.x, bf2f(wv[1]) * f0.y);
          unsigned q1 = cvt_pk_bf16(bf2f(wv[2]) * f0.z, bf2f(wv[3]) * f0.w);
          unsigned q2 = cvt_pk_bf16(bf2f(wv[4]) * f1.x, bf2f(wv[5]) * f1.y);
          unsigned q3 = cvt_pk_bf16(bf2f(wv[6]) * f1.z, bf2f(wv[7]) * f1.w);
          union { unsigned u4[4]; bf16x8 v; } pk;
          pk.u4[0] = q0; pk.u4[1] = q1; pk.u4[2] = q2; pk.u4[3] = q3;
          *(bf16x8*)&As[((dw * 64 + o) * 64) + ((c ^ (o & 7)) * 8)] = pk.v;
        }
      } else {
        for (int u = tid; u < 2560; u += 256) {
          int dw = u >> 9, rem = u & 511;
          int o = rem >> 3, c = rem & 7;
          bf16x8 wv = *(const bf16x8*)&wperm[(((long)(dh * 5 + dw) * 128) + o0 + o) * 128 + kh * 64 + c * 8];
          *(bf16x8*)&As[((dw * 64 + o) * 64) + ((c ^ (o & 7)) * 8)] = wv;
        }
      }
      // ---- stage B (C1: once per kh; C2: every dh since slab row moves)
      if (!C1 || dh == 0) {
        const short* src = C1 ? act + ((long)(b * 292) + w0) * 128 + kh * 64
                              : act + (((long)(b * 29) + hrow + dh) * 148) * 128 + kh * 64;
        for (int u = tid; u < 1184; u += 256) {
          int row = u >> 3, c = u & 7;
          bf16x8 v = *(const bf16x8*)&src[(long)row * 128 + c * 8];
          *(bf16x8*)&Bs[row * 64 + ((c ^ (row & 7)) * 8)] = v;
        }
      }
      __syncthreads();
      // ---- MFMA: 5 dw x 2 ks x 9 ni
#pragma unroll
      for (int dw = 0; dw < 5; ++dw) {
        const int br = lr + dw;                       // B row base (ni*16 added below)
        const int arow = wave * 16 + lr;
#pragma unroll
        for (int ks = 0; ks < 2; ++ks) {
          const int ach = ks * 4 + kqc;               // chunk 0..7
          bf16x8 af = *(const bf16x8*)&As[(dw * 64 + arow) * 64 + ((ach ^ (arow & 7)) * 8)];
          const short* bp = &Bs[br * 64 + ((ach ^ (br & 7)) * 8)];
#pragma unroll
          for (int ni = 0; ni < 9; ++ni) {
            bf16x8 bfr = *(const bf16x8*)&bp[ni * 1024];
            acc[ni] = __builtin_amdgcn_mfma_f32_16x16x32_bf16(af, bfr, acc[ni], 0, 0, 0);
          }
        }
      }
    }
  }
  // ---- epilogue
  const int dro = kqc * 4;
  const int og = o0 + wave * 16 + dro;
  if constexpr (C1) {
#pragma unroll
    for (int ni = 0; ni < 9; ++ni) {
      int wg = w0 + ni * 16 + lr;
      short4v pk;
#pragma unroll
      for (int r = 0; r < 4; ++r)
        pk[r] = f2bf(fmaxf(acc[ni][r] + bias[og + r], 0.f));
      *(short4v*)&y1t[(((long)(b * 50) + hrow) * 288 + wg) * 128 + og] = pk;
    }
  } else {
#pragma unroll
    for (int ni = 0; ni < 9; ++ni) {
      int wg = ni * 16 + lr;
#pragma unroll
      for (int r = 0; r < 4; ++r)
        y2[((long)(b * 128) + og + r) * 3600 + hrow * 144 + wg] =
            fmaxf(acc[ni][r] + bias[og + r], 0.f);
    }
  }
}

// ------------------------------------------------------------------
// 2x2 maxpool: y1t[b][h][w][o] -> x2t[b][hp+2][wp+2][o]  (all bf16, vec8)
// ------------------------------------------------------------------
__global__ void pool_t(const short* __restrict__ y1t, short* __restrict__ x2t)
{
  int idx = blockIdx.x * 256 + threadIdx.x;
  if (idx >= B_ * HP_ * WP_ * 16) return;
  int c8 = idx & 15; int t = idx >> 4;
  int wp = t % WP_; t /= WP_;
  int hp = t % HP_; int b = t / HP_;
  const short* base = y1t + (((long)(b * 50 + 2 * hp) * 288) + 2 * wp) * 128 + c8 * 8;
  bf16x8 v00 = *(const bf16x8*)&base[0];
  bf16x8 v01 = *(const bf16x8*)&base[128];
  bf16x8 v10 = *(const bf16x8*)&base[288 * 128];
  bf16x8 v11 = *(const bf16x8*)&base[288 * 128 + 128];
  bf16x8 r;
#pragma unroll
  for (int e = 0; e < 8; ++e)
    r[e] = f2bf(fmaxf(fmaxf(bf2f(v00[e]), bf2f(v01[e])), fmaxf(bf2f(v10[e]), bf2f(v11[e]))));
  *(bf16x8*)&x2t[(((long)(b * 29) + hp + 2) * 148 + wp + 2) * 128 + c8 * 8] = r;
}

// ------------------------------------------------------------------
__global__ __launch_bounds__(64) void ln_kernel(float* __restrict__ y2,
                                                const float* __restrict__ g,
                                                const float* __restrict__ bb)
{
  float* p = y2 + (long)blockIdx.x * WP_;
  const int lane = threadIdx.x;
  float v[3]; float s = 0.f, ss = 0.f;
#pragma unroll
  for (int q = 0; q < 3; ++q) {
    int wp = lane + q * 64;
    float x = (wp < WP_) ? p[wp] : 0.f;
    v[q] = x; s += x; ss = fmaf(x, x, ss);
  }
#pragma unroll
  for (int off = 32; off; off >>= 1) { s += __shfl_xor(s, off, 64); ss += __shfl_xor(ss, off, 64); }
  float mu = s * (1.f / (float)WP_);
  float var = ss * (1.f / (float)WP_) - mu * mu;
  float inv = rsqrtf(var + 1e-5f);
#pragma unroll
  for (int q = 0; q < 3; ++q) {
    int wp = lane + q * 64;
    if (wp < WP_) p[wp] = (v[q] - mu) * inv * g[wp] + bb[wp];
  }
}

__global__ void meanhp_kernel(const float* __restrict__ y2, float* __restrict__ z)
{
  int idx = blockIdx.x * 256 + threadIdx.x;
  if (idx >= B_ * S_ * WP_) return;
  int wp = idx % WP_; int t = idx / WP_;
  const float* p = y2 + (long)t * HP_ * WP_ + wp;
  float s = 0.f;
  for (int hp = 0; hp < HP_; ++hp) s += p[hp * WP_];
  z[idx] = s * (1.f / (float)HP_);
}

__global__ void maskout_kernel(float* __restrict__ out, const int* __restrict__ ml,
                               const int* __restrict__ ign)
{
  int idx = blockIdx.x * 256 + threadIdx.x;
  if (idx >= B_ * S_ * NOUT_) return;
  if (ign[0] == 0) return;
  if (ml[idx / NOUT_] <= 0) out[idx] = 0.f;
}

// ------------------------------------------------------------------
extern "C" void kernel_launch(void* const* d_in, const int* in_sizes, int n_in,
                              void* d_out, int out_size, void* d_ws, size_t ws_size,
                              hipStream_t stream)
{
  const float* bert = (const float*)d_in[0];
  const float* mem  = (const float*)d_in[1];
  const int*   ml   = (const int*)d_in[2];
  const float* cw   = (const float*)d_in[3];
  const int*   ign  = (const int*)d_in[4];
  const float* W1   = (const float*)d_in[6];
  const float* b1l  = (const float*)d_in[7];
  const float* sent = (const float*)d_in[8];
  const float* w1m  = (const float*)d_in[9];
  const float* w2m  = (const float*)d_in[10];
  const float* c1w  = (const float*)d_in[11];
  const float* c1b  = (const float*)d_in[12];
  const float* c2w  = (const float*)d_in[13];
  const float* c2b  = (const float*)d_in[14];
  const float* lng  = (const float*)d_in[15];
  const float* lnb  = (const float*)d_in[16];
  const float* Wo   = (const float*)d_in[17];
  const float* bo   = (const float*)d_in[18];
  float* out = (float*)d_out;

  float* ws    = (float*)d_ws;
  float* eb    = ws;                    // 147456
  float* ebb   = eb + 147456;           // 1152
  float* E     = ebb + 1152;            // 147456
  float* P     = E + 147456;            // 331776
  float* t2    = P + 331776;            // 147456
  float* attTp = t2 + 147456;           // 4*54*128 = 27648
  float* w1s   = attTp + 27648;         // 288
  float* w2s   = w1s + 288;             // 288
  float* z     = w2s + 288;             // 73728
  float* y2    = z + 73728;             // 4*128*3600 = 1843200
  short* Gt    = (short*)(y2 + 1843200);    // 4*292*128 = 149504
  short* w1p   = Gt + 149504;               // 25*128*128 = 409600
  short* w2p   = w1p + 409600;              // 409600
  short* y1t   = w2p + 409600;              // 4*50*288*128 = 7372800
  short* x2t   = y1t + 7372800;             // 4*29*148*128 = 2197504
  // total ~32 MB

  dim3 blk(256);

  // zero halos (interiors fully rewritten each call)
  hipMemsetAsync(Gt, 0, (size_t)149504 * 2, stream);
  hipMemsetAsync(x2t, 0, (size_t)2197504 * 2, stream);
  hipMemsetAsync(attTp, 0, (size_t)27648 * 4, stream);

  wperm_kernel<<<dim3(1600), blk, 0, stream>>>(c1w, w1p);
  wperm_kernel<<<dim3(1600), blk, 0, stream>>>(c2w, w2p);
  wsum_kernel<<<dim3(5), dim3(64), 0, stream>>>(w1m, w2m, w1s, w2s);

  // eb = bert @ W_lin1^T + b_lin1   [512 x 288], K=768
  gemm_generic<<<dim3(5, 8, 1), blk, 0, stream>>>(
      bert, W1, b1l, eb, 512, 288, 768,
      0L, 768L, 1L, 0L, 1L, 768L, 0L, 288L, 1L);

  ebbar_kernel<<<dim3(4), dim3(256), 0, stream>>>(eb, ebb);

  score_kernel<<<dim3(S_, B_), blk, 0, stream>>>(mem, sent, ebb, cw, ml, E, attTp);

  // P_b = eb_b^T @ eb_b   [288 x 288], K=128, batch 4
  gemm_generic<<<dim3(5, 5, 4), blk, 0, stream>>>(
      eb, eb, (const float*)nullptr, P, 288, 288, 128,
      (long)S_ * M_, 1L, (long)M_, (long)S_ * M_, (long)M_, 1L, (long)M_ * M_, (long)M_, 1L);

  // t2 = E @ P   [128 x 288], K=288, batch 4
  gemm_generic<<<dim3(5, 2, 4), blk, 0, stream>>>(
      E, P, (const float*)nullptr, t2, 128, 288, 288,
      (long)S_ * M_, (long)M_, 1L, (long)M_ * M_, (long)M_, 1L, (long)S_ * M_, (long)M_, 1L);

  g_kernel<<<dim3(S_, B_), blk, 0, stream>>>(E, t2, w1s, w2s, Gt);

  // conv1: grid (2 w-tiles, 50 h, 4b x 2 o-tiles)
  conv_tap<true><<<dim3(2, 50, 8), blk, 0, stream>>>(w1p, Gt, attTp, c1b, y1t, (float*)nullptr);

  pool_t<<<dim3((B_ * HP_ * WP_ * 16 + 255) / 256), blk, 0, stream>>>(y1t, x2t);

  // conv2: grid (1, 25 hp, 4b x 2 o-tiles)
  conv_tap<false><<<dim3(1, 25, 8), blk, 0, stream>>>(w2p, x2t, (const float*)nullptr, c2b,
                                                      (short*)nullptr, y2);

  ln_kernel<<<dim3(B_ * S_ * HP_), dim3(64), 0, stream>>>(y2, lng, lnb);

  meanhp_kernel<<<dim3((B_ * S_ * WP_ + 255) / 256), blk, 0, stream>>>(y2, z);

  // out = z @ W_out^T + b_out   [512 x 300], K=144
  gemm_generic<<<dim3(5, 8, 1), blk, 0, stream>>>(
      z, Wo, bo, out, 512, 300, 144,
      0L, 144L, 1L, 0L, 1L, 144L, 0L, 300L, 1L);

  maskout_kernel<<<dim3((B_ * S_ * NOUT_ + 255) / 256), blk, 0, stream>>>(out, ml, ign);
}

// Round 5
// 467.054 us; speedup vs baseline: 2.7203x; 1.0414x over previous
//
#include <hip/hip_runtime.h>

#define B_    4
#define S_    128
#define BERT_ 768
#define C_    49
#define C1_   50
#define M_    288
#define HP_   25
#define WP_   144
#define NOUT_ 300

typedef short bf16x8 __attribute__((ext_vector_type(8)));
typedef short short4v __attribute__((ext_vector_type(4)));
typedef float f32x4 __attribute__((ext_vector_type(4)));

static __device__ __forceinline__ short f2bf(float f) {
  unsigned u = __float_as_uint(f);
  unsigned r = (u + 0x7fffu + ((u >> 16) & 1u)) >> 16;
  return (short)r;
}
static __device__ __forceinline__ float bf2f(short v) {
  return __uint_as_float(((unsigned)(unsigned short)v) << 16);
}
// pack 2 f32 -> u32 of 2 bf16 (RNE), single HW instr on gfx950
static __device__ __forceinline__ unsigned cvt_pk_bf16(float lo, float hi) {
  unsigned r;
  asm("v_cvt_pk_bf16_f32 %0, %1, %2" : "=v"(r) : "v"(lo), "v"(hi));
  return r;
}

// ------------------------------------------------------------------
// f32 fallback GEMM (small ops: eb, P, t2, out)
// ------------------------------------------------------------------
__device__ __forceinline__ void mm16(const float (*As)[68], const float (*Bs)[68],
                                     int tx, int ty, float acc[4][4]) {
#pragma unroll
  for (int kk = 0; kk < 16; ++kk) {
    float4 av = *reinterpret_cast<const float4*>(&As[kk][ty * 4]);
    float4 bv = *reinterpret_cast<const float4*>(&Bs[kk][tx * 4]);
    float a[4] = {av.x, av.y, av.z, av.w};
    float b[4] = {bv.x, bv.y, bv.z, bv.w};
#pragma unroll
    for (int u = 0; u < 4; ++u)
#pragma unroll
      for (int v = 0; v < 4; ++v)
        acc[u][v] = fmaf(a[u], b[v], acc[u][v]);
  }
}

__global__ __launch_bounds__(256) void gemm_generic(
    const float* __restrict__ A, const float* __restrict__ Bm,
    const float* __restrict__ bias, float* __restrict__ Out,
    int Mr, int Nc, int K,
    long aB, long aI, long aK,
    long bB, long bK, long bJ,
    long oB, long oI, long oJ)
{
  const int bz = blockIdx.z;
  const int i0 = blockIdx.y * 64, j0 = blockIdx.x * 64;
  __shared__ float As[16][68];
  __shared__ float Bs[16][68];
  const int tid = threadIdx.x;
  const int tx = tid & 15, ty = tid >> 4;
  float acc[4][4] = {};
  const float* Ab = A + (long)bz * aB;
  const float* Bb = Bm + (long)bz * bB;
  for (int k0 = 0; k0 < K; k0 += 16) {
    for (int e = tid; e < 64 * 16; e += 256) {
      int i = e >> 4, k = e & 15;
      int gi = i0 + i, gk = k0 + k;
      As[k][i] = (gi < Mr && gk < K) ? Ab[(long)gi * aI + (long)gk * aK] : 0.f;
    }
    for (int e = tid; e < 16 * 64; e += 256) {
      int k = e >> 6, j = e & 63;
      int gj = j0 + j, gk = k0 + k;
      Bs[k][j] = (gj < Nc && gk < K) ? Bb[(long)gk * bK + (long)gj * bJ] : 0.f;
    }
    __syncthreads();
    mm16(As, Bs, tx, ty, acc);
    __syncthreads();
  }
#pragma unroll
  for (int u = 0; u < 4; ++u) {
    int gi = i0 + ty * 4 + u;
    if (gi >= Mr) continue;
#pragma unroll
    for (int v = 0; v < 4; ++v) {
      int gj = j0 + tx * 4 + v;
      if (gj >= Nc) continue;
      float r = acc[u][v];
      if (bias) r += bias[gj];
      Out[(long)bz * oB + (long)gi * oI + (long)gj * oJ] = r;
    }
  }
}

// ------------------------------------------------------------------
__global__ void wsum_kernel(const float* __restrict__ w1, const float* __restrict__ w2,
                            float* __restrict__ w1s, float* __restrict__ w2s)
{
  int m = blockIdx.x * 64 + threadIdx.x;
  if (m >= M_) return;
  float a = 0.f, b = 0.f;
  for (int c = 0; c < C1_; ++c) { a += w1[m * C1_ + c]; b += w2[m * C1_ + c]; }
  w1s[m] = a; w2s[m] = b;
}

__global__ void ebbar_kernel(const float* __restrict__ eb, float* __restrict__ ebb)
{
  int b = blockIdx.x;
  for (int m = threadIdx.x; m < M_; m += blockDim.x) {
    float s = 0.f;
    for (int t = 0; t < S_; ++t) s += eb[((long)(b * S_ + t)) * M_ + m];
    ebb[b * M_ + m] = s * (1.f / (float)S_);
  }
}

// ------------------------------------------------------------------
// wq[((tap*16 + chq)*128 + o)*8 + e] = bf16(w[(o*128 + chq*8+e)*25 + tap])
// A-frag for (tap, ks, kq-quarter, o-row) is a contiguous 16B chunk.
// ------------------------------------------------------------------
__global__ void wperm_kernel(const float* __restrict__ w, short* __restrict__ wq)
{
  int idx = blockIdx.x * 256 + threadIdx.x;
  if (idx >= 25 * 128 * 128) return;
  int e = idx & 7; int t = idx >> 3;
  int o = t & 127; t >>= 7;
  int chq = t & 15; int tap = t >> 4;
  int ch = chq * 8 + e;
  wq[idx] = f2bf(w[((long)(o * 128 + ch)) * 25 + tap]);
}

// ------------------------------------------------------------------
// fused per-(b,s): E, scores, softmaxes, top-5, att -> attTp (padded, transposed)
// attTp[b][j+2][s] (54 rows of 128)
// ------------------------------------------------------------------
__global__ __launch_bounds__(256) void score_kernel(
    const float* __restrict__ mem, const float* __restrict__ sentinel,
    const float* __restrict__ ebbar, const float* __restrict__ cw,
    const int* __restrict__ ml, float* __restrict__ E, float* __restrict__ attTp)
{
  const int s = blockIdx.x, b = blockIdx.y;
  const int tid = threadIdx.x, wave = tid >> 6, lane = tid & 63;
  __shared__ float sEb[M_];
  __shared__ float sE[4][M_];
  __shared__ float sScore[C1_];
  for (int m = tid; m < M_; m += 256) sEb[m] = ebbar[b * M_ + m];
  __syncthreads();

  const float* base = mem + ((long)(b * S_ + s)) * C_ * M_;
  float Ereg[5] = {0.f, 0.f, 0.f, 0.f, 0.f};
  for (int jj = wave; jj < C_; jj += 4) {
    const float* row = base + (long)jj * M_;
    float d = 0.f;
#pragma unroll
    for (int q = 0; q < 5; ++q) {
      int m = lane + q * 64;
      if (m < M_) { float v = row[m]; Ereg[q] += v; d = fmaf(v, sEb[m], d); }
    }
#pragma unroll
    for (int off = 32; off; off >>= 1) d += __shfl_down(d, off, 64);
    if (lane == 0) sScore[jj + 1] = d;
  }
#pragma unroll
  for (int q = 0; q < 5; ++q) { int m = lane + q * 64; if (m < M_) sE[wave][m] = Ereg[q]; }
  __syncthreads();

  if (wave == 0) {
    float d0 = 0.f;
    for (int m = lane; m < M_; m += 64) d0 = fmaf(sentinel[m], sEb[m], d0);
#pragma unroll
    for (int off = 32; off; off >>= 1) d0 += __shfl_down(d0, off, 64);
    if (lane == 0) sScore[0] = d0;
  }
  for (int m = tid; m < M_; m += 256)
    E[((long)(b * S_ + s)) * M_ + m] = sentinel[m] + sE[0][m] + sE[1][m] + sE[2][m] + sE[3][m];
  __syncthreads();

  if (wave == 0) {
    const int mlv = ml[b * S_ + s];
    float sc = (lane < C1_) ? sScore[lane] : 0.f;
    if (lane < C1_ && mlv < lane) sc -= 1e6f;
    float mx = (lane < C1_) ? sc : -3.0e38f;
#pragma unroll
    for (int off = 32; off; off >>= 1) mx = fmaxf(mx, __shfl_xor(mx, off, 64));
    float e1 = (lane < C1_) ? __expf(sc - mx) : 0.f;
    float s1 = e1;
#pragma unroll
    for (int off = 32; off; off >>= 1) s1 += __shfl_xor(s1, off, 64);
    float p1 = e1 / s1;
    float cv = 0.f;
    if (lane >= 1 && lane < C1_) cv = cw[((long)(b * S_ + s)) * C_ + lane - 1];
    float mx2 = (lane < C1_) ? cv : -3.0e38f;
#pragma unroll
    for (int off = 32; off; off >>= 1) mx2 = fmaxf(mx2, __shfl_xor(mx2, off, 64));
    float e2 = (lane < C1_) ? __expf(cv - mx2) : 0.f;
    float s2 = e2;
#pragma unroll
    for (int off = 32; off; off >>= 1) s2 += __shfl_xor(s2, off, 64);
    float p2 = e2 / s2;
    float scm = 0.7f * p1 + 0.3f * p2;
    bool active = (lane < C1_);
    float thr = 0.f;
    for (int r = 0; r < 5; ++r) {
      float v = active ? scm : -3.0e38f;
      int idx = lane;
#pragma unroll
      for (int off = 32; off; off >>= 1) {
        float ov = __shfl_xor(v, off, 64);
        int oi = __shfl_xor(idx, off, 64);
        if (ov > v || (ov == v && oi < idx)) { v = ov; idx = oi; }
      }
      thr = v;
      if (lane == idx) active = false;
    }
    float kept = (lane < C1_ && scm >= thr) ? scm : 0.f;
    float mx3 = (lane < C1_) ? kept : -3.0e38f;
#pragma unroll
    for (int off = 32; off; off >>= 1) mx3 = fmaxf(mx3, __shfl_xor(mx3, off, 64));
    float e3 = (lane < C1_) ? __expf(kept - mx3) : 0.f;
    float s3 = e3;
#pragma unroll
    for (int off = 32; off; off >>= 1) s3 += __shfl_xor(s3, off, 64);
    if (lane < C1_) attTp[((long)(b * 54) + lane + 2) * 128 + s] = e3 / s3;
  }
}

// ------------------------------------------------------------------
// G[b,s,n] -> bf16 transposed into Gt[b][n+2][s]  (292 rows x 128)
// ------------------------------------------------------------------
__global__ __launch_bounds__(256) void g_kernel(
    const float* __restrict__ E, const float* __restrict__ t2,
    const float* __restrict__ w1s, const float* __restrict__ w2s,
    short* __restrict__ Gt)
{
  const int s = blockIdx.x, b = blockIdx.y;
  __shared__ float sE[M_], s1[M_], s2[M_];
  const int tid = threadIdx.x;
  const long base = (long)(b * S_ + s) * M_;
  for (int m = tid; m < M_; m += 256) { sE[m] = E[base + m]; s1[m] = w1s[m]; s2[m] = w2s[m]; }
  __syncthreads();
  for (int n = tid; n < M_; n += 256) {
    float a = sE[n];
    float c = t2[base + n];
    float num = 0.f, den = 0.f;
#pragma unroll 4
    for (int m = 0; m < M_; ++m) {
      float z = fmaf(s1[m], a, s2[m] * c);
      float u = __expf(2.f * z);
      float th = 1.f - 2.f / (u + 1.f);
      float e = __expf(th);
      num = fmaf(sE[m], e, num);
      den += e;
    }
    Gt[((long)(b * 292) + 2 + n) * 128 + s] = f2bf(num / den);
  }
}

// ------------------------------------------------------------------
// Unified tap-GEMM conv, v2: reg-A (coalesced weight frags), LDS-B only.
// Per dh: stage B' (att-folded for C1) -> barrier -> 5dw x 4ks x (Afrag + 9 MFMA).
// C1: act=Gt[4][292][128], attp=attTp[4][54][128]; out y1t[b][h][w][o] bf16
// C2: act=x2t[4][29][148][128];                    out y2[b][o][hp][wp] f32
// grid: (wtiles, hrows, b*2+otile); BM=64 o, BN=144 w, K=128 ch x 25 taps
// ------------------------------------------------------------------
template<bool C1>
__global__ __launch_bounds__(256) void conv_tap2(
    const short* __restrict__ wq,
    const short* __restrict__ act,
    const float* __restrict__ attp,
    const float* __restrict__ bias,
    short* __restrict__ y1t,
    float* __restrict__ y2)
{
  const int bz = blockIdx.z;
  const int b = bz >> 1, o0 = (bz & 1) * 64;
  const int hrow = blockIdx.y;                 // C1: h 0..49 ; C2: hp 0..24
  const int w0 = C1 ? blockIdx.x * 144 : 0;
  __shared__ __attribute__((aligned(16))) short Bs[148 * 128];   // 37888 B
  const int tid = threadIdx.x;
  const int wave = tid >> 6, lane = tid & 63;
  const int lr = lane & 15, kq = lane >> 4;    // kq = 0..3
  f32x4 acc[9] = {};

  for (int dh = 0; dh < 5; ++dh) {
    if (dh) __syncthreads();
    // ---- stage B' (148 rows x 16 chunks of 8 ch), XOR-swizzled chunks
    if constexpr (C1) {
      const short* src = act + ((long)(b * 292) + w0) * 128;
      const float* arow = attp + ((long)(b * 54) + hrow + dh) * 128;
      for (int u = tid; u < 2368; u += 256) {
        int row = u >> 4, c = u & 15;
        bf16x8 v = *(const bf16x8*)&src[row * 128 + c * 8];
        float4 a0 = *(const float4*)&arow[c * 8];
        float4 a1 = *(const float4*)&arow[c * 8 + 4];
        union { unsigned u4[4]; bf16x8 v; } pk;
        pk.u4[0] = cvt_pk_bf16(bf2f(v[0]) * a0.x, bf2f(v[1]) * a0.y);
        pk.u4[1] = cvt_pk_bf16(bf2f(v[2]) * a0.z, bf2f(v[3]) * a0.w);
        pk.u4[2] = cvt_pk_bf16(bf2f(v[4]) * a1.x, bf2f(v[5]) * a1.y);
        pk.u4[3] = cvt_pk_bf16(bf2f(v[6]) * a1.z, bf2f(v[7]) * a1.w);
        *(bf16x8*)&Bs[row * 128 + ((c ^ (row & 7)) * 8)] = pk.v;
      }
    } else {
      const short* src = act + (((long)(b * 29) + hrow + dh) * 148) * 128;
      for (int u = tid; u < 2368; u += 256) {
        int row = u >> 4, c = u & 15;
        bf16x8 v = *(const bf16x8*)&src[row * 128 + c * 8];
        *(bf16x8*)&Bs[row * 128 + ((c ^ (row & 7)) * 8)] = v;
      }
    }
    __syncthreads();
    // ---- MFMA: A-frags straight from global (coalesced 256B per quarter-wave)
    for (int dw = 0; dw < 5; ++dw) {
      const int tap = dh * 5 + dw;
#pragma unroll
      for (int ks = 0; ks < 4; ++ks) {
        bf16x8 af = *(const bf16x8*)&wq[(((long)(tap * 16 + ks * 4 + kq)) * 128
                                         + o0 + wave * 16 + lr) * 8];
#pragma unroll
        for (int ni = 0; ni < 9; ++ni) {
          const int row = lr + ni * 16 + dw;
          bf16x8 bfr = *(const bf16x8*)&Bs[row * 128 + (((ks * 4 + kq) ^ (row & 7)) * 8)];
          acc[ni] = __builtin_amdgcn_mfma_f32_16x16x32_bf16(af, bfr, acc[ni], 0, 0, 0);
        }
      }
    }
  }
  // ---- epilogue (C/D: col=lane&15 -> w, row=(lane>>4)*4+r -> o)
  const int og = o0 + wave * 16 + kq * 4;
  if constexpr (C1) {
#pragma unroll
    for (int ni = 0; ni < 9; ++ni) {
      int wg = w0 + ni * 16 + lr;
      short4v pk;
#pragma unroll
      for (int r = 0; r < 4; ++r)
        pk[r] = f2bf(fmaxf(acc[ni][r] + bias[og + r], 0.f));
      *(short4v*)&y1t[(((long)(b * 50) + hrow) * 288 + wg) * 128 + og] = pk;
    }
  } else {
#pragma unroll
    for (int ni = 0; ni < 9; ++ni) {
      int wg = ni * 16 + lr;
#pragma unroll
      for (int r = 0; r < 4; ++r)
        y2[((long)(b * 128) + og + r) * 3600 + hrow * 144 + wg] =
            fmaxf(acc[ni][r] + bias[og + r], 0.f);
    }
  }
}

// ------------------------------------------------------------------
// 2x2 maxpool: y1t[b][h][w][o] -> x2t[b][hp+2][wp+2][o]  (all bf16, vec8)
// ------------------------------------------------------------------
__global__ void pool_t(const short* __restrict__ y1t, short* __restrict__ x2t)
{
  int idx = blockIdx.x * 256 + threadIdx.x;
  if (idx >= B_ * HP_ * WP_ * 16) return;
  int c8 = idx & 15; int t = idx >> 4;
  int wp = t % WP_; t /= WP_;
  int hp = t % HP_; int b = t / HP_;
  const short* base = y1t + (((long)(b * 50 + 2 * hp) * 288) + 2 * wp) * 128 + c8 * 8;
  bf16x8 v00 = *(const bf16x8*)&base[0];
  bf16x8 v01 = *(const bf16x8*)&base[128];
  bf16x8 v10 = *(const bf16x8*)&base[288 * 128];
  bf16x8 v11 = *(const bf16x8*)&base[288 * 128 + 128];
  bf16x8 r;
#pragma unroll
  for (int e = 0; e < 8; ++e)
    r[e] = f2bf(fmaxf(fmaxf(bf2f(v00[e]), bf2f(v01[e])), fmaxf(bf2f(v10[e]), bf2f(v11[e]))));
  *(bf16x8*)&x2t[(((long)(b * 29) + hp + 2) * 148 + wp + 2) * 128 + c8 * 8] = r;
}

// ------------------------------------------------------------------
__global__ __launch_bounds__(64) void ln_kernel(float* __restrict__ y2,
                                                const float* __restrict__ g,
                                                const float* __restrict__ bb)
{
  float* p = y2 + (long)blockIdx.x * WP_;
  const int lane = threadIdx.x;
  float v[3]; float s = 0.f, ss = 0.f;
#pragma unroll
  for (int q = 0; q < 3; ++q) {
    int wp = lane + q * 64;
    float x = (wp < WP_) ? p[wp] : 0.f;
    v[q] = x; s += x; ss = fmaf(x, x, ss);
  }
#pragma unroll
  for (int off = 32; off; off >>= 1) { s += __shfl_xor(s, off, 64); ss += __shfl_xor(ss, off, 64); }
  float mu = s * (1.f / (float)WP_);
  float var = ss * (1.f / (float)WP_) - mu * mu;
  float inv = rsqrtf(var + 1e-5f);
#pragma unroll
  for (int q = 0; q < 3; ++q) {
    int wp = lane + q * 64;
    if (wp < WP_) p[wp] = (v[q] - mu) * inv * g[wp] + bb[wp];
  }
}

__global__ void meanhp_kernel(const float* __restrict__ y2, float* __restrict__ z)
{
  int idx = blockIdx.x * 256 + threadIdx.x;
  if (idx >= B_ * S_ * WP_) return;
  int wp = idx % WP_; int t = idx / WP_;
  const float* p = y2 + (long)t * HP_ * WP_ + wp;
  float s = 0.f;
  for (int hp = 0; hp < HP_; ++hp) s += p[hp * WP_];
  z[idx] = s * (1.f / (float)HP_);
}

__global__ void maskout_kernel(float* __restrict__ out, const int* __restrict__ ml,
                               const int* __restrict__ ign)
{
  int idx = blockIdx.x * 256 + threadIdx.x;
  if (idx >= B_ * S_ * NOUT_) return;
  if (ign[0] == 0) return;
  if (ml[idx / NOUT_] <= 0) out[idx] = 0.f;
}

// ------------------------------------------------------------------
extern "C" void kernel_launch(void* const* d_in, const int* in_sizes, int n_in,
                              void* d_out, int out_size, void* d_ws, size_t ws_size,
                              hipStream_t stream)
{
  const float* bert = (const float*)d_in[0];
  const float* mem  = (const float*)d_in[1];
  const int*   ml   = (const int*)d_in[2];
  const float* cw   = (const float*)d_in[3];
  const int*   ign  = (const int*)d_in[4];
  const float* W1   = (const float*)d_in[6];
  const float* b1l  = (const float*)d_in[7];
  const float* sent = (const float*)d_in[8];
  const float* w1m  = (const float*)d_in[9];
  const float* w2m  = (const float*)d_in[10];
  const float* c1w  = (const float*)d_in[11];
  const float* c1b  = (const float*)d_in[12];
  const float* c2w  = (const float*)d_in[13];
  const float* c2b  = (const float*)d_in[14];
  const float* lng  = (const float*)d_in[15];
  const float* lnb  = (const float*)d_in[16];
  const float* Wo   = (const float*)d_in[17];
  const float* bo   = (const float*)d_in[18];
  float* out = (float*)d_out;

  float* ws    = (float*)d_ws;
  float* eb    = ws;                    // 147456
  float* ebb   = eb + 147456;           // 1152
  float* E     = ebb + 1152;            // 147456
  float* P     = E + 147456;            // 331776
  float* t2    = P + 331776;            // 147456
  float* attTp = t2 + 147456;           // 4*54*128 = 27648
  float* w1s   = attTp + 27648;         // 288
  float* w2s   = w1s + 288;             // 288
  float* z     = w2s + 288;             // 73728
  float* y2    = z + 73728;             // 4*128*3600 = 1843200
  short* Gt    = (short*)(y2 + 1843200);    // 4*292*128 = 149504
  short* w1p   = Gt + 149504;               // 25*128*128 = 409600
  short* w2p   = w1p + 409600;              // 409600
  short* y1t   = w2p + 409600;              // 4*50*288*128 = 7372800
  short* x2t   = y1t + 7372800;             // 4*29*148*128 = 2197504
  // total ~32 MB

  dim3 blk(256);

  // zero halos (interiors fully rewritten each call)
  hipMemsetAsync(Gt, 0, (size_t)149504 * 2, stream);
  hipMemsetAsync(x2t, 0, (size_t)2197504 * 2, stream);
  hipMemsetAsync(attTp, 0, (size_t)27648 * 4, stream);

  wperm_kernel<<<dim3(1600), blk, 0, stream>>>(c1w, w1p);
  wperm_kernel<<<dim3(1600), blk, 0, stream>>>(c2w, w2p);
  wsum_kernel<<<dim3(5), dim3(64), 0, stream>>>(w1m, w2m, w1s, w2s);

  // eb = bert @ W_lin1^T + b_lin1   [512 x 288], K=768
  gemm_generic<<<dim3(5, 8, 1), blk, 0, stream>>>(
      bert, W1, b1l, eb, 512, 288, 768,
      0L, 768L, 1L, 0L, 1L, 768L, 0L, 288L, 1L);

  ebbar_kernel<<<dim3(4), dim3(256), 0, stream>>>(eb, ebb);

  score_kernel<<<dim3(S_, B_), blk, 0, stream>>>(mem, sent, ebb, cw, ml, E, attTp);

  // P_b = eb_b^T @ eb_b   [288 x 288], K=128, batch 4
  gemm_generic<<<dim3(5, 5, 4), blk, 0, stream>>>(
      eb, eb, (const float*)nullptr, P, 288, 288, 128,
      (long)S_ * M_, 1L, (long)M_, (long)S_ * M_, (long)M_, 1L, (long)M_ * M_, (long)M_, 1L);

  // t2 = E @ P   [128 x 288], K=288, batch 4
  gemm_generic<<<dim3(5, 2, 4), blk, 0, stream>>>(
      E, P, (const float*)nullptr, t2, 128, 288, 288,
      (long)S_ * M_, (long)M_, 1L, (long)M_ * M_, (long)M_, 1L, (long)S_ * M_, (long)M_, 1L);

  g_kernel<<<dim3(S_, B_), blk, 0, stream>>>(E, t2, w1s, w2s, Gt);

  // conv1: grid (2 w-tiles, 50 h, 4b x 2 o-tiles)
  conv_tap2<true><<<dim3(2, 50, 8), blk, 0, stream>>>(w1p, Gt, attTp, c1b, y1t, (float*)nullptr);

  pool_t<<<dim3((B_ * HP_ * WP_ * 16 + 255) / 256), blk, 0, stream>>>(y1t, x2t);

  // conv2: grid (1, 25 hp, 4b x 2 o-tiles)
  conv_tap2<false><<<dim3(1, 25, 8), blk, 0, stream>>>(w2p, x2t, (const float*)nullptr, c2b,
                                                       (short*)nullptr, y2);

  ln_kernel<<<dim3(B_ * S_ * HP_), dim3(64), 0, stream>>>(y2, lng, lnb);

  meanhp_kernel<<<dim3((B_ * S_ * WP_ + 255) / 256), blk, 0, stream>>>(y2, z);

  // out = z @ W_out^T + b_out   [512 x 300], K=144
  gemm_generic<<<dim3(5, 8, 1), blk, 0, stream>>>(
      z, Wo, bo, out, 512, 300, 144,
      0L, 144L, 1L, 0L, 1L, 144L, 0L, 300L, 1L);

  maskout_kernel<<<dim3((B_ * S_ * NOUT_ + 255) / 256), blk, 0, stream>>>(out, ml, ign);
}

// Round 7
// 343.394 us; speedup vs baseline: 3.6999x; 1.3601x over previous
//
#include <hip/hip_runtime.h>

#define B_    4
#define S_    128
#define BERT_ 768
#define C_    49
#define C1_   50
#define M_    288
#define HP_   25
#define WP_   144
#define NOUT_ 300

typedef short bf16x8 __attribute__((ext_vector_type(8)));
typedef short short4v __attribute__((ext_vector_type(4)));
typedef float f32x4 __attribute__((ext_vector_type(4)));

static __device__ __forceinline__ short f2bf(float f) {
  unsigned u = __float_as_uint(f);
  unsigned r = (u + 0x7fffu + ((u >> 16) & 1u)) >> 16;
  return (short)r;
}
static __device__ __forceinline__ float bf2f(short v) {
  return __uint_as_float(((unsigned)(unsigned short)v) << 16);
}
static __device__ __forceinline__ unsigned cvt_pk_bf16(float lo, float hi) {
  unsigned r;
  asm("v_cvt_pk_bf16_f32 %0, %1, %2" : "=v"(r) : "v"(lo), "v"(hi));
  return r;
}

// ------------------------------------------------------------------
// cast f32 [R][Ks] -> split bf16 (hi,lo) [R][Kd], zero pad cols [Ks,Kd)
// ------------------------------------------------------------------
__global__ void cast_pad_split(const float* __restrict__ src, short* __restrict__ dst,
                               long loOff, int R, int Ks, int Kd)
{
  int idx = blockIdx.x * 256 + threadIdx.x;
  if (idx >= R * Kd) return;
  int k = idx % Kd, r = idx / Kd;
  short h = 0, l = 0;
  if (k < Ks) {
    float v = src[(long)r * Ks + k];
    h = f2bf(v);
    l = f2bf(v - bf2f(h));
  }
  dst[idx] = h;
  dst[idx + loOff] = l;
}

// ------------------------------------------------------------------
// split-bf16 MFMA GEMM: Out[i,j] = sum_k A[i,k]*B[j,k] (+bias[j])
// A,B split bf16 (hi at base, lo at base+{a,b}Lo), row-major, K-contig,
// K = KH*64. 64x64 tile, 4 waves, XOR-swizzled LDS.
// acc += Ahi*Bhi + Ahi*Blo + Alo*Bhi  (rel err ~2^-17)
// OMODE 0: f32 out. 1: f32 out + split ebt[((i>>7)*288+j)*128+(i&127)].
// 2: split bf16 out row-major (obB/obP, lo at +obLo).
// ------------------------------------------------------------------
template<int OMODE>
__global__ __launch_bounds__(256) void gemm_split(
    const short* __restrict__ A, const short* __restrict__ Bm,
    const float* __restrict__ bias,
    float* __restrict__ Outf, short* __restrict__ Outb,
    int Mr, int Nc, int KH,
    long aB, int aP, long aLo,
    long bB, int bP, long bLo,
    long oB, int oP,
    long obB, int obP, long obLo)
{
  const int z = blockIdx.z;
  const int i0 = blockIdx.y * 64, j0 = blockIdx.x * 64;
  __shared__ __attribute__((aligned(16))) short As[2][64 * 64];
  __shared__ __attribute__((aligned(16))) short Bs[2][64 * 64];
  const int tid = threadIdx.x;
  const int wave = tid >> 6, lane = tid & 63;
  const int lr = lane & 15, kq = lane >> 4;
  f32x4 acc[4] = {};
  const short* Ab = A + z * aB;
  const short* Bb = Bm + z * bB;
  const bf16x8 vz = {0, 0, 0, 0, 0, 0, 0, 0};
  for (int kh = 0; kh < KH; ++kh) {
    if (kh) __syncthreads();
    for (int u = tid; u < 512; u += 256) {
      int row = u >> 3, c = u & 7;
      int gi = i0 + row;
      const short* src = &Ab[(long)gi * aP + kh * 64 + c * 8];
      bf16x8 vh = (gi < Mr) ? *(const bf16x8*)src : vz;
      bf16x8 vl = (gi < Mr) ? *(const bf16x8*)(src + aLo) : vz;
      int dst = row * 64 + ((c ^ (row & 7)) * 8);
      *(bf16x8*)&As[0][dst] = vh;
      *(bf16x8*)&As[1][dst] = vl;
    }
    for (int u = tid; u < 512; u += 256) {
      int row = u >> 3, c = u & 7;
      int gj = j0 + row;
      const short* src = &Bb[(long)gj * bP + kh * 64 + c * 8];
      bf16x8 vh = (gj < Nc) ? *(const bf16x8*)src : vz;
      bf16x8 vl = (gj < Nc) ? *(const bf16x8*)(src + bLo) : vz;
      int dst = row * 64 + ((c ^ (row & 7)) * 8);
      *(bf16x8*)&Bs[0][dst] = vh;
      *(bf16x8*)&Bs[1][dst] = vl;
    }
    __syncthreads();
#pragma unroll
    for (int ks = 0; ks < 2; ++ks) {
      const int ch = ks * 4 + kq;
      const int ar = wave * 16 + lr;
      const int ao = ar * 64 + ((ch ^ (ar & 7)) * 8);
      bf16x8 ah = *(const bf16x8*)&As[0][ao];
      bf16x8 al = *(const bf16x8*)&As[1][ao];
#pragma unroll
      for (int ni = 0; ni < 4; ++ni) {
        const int br = ni * 16 + lr;
        const int bo2 = br * 64 + ((ch ^ (br & 7)) * 8);
        bf16x8 bh = *(const bf16x8*)&Bs[0][bo2];
        bf16x8 bl = *(const bf16x8*)&Bs[1][bo2];
        acc[ni] = __builtin_amdgcn_mfma_f32_16x16x32_bf16(ah, bh, acc[ni], 0, 0, 0);
        acc[ni] = __builtin_amdgcn_mfma_f32_16x16x32_bf16(ah, bl, acc[ni], 0, 0, 0);
        acc[ni] = __builtin_amdgcn_mfma_f32_16x16x32_bf16(al, bh, acc[ni], 0, 0, 0);
      }
    }
  }
#pragma unroll
  for (int ni = 0; ni < 4; ++ni) {
    int jg = j0 + ni * 16 + lr;
    if (jg >= Nc) continue;
#pragma unroll
    for (int r = 0; r < 4; ++r) {
      int ig = i0 + wave * 16 + kq * 4 + r;
      if (ig >= Mr) continue;
      float v = acc[ni][r];
      if (bias) v += bias[jg];
      if constexpr (OMODE == 0 || OMODE == 1)
        Outf[z * oB + (long)ig * oP + jg] = v;
      if constexpr (OMODE == 1) {
        long o = ((long)((ig >> 7) * 288 + jg)) * 128 + (ig & 127);
        short h = f2bf(v);
        Outb[o] = h;
        Outb[o + obLo] = f2bf(v - bf2f(h));
      }
      if constexpr (OMODE == 2) {
        long o = z * obB + (long)ig * obP + jg;
        short h = f2bf(v);
        Outb[o] = h;
        Outb[o + obLo] = f2bf(v - bf2f(h));
      }
    }
  }
}

// ------------------------------------------------------------------
__global__ void wsum_kernel(const float* __restrict__ w1, const float* __restrict__ w2,
                            float* __restrict__ w1s, float* __restrict__ w2s)
{
  int m = blockIdx.x * 64 + threadIdx.x;
  if (m >= M_) return;
  float a = 0.f, b = 0.f;
  for (int c = 0; c < C1_; ++c) { a += w1[m * C1_ + c]; b += w2[m * C1_ + c]; }
  w1s[m] = a; w2s[m] = b;
}

__global__ void ebbar_kernel(const float* __restrict__ eb, float* __restrict__ ebb)
{
  int b = blockIdx.x;
  for (int m = threadIdx.x; m < M_; m += blockDim.x) {
    float s = 0.f;
    for (int t = 0; t < S_; ++t) s += eb[((long)(b * S_ + t)) * M_ + m];
    ebb[b * M_ + m] = s * (1.f / (float)S_);
  }
}

// ------------------------------------------------------------------
// wq[((tap*16 + chq)*128 + o)*8 + e] = bf16(w[(o*128 + chq*8+e)*25 + tap])
// ------------------------------------------------------------------
__global__ void wperm_kernel(const float* __restrict__ w, short* __restrict__ wq)
{
  int idx = blockIdx.x * 256 + threadIdx.x;
  if (idx >= 25 * 128 * 128) return;
  int e = idx & 7; int t = idx >> 3;
  int o = t & 127; t >>= 7;
  int chq = t & 15; int tap = t >> 4;
  int ch = chq * 8 + e;
  wq[idx] = f2bf(w[((long)(o * 128 + ch)) * 25 + tap]);
}

// ------------------------------------------------------------------
// fused per-(b,s): E (f32 + split bf16 padded), scores, softmaxes, top-5, att
// ------------------------------------------------------------------
__global__ __launch_bounds__(256) void score_kernel(
    const float* __restrict__ mem, const float* __restrict__ sentinel,
    const float* __restrict__ ebbar, const float* __restrict__ cw,
    const int* __restrict__ ml, float* __restrict__ E, short* __restrict__ Eb,
    float* __restrict__ attTp)
{
  const int s = blockIdx.x, b = blockIdx.y;
  const int tid = threadIdx.x, wave = tid >> 6, lane = tid & 63;
  __shared__ float sEb[M_];
  __shared__ float sE[4][M_];
  __shared__ float sScore[C1_];
  for (int m = tid; m < M_; m += 256) sEb[m] = ebbar[b * M_ + m];
  __syncthreads();

  const float* base = mem + ((long)(b * S_ + s)) * C_ * M_;
  float Ereg[5] = {0.f, 0.f, 0.f, 0.f, 0.f};
  for (int jj = wave; jj < C_; jj += 4) {
    const float* row = base + (long)jj * M_;
    float d = 0.f;
#pragma unroll
    for (int q = 0; q < 5; ++q) {
      int m = lane + q * 64;
      if (m < M_) { float v = row[m]; Ereg[q] += v; d = fmaf(v, sEb[m], d); }
    }
#pragma unroll
    for (int off = 32; off; off >>= 1) d += __shfl_down(d, off, 64);
    if (lane == 0) sScore[jj + 1] = d;
  }
#pragma unroll
  for (int q = 0; q < 5; ++q) { int m = lane + q * 64; if (m < M_) sE[wave][m] = Ereg[q]; }
  __syncthreads();

  if (wave == 0) {
    float d0 = 0.f;
    for (int m = lane; m < M_; m += 64) d0 = fmaf(sentinel[m], sEb[m], d0);
#pragma unroll
    for (int off = 32; off; off >>= 1) d0 += __shfl_down(d0, off, 64);
    if (lane == 0) sScore[0] = d0;
  }
  for (int m = tid; m < M_; m += 256) {
    float ev = sentinel[m] + sE[0][m] + sE[1][m] + sE[2][m] + sE[3][m];
    E[((long)(b * S_ + s)) * M_ + m] = ev;
    short h = f2bf(ev);
    Eb[((long)(b * S_ + s)) * 384 + m] = h;
    Eb[196608 + ((long)(b * S_ + s)) * 384 + m] = f2bf(ev - bf2f(h));
  }
  __syncthreads();

  if (wave == 0) {
    const int mlv = ml[b * S_ + s];
    float sc = (lane < C1_) ? sScore[lane] : 0.f;
    if (lane < C1_ && mlv < lane) sc -= 1e6f;
    float mx = (lane < C1_) ? sc : -3.0e38f;
#pragma unroll
    for (int off = 32; off; off >>= 1) mx = fmaxf(mx, __shfl_xor(mx, off, 64));
    float e1 = (lane < C1_) ? __expf(sc - mx) : 0.f;
    float s1 = e1;
#pragma unroll
    for (int off = 32; off; off >>= 1) s1 += __shfl_xor(s1, off, 64);
    float p1 = e1 / s1;
    float cv = 0.f;
    if (lane >= 1 && lane < C1_) cv = cw[((long)(b * S_ + s)) * C_ + lane - 1];
    float mx2 = (lane < C1_) ? cv : -3.0e38f;
#pragma unroll
    for (int off = 32; off; off >>= 1) mx2 = fmaxf(mx2, __shfl_xor(mx2, off, 64));
    float e2 = (lane < C1_) ? __expf(cv - mx2) : 0.f;
    float s2 = e2;
#pragma unroll
    for (int off = 32; off; off >>= 1) s2 += __shfl_xor(s2, off, 64);
    float p2 = e2 / s2;
    float scm = 0.7f * p1 + 0.3f * p2;
    bool active = (lane < C1_);
    float thr = 0.f;
    for (int r = 0; r < 5; ++r) {
      float v = active ? scm : -3.0e38f;
      int idx = lane;
#pragma unroll
      for (int off = 32; off; off >>= 1) {
        float ov = __shfl_xor(v, off, 64);
        int oi = __shfl_xor(idx, off, 64);
        if (ov > v || (ov == v && oi < idx)) { v = ov; idx = oi; }
      }
      thr = v;
      if (lane == idx) active = false;
    }
    float kept = (lane < C1_ && scm >= thr) ? scm : 0.f;
    float mx3 = (lane < C1_) ? kept : -3.0e38f;
#pragma unroll
    for (int off = 32; off; off >>= 1) mx3 = fmaxf(mx3, __shfl_xor(mx3, off, 64));
    float e3 = (lane < C1_) ? __expf(kept - mx3) : 0.f;
    float s3 = e3;
#pragma unroll
    for (int off = 32; off; off >>= 1) s3 += __shfl_xor(s3, off, 64);
    if (lane < C1_) attTp[((long)(b * 54) + lane + 2) * 128 + s] = e3 / s3;
  }
}

// ------------------------------------------------------------------
// G[b,s,n] -> bf16 transposed into Gt[b][n+2][s]
// ------------------------------------------------------------------
__global__ __launch_bounds__(256) void g_kernel(
    const float* __restrict__ E, const float* __restrict__ t2,
    const float* __restrict__ w1s, const float* __restrict__ w2s,
    short* __restrict__ Gt)
{
  const int s = blockIdx.x, b = blockIdx.y;
  __shared__ float sE[M_], s1[M_], s2[M_];
  const int tid = threadIdx.x;
  const long base = (long)(b * S_ + s) * M_;
  for (int m = tid; m < M_; m += 256) { sE[m] = E[base + m]; s1[m] = w1s[m]; s2[m] = w2s[m]; }
  __syncthreads();
  for (int n = tid; n < M_; n += 256) {
    float a = sE[n];
    float c = t2[base + n];
    float num = 0.f, den = 0.f;
#pragma unroll 4
    for (int m = 0; m < M_; ++m) {
      float z = fmaf(s1[m], a, s2[m] * c);
      float u = __expf(2.f * z);
      float th = 1.f - 2.f / (u + 1.f);
      float e = __expf(th);
      num = fmaf(sE[m], e, num);
      den += e;
    }
    Gt[((long)(b * 292) + 2 + n) * 128 + s] = f2bf(num / den);
  }
}

// ------------------------------------------------------------------
// Unified tap-GEMM conv (reg-A weight frags, LDS-B XOR-swizzled)
// ------------------------------------------------------------------
template<bool C1>
__global__ __launch_bounds__(256) void conv_tap2(
    const short* __restrict__ wq,
    const short* __restrict__ act,
    const float* __restrict__ attp,
    const float* __restrict__ bias,
    short* __restrict__ y1t,
    float* __restrict__ y2)
{
  const int bz = blockIdx.z;
  const int b = bz >> 1, o0 = (bz & 1) * 64;
  const int hrow = blockIdx.y;
  const int w0 = C1 ? blockIdx.x * 144 : 0;
  __shared__ __attribute__((aligned(16))) short Bs[148 * 128];
  const int tid = threadIdx.x;
  const int wave = tid >> 6, lane = tid & 63;
  const int lr = lane & 15, kq = lane >> 4;
  f32x4 acc[9] = {};

  for (int dh = 0; dh < 5; ++dh) {
    if (dh) __syncthreads();
    if constexpr (C1) {
      const short* src = act + ((long)(b * 292) + w0) * 128;
      const float* arow = attp + ((long)(b * 54) + hrow + dh) * 128;
      for (int u = tid; u < 2368; u += 256) {
        int row = u >> 4, c = u & 15;
        bf16x8 v = *(const bf16x8*)&src[row * 128 + c * 8];
        float4 a0 = *(const float4*)&arow[c * 8];
        float4 a1 = *(const float4*)&arow[c * 8 + 4];
        union { unsigned u4[4]; bf16x8 v; } pk;
        pk.u4[0] = cvt_pk_bf16(bf2f(v[0]) * a0.x, bf2f(v[1]) * a0.y);
        pk.u4[1] = cvt_pk_bf16(bf2f(v[2]) * a0.z, bf2f(v[3]) * a0.w);
        pk.u4[2] = cvt_pk_bf16(bf2f(v[4]) * a1.x, bf2f(v[5]) * a1.y);
        pk.u4[3] = cvt_pk_bf16(bf2f(v[6]) * a1.z, bf2f(v[7]) * a1.w);
        *(bf16x8*)&Bs[row * 128 + ((c ^ (row & 7)) * 8)] = pk.v;
      }
    } else {
      const short* src = act + (((long)(b * 29) + hrow + dh) * 148) * 128;
      for (int u = tid; u < 2368; u += 256) {
        int row = u >> 4, c = u & 15;
        bf16x8 v = *(const bf16x8*)&src[row * 128 + c * 8];
        *(bf16x8*)&Bs[row * 128 + ((c ^ (row & 7)) * 8)] = v;
      }
    }
    __syncthreads();
    for (int dw = 0; dw < 5; ++dw) {
      const int tap = dh * 5 + dw;
#pragma unroll
      for (int ks = 0; ks < 4; ++ks) {
        bf16x8 af = *(const bf16x8*)&wq[(((long)(tap * 16 + ks * 4 + kq)) * 128
                                         + o0 + wave * 16 + lr) * 8];
#pragma unroll
        for (int ni = 0; ni < 9; ++ni) {
          const int row = lr + ni * 16 + dw;
          bf16x8 bfr = *(const bf16x8*)&Bs[row * 128 + (((ks * 4 + kq) ^ (row & 7)) * 8)];
          acc[ni] = __builtin_amdgcn_mfma_f32_16x16x32_bf16(af, bfr, acc[ni], 0, 0, 0);
        }
      }
    }
  }
  const int og = o0 + wave * 16 + kq * 4;
  if constexpr (C1) {
#pragma unroll
    for (int ni = 0; ni < 9; ++ni) {
      int wg = w0 + ni * 16 + lr;
      short4v pk;
#pragma unroll
      for (int r = 0; r < 4; ++r)
        pk[r] = f2bf(fmaxf(acc[ni][r] + bias[og + r], 0.f));
      *(short4v*)&y1t[(((long)(b * 50) + hrow) * 288 + wg) * 128 + og] = pk;
    }
  } else {
#pragma unroll
    for (int ni = 0; ni < 9; ++ni) {
      int wg = ni * 16 + lr;
#pragma unroll
      for (int r = 0; r < 4; ++r)
        y2[((long)(b * 128) + og + r) * 3600 + hrow * 144 + wg] =
            fmaxf(acc[ni][r] + bias[og + r], 0.f);
    }
  }
}

// ------------------------------------------------------------------
__global__ void pool_t(const short* __restrict__ y1t, short* __restrict__ x2t)
{
  int idx = blockIdx.x * 256 + threadIdx.x;
  if (idx >= B_ * HP_ * WP_ * 16) return;
  int c8 = idx & 15; int t = idx >> 4;
  int wp = t % WP_; t /= WP_;
  int hp = t % HP_; int b = t / HP_;
  const short* base = y1t + (((long)(b * 50 + 2 * hp) * 288) + 2 * wp) * 128 + c8 * 8;
  bf16x8 v00 = *(const bf16x8*)&base[0];
  bf16x8 v01 = *(const bf16x8*)&base[128];
  bf16x8 v10 = *(const bf16x8*)&base[288 * 128];
  bf16x8 v11 = *(const bf16x8*)&base[288 * 128 + 128];
  bf16x8 r;
#pragma unroll
  for (int e = 0; e < 8; ++e)
    r[e] = f2bf(fmaxf(fmaxf(bf2f(v00[e]), bf2f(v01[e])), fmaxf(bf2f(v10[e]), bf2f(v11[e]))));
  *(bf16x8*)&x2t[(((long)(b * 29) + hp + 2) * 148 + wp + 2) * 128 + c8 * 8] = r;
}

// ------------------------------------------------------------------
__global__ __launch_bounds__(64) void ln_kernel(float* __restrict__ y2,
                                                const float* __restrict__ g,
                                                const float* __restrict__ bb)
{
  float* p = y2 + (long)blockIdx.x * WP_;
  const int lane = threadIdx.x;
  float v[3]; float s = 0.f, ss = 0.f;
#pragma unroll
  for (int q = 0; q < 3; ++q) {
    int wp = lane + q * 64;
    float x = (wp < WP_) ? p[wp] : 0.f;
    v[q] = x; s += x; ss = fmaf(x, x, ss);
  }
#pragma unroll
  for (int off = 32; off; off >>= 1) { s += __shfl_xor(s, off, 64); ss += __shfl_xor(ss, off, 64); }
  float mu = s * (1.f / (float)WP_);
  float var = ss * (1.f / (float)WP_) - mu * mu;
  float inv = rsqrtf(var + 1e-5f);
#pragma unroll
  for (int q = 0; q < 3; ++q) {
    int wp = lane + q * 64;
    if (wp < WP_) p[wp] = (v[q] - mu) * inv * g[wp] + bb[wp];
  }
}

// mean over hp -> split bf16 zb[512][256] (pad zeroed by memset)
__global__ void meanhp_kernel(const float* __restrict__ y2, short* __restrict__ zb)
{
  int idx = blockIdx.x * 256 + threadIdx.x;
  if (idx >= B_ * S_ * WP_) return;
  int wp = idx % WP_; int t = idx / WP_;
  const float* p = y2 + (long)t * HP_ * WP_ + wp;
  float s = 0.f;
  for (int hp = 0; hp < HP_; ++hp) s += p[hp * WP_];
  float v = s * (1.f / (float)HP_);
  short h = f2bf(v);
  zb[(long)t * 256 + wp] = h;
  zb[131072 + (long)t * 256 + wp] = f2bf(v - bf2f(h));
}

__global__ void maskout_kernel(float* __restrict__ out, const int* __restrict__ ml,
                               const int* __restrict__ ign)
{
  int idx = blockIdx.x * 256 + threadIdx.x;
  if (idx >= B_ * S_ * NOUT_) return;
  if (ign[0] == 0) return;
  if (ml[idx / NOUT_] <= 0) out[idx] = 0.f;
}

// ------------------------------------------------------------------
extern "C" void kernel_launch(void* const* d_in, const int* in_sizes, int n_in,
                              void* d_out, int out_size, void* d_ws, size_t ws_size,
                              hipStream_t stream)
{
  const float* bert = (const float*)d_in[0];
  const float* mem  = (const float*)d_in[1];
  const int*   ml   = (const int*)d_in[2];
  const float* cw   = (const float*)d_in[3];
  const int*   ign  = (const int*)d_in[4];
  const float* W1   = (const float*)d_in[6];
  const float* b1l  = (const float*)d_in[7];
  const float* sent = (const float*)d_in[8];
  const float* w1m  = (const float*)d_in[9];
  const float* w2m  = (const float*)d_in[10];
  const float* c1w  = (const float*)d_in[11];
  const float* c1b  = (const float*)d_in[12];
  const float* c2w  = (const float*)d_in[13];
  const float* c2b  = (const float*)d_in[14];
  const float* lng  = (const float*)d_in[15];
  const float* lnb  = (const float*)d_in[16];
  const float* Wo   = (const float*)d_in[17];
  const float* bo   = (const float*)d_in[18];
  float* out = (float*)d_out;

  float* ws    = (float*)d_ws;
  float* eb    = ws;                    // 147456
  float* ebb   = eb + 147456;           // 1152
  float* E     = ebb + 1152;            // 147456
  float* t2    = E + 147456;            // 147456
  float* attTp = t2 + 147456;           // 27648
  float* w1s   = attTp + 27648;         // 288
  float* w2s   = w1s + 288;             // 288
  float* y2    = w2s + 288;             // 1843200
  short* Gt    = (short*)(y2 + 1843200);    // 149504
  short* w1p   = Gt + 149504;               // 409600
  short* w2p   = w1p + 409600;              // 409600
  short* y1t   = w2p + 409600;              // 7372800
  short* x2t   = y1t + 7372800;             // 2197504
  short* bertb = x2t + 2197504;             // 2x 512*768  = 786432
  short* w1b   = bertb + 786432;            // 2x 288*768  = 442368
  short* wob   = w1b + 442368;              // 2x 300*256  = 153600
  short* ebt   = wob + 153600;              // 2x 4*288*128 = 294912
  short* Eb    = ebt + 294912;              // 2x 512*384  = 393216
  short* pb    = Eb + 393216;               // 2x 4*288*384 = 884736
  short* zb    = pb + 884736;               // 2x 512*256  = 262144
  // total ~37 MB

  dim3 blk(256);

  // zero halos / pads (interiors fully rewritten each call)
  hipMemsetAsync(Gt, 0, (size_t)149504 * 2, stream);
  hipMemsetAsync(x2t, 0, (size_t)2197504 * 2, stream);
  hipMemsetAsync(attTp, 0, (size_t)27648 * 4, stream);
  hipMemsetAsync(Eb, 0, (size_t)393216 * 2, stream);
  hipMemsetAsync(pb, 0, (size_t)884736 * 2, stream);
  hipMemsetAsync(zb, 0, (size_t)262144 * 2, stream);

  cast_pad_split<<<dim3(1536), blk, 0, stream>>>(bert, bertb, 393216L, 512, 768, 768);
  cast_pad_split<<<dim3(864), blk, 0, stream>>>(W1, w1b, 221184L, 288, 768, 768);
  cast_pad_split<<<dim3(300), blk, 0, stream>>>(Wo, wob, 76800L, 300, 144, 256);
  wperm_kernel<<<dim3(1600), blk, 0, stream>>>(c1w, w1p);
  wperm_kernel<<<dim3(1600), blk, 0, stream>>>(c2w, w2p);
  wsum_kernel<<<dim3(5), dim3(64), 0, stream>>>(w1m, w2m, w1s, w2s);

  // eb = bert @ W1^T + b1  [512x288] K=768(12 chunks); emits f32 eb + split ebt
  gemm_split<1><<<dim3(5, 8, 1), blk, 0, stream>>>(
      bertb, w1b, b1l, eb, ebt, 512, 288, 12,
      0L, 768, 393216L, 0L, 768, 221184L, 0L, 288, 0L, 0, 147456L);

  ebbar_kernel<<<dim3(4), dim3(256), 0, stream>>>(eb, ebb);

  score_kernel<<<dim3(S_, B_), blk, 0, stream>>>(mem, sent, ebb, cw, ml, E, Eb, attTp);

  // P_b = eb_b^T @ eb_b  [288x288] K=128(2 chunks) -> split pb
  gemm_split<2><<<dim3(5, 5, 4), blk, 0, stream>>>(
      ebt, ebt, (const float*)nullptr, (float*)nullptr, pb, 288, 288, 2,
      (long)288 * 128, 128, 147456L, (long)288 * 128, 128, 147456L,
      0L, 0, (long)288 * 384, 384, 442368L);

  // t2 = E @ P  [128x288] K=384(6 chunks, padded)
  gemm_split<0><<<dim3(5, 2, 4), blk, 0, stream>>>(
      Eb, pb, (const float*)nullptr, t2, (short*)nullptr, 128, 288, 6,
      (long)128 * 384, 384, 196608L, (long)288 * 384, 384, 442368L,
      (long)128 * 288, 288, 0L, 0, 0L);

  g_kernel<<<dim3(S_, B_), blk, 0, stream>>>(E, t2, w1s, w2s, Gt);

  conv_tap2<true><<<dim3(2, 50, 8), blk, 0, stream>>>(w1p, Gt, attTp, c1b, y1t, (float*)nullptr);

  pool_t<<<dim3((B_ * HP_ * WP_ * 16 + 255) / 256), blk, 0, stream>>>(y1t, x2t);

  conv_tap2<false><<<dim3(1, 25, 8), blk, 0, stream>>>(w2p, x2t, (const float*)nullptr, c2b,
                                                       (short*)nullptr, y2);

  ln_kernel<<<dim3(B_ * S_ * HP_), dim3(64), 0, stream>>>(y2, lng, lnb);

  meanhp_kernel<<<dim3((B_ * S_ * WP_ + 255) / 256), blk, 0, stream>>>(y2, zb);

  // out = z @ W_out^T + b_out  [512x300] K=256(4 chunks, padded)
  gemm_split<0><<<dim3(5, 8, 1), blk, 0, stream>>>(
      zb, wob, bo, out, (short*)nullptr, 512, 300, 4,
      0L, 256, 131072L, 0L, 256, 76800L, 0L, 300, 0L, 0, 0L);

  maskout_kernel<<<dim3((B_ * S_ * NOUT_ + 255) / 256), blk, 0, stream>>>(out, ml, ign);
}

// Round 8
// 321.120 us; speedup vs baseline: 3.9565x; 1.0694x over previous
//
#include <hip/hip_runtime.h>

#define B_    4
#define S_    128
#define BERT_ 768
#define C_    49
#define C1_   50
#define M_    288
#define HP_   25
#define WP_   144
#define NOUT_ 300

typedef short bf16x8 __attribute__((ext_vector_type(8)));
typedef short short4v __attribute__((ext_vector_type(4)));
typedef float f32x4 __attribute__((ext_vector_type(4)));

static __device__ __forceinline__ short f2bf(float f) {
  unsigned u = __float_as_uint(f);
  unsigned r = (u + 0x7fffu + ((u >> 16) & 1u)) >> 16;
  return (short)r;
}
static __device__ __forceinline__ float bf2f(short v) {
  return __uint_as_float(((unsigned)(unsigned short)v) << 16);
}
static __device__ __forceinline__ unsigned cvt_pk_bf16(float lo, float hi) {
  unsigned r;
  asm("v_cvt_pk_bf16_f32 %0, %1, %2" : "=v"(r) : "v"(lo), "v"(hi));
  return r;
}

// ------------------------------------------------------------------
// cast f32 [R][Ks] -> split bf16 (hi,lo) [R][Kd], zero pad cols [Ks,Kd)
// ------------------------------------------------------------------
__global__ void cast_pad_split(const float* __restrict__ src, short* __restrict__ dst,
                               long loOff, int R, int Ks, int Kd)
{
  int idx = blockIdx.x * 256 + threadIdx.x;
  if (idx >= R * Kd) return;
  int k = idx % Kd, r = idx / Kd;
  short h = 0, l = 0;
  if (k < Ks) {
    float v = src[(long)r * Ks + k];
    h = f2bf(v);
    l = f2bf(v - bf2f(h));
  }
  dst[idx] = h;
  dst[idx + loOff] = l;
}

// ------------------------------------------------------------------
// split-bf16 MFMA GEMM (see R7 notes). Out[i,j] = sum_k A[i,k]*B[j,k] (+bias)
// ------------------------------------------------------------------
template<int OMODE>
__global__ __launch_bounds__(256) void gemm_split(
    const short* __restrict__ A, const short* __restrict__ Bm,
    const float* __restrict__ bias,
    float* __restrict__ Outf, short* __restrict__ Outb,
    int Mr, int Nc, int KH,
    long aB, int aP, long aLo,
    long bB, int bP, long bLo,
    long oB, int oP,
    long obB, int obP, long obLo)
{
  const int z = blockIdx.z;
  const int i0 = blockIdx.y * 64, j0 = blockIdx.x * 64;
  __shared__ __attribute__((aligned(16))) short As[2][64 * 64];
  __shared__ __attribute__((aligned(16))) short Bs[2][64 * 64];
  const int tid = threadIdx.x;
  const int wave = tid >> 6, lane = tid & 63;
  const int lr = lane & 15, kq = lane >> 4;
  f32x4 acc[4] = {};
  const short* Ab = A + z * aB;
  const short* Bb = Bm + z * bB;
  const bf16x8 vz = {0, 0, 0, 0, 0, 0, 0, 0};
  for (int kh = 0; kh < KH; ++kh) {
    if (kh) __syncthreads();
    for (int u = tid; u < 512; u += 256) {
      int row = u >> 3, c = u & 7;
      int gi = i0 + row;
      const short* src = &Ab[(long)gi * aP + kh * 64 + c * 8];
      bf16x8 vh = (gi < Mr) ? *(const bf16x8*)src : vz;
      bf16x8 vl = (gi < Mr) ? *(const bf16x8*)(src + aLo) : vz;
      int dst = row * 64 + ((c ^ (row & 7)) * 8);
      *(bf16x8*)&As[0][dst] = vh;
      *(bf16x8*)&As[1][dst] = vl;
    }
    for (int u = tid; u < 512; u += 256) {
      int row = u >> 3, c = u & 7;
      int gj = j0 + row;
      const short* src = &Bb[(long)gj * bP + kh * 64 + c * 8];
      bf16x8 vh = (gj < Nc) ? *(const bf16x8*)src : vz;
      bf16x8 vl = (gj < Nc) ? *(const bf16x8*)(src + bLo) : vz;
      int dst = row * 64 + ((c ^ (row & 7)) * 8);
      *(bf16x8*)&Bs[0][dst] = vh;
      *(bf16x8*)&Bs[1][dst] = vl;
    }
    __syncthreads();
#pragma unroll
    for (int ks = 0; ks < 2; ++ks) {
      const int ch = ks * 4 + kq;
      const int ar = wave * 16 + lr;
      const int ao = ar * 64 + ((ch ^ (ar & 7)) * 8);
      bf16x8 ah = *(const bf16x8*)&As[0][ao];
      bf16x8 al = *(const bf16x8*)&As[1][ao];
#pragma unroll
      for (int ni = 0; ni < 4; ++ni) {
        const int br = ni * 16 + lr;
        const int bo2 = br * 64 + ((ch ^ (br & 7)) * 8);
        bf16x8 bh = *(const bf16x8*)&Bs[0][bo2];
        bf16x8 bl = *(const bf16x8*)&Bs[1][bo2];
        acc[ni] = __builtin_amdgcn_mfma_f32_16x16x32_bf16(ah, bh, acc[ni], 0, 0, 0);
        acc[ni] = __builtin_amdgcn_mfma_f32_16x16x32_bf16(ah, bl, acc[ni], 0, 0, 0);
        acc[ni] = __builtin_amdgcn_mfma_f32_16x16x32_bf16(al, bh, acc[ni], 0, 0, 0);
      }
    }
  }
#pragma unroll
  for (int ni = 0; ni < 4; ++ni) {
    int jg = j0 + ni * 16 + lr;
    if (jg >= Nc) continue;
#pragma unroll
    for (int r = 0; r < 4; ++r) {
      int ig = i0 + wave * 16 + kq * 4 + r;
      if (ig >= Mr) continue;
      float v = acc[ni][r];
      if (bias) v += bias[jg];
      if constexpr (OMODE == 0 || OMODE == 1)
        Outf[z * oB + (long)ig * oP + jg] = v;
      if constexpr (OMODE == 1) {
        long o = ((long)((ig >> 7) * 288 + jg)) * 128 + (ig & 127);
        short h = f2bf(v);
        Outb[o] = h;
        Outb[o + obLo] = f2bf(v - bf2f(h));
      }
      if constexpr (OMODE == 2) {
        long o = z * obB + (long)ig * obP + jg;
        short h = f2bf(v);
        Outb[o] = h;
        Outb[o + obLo] = f2bf(v - bf2f(h));
      }
    }
  }
}

// ------------------------------------------------------------------
__global__ void wsum_kernel(const float* __restrict__ w1, const float* __restrict__ w2,
                            float* __restrict__ w1s, float* __restrict__ w2s)
{
  int m = blockIdx.x * 64 + threadIdx.x;
  if (m >= M_) return;
  float a = 0.f, b = 0.f;
  for (int c = 0; c < C1_; ++c) { a += w1[m * C1_ + c]; b += w2[m * C1_ + c]; }
  w1s[m] = a; w2s[m] = b;
}

__global__ void ebbar_kernel(const float* __restrict__ eb, float* __restrict__ ebb)
{
  int b = blockIdx.x;
  for (int m = threadIdx.x; m < M_; m += blockDim.x) {
    float s = 0.f;
    for (int t = 0; t < S_; ++t) s += eb[((long)(b * S_ + t)) * M_ + m];
    ebb[b * M_ + m] = s * (1.f / (float)S_);
  }
}

// ------------------------------------------------------------------
// wq[((tap*16 + chq)*128 + o)*8 + e] = bf16(w[(o*128 + chq*8+e)*25 + tap])
// ------------------------------------------------------------------
__global__ void wperm_kernel(const float* __restrict__ w, short* __restrict__ wq)
{
  int idx = blockIdx.x * 256 + threadIdx.x;
  if (idx >= 25 * 128 * 128) return;
  int e = idx & 7; int t = idx >> 3;
  int o = t & 127; t >>= 7;
  int chq = t & 15; int tap = t >> 4;
  int ch = chq * 8 + e;
  wq[idx] = f2bf(w[((long)(o * 128 + ch)) * 25 + tap]);
}

// ------------------------------------------------------------------
// fused per-(b,s): E (f32 + split bf16 padded), scores, softmaxes, top-5, att
// ------------------------------------------------------------------
__global__ __launch_bounds__(256) void score_kernel(
    const float* __restrict__ mem, const float* __restrict__ sentinel,
    const float* __restrict__ ebbar, const float* __restrict__ cw,
    const int* __restrict__ ml, float* __restrict__ E, short* __restrict__ Eb,
    float* __restrict__ attTp)
{
  const int s = blockIdx.x, b = blockIdx.y;
  const int tid = threadIdx.x, wave = tid >> 6, lane = tid & 63;
  __shared__ float sEb[M_];
  __shared__ float sE[4][M_];
  __shared__ float sScore[C1_];
  for (int m = tid; m < M_; m += 256) sEb[m] = ebbar[b * M_ + m];
  __syncthreads();

  const float* base = mem + ((long)(b * S_ + s)) * C_ * M_;
  float Ereg[5] = {0.f, 0.f, 0.f, 0.f, 0.f};
  for (int jj = wave; jj < C_; jj += 4) {
    const float* row = base + (long)jj * M_;
    float d = 0.f;
#pragma unroll
    for (int q = 0; q < 5; ++q) {
      int m = lane + q * 64;
      if (m < M_) { float v = row[m]; Ereg[q] += v; d = fmaf(v, sEb[m], d); }
    }
#pragma unroll
    for (int off = 32; off; off >>= 1) d += __shfl_down(d, off, 64);
    if (lane == 0) sScore[jj + 1] = d;
  }
#pragma unroll
  for (int q = 0; q < 5; ++q) { int m = lane + q * 64; if (m < M_) sE[wave][m] = Ereg[q]; }
  __syncthreads();

  if (wave == 0) {
    float d0 = 0.f;
    for (int m = lane; m < M_; m += 64) d0 = fmaf(sentinel[m], sEb[m], d0);
#pragma unroll
    for (int off = 32; off; off >>= 1) d0 += __shfl_down(d0, off, 64);
    if (lane == 0) sScore[0] = d0;
  }
  for (int m = tid; m < M_; m += 256) {
    float ev = sentinel[m] + sE[0][m] + sE[1][m] + sE[2][m] + sE[3][m];
    E[((long)(b * S_ + s)) * M_ + m] = ev;
    short h = f2bf(ev);
    Eb[((long)(b * S_ + s)) * 384 + m] = h;
    Eb[196608 + ((long)(b * S_ + s)) * 384 + m] = f2bf(ev - bf2f(h));
  }
  __syncthreads();

  if (wave == 0) {
    const int mlv = ml[b * S_ + s];
    float sc = (lane < C1_) ? sScore[lane] : 0.f;
    if (lane < C1_ && mlv < lane) sc -= 1e6f;
    float mx = (lane < C1_) ? sc : -3.0e38f;
#pragma unroll
    for (int off = 32; off; off >>= 1) mx = fmaxf(mx, __shfl_xor(mx, off, 64));
    float e1 = (lane < C1_) ? __expf(sc - mx) : 0.f;
    float s1 = e1;
#pragma unroll
    for (int off = 32; off; off >>= 1) s1 += __shfl_xor(s1, off, 64);
    float p1 = e1 / s1;
    float cv = 0.f;
    if (lane >= 1 && lane < C1_) cv = cw[((long)(b * S_ + s)) * C_ + lane - 1];
    float mx2 = (lane < C1_) ? cv : -3.0e38f;
#pragma unroll
    for (int off = 32; off; off >>= 1) mx2 = fmaxf(mx2, __shfl_xor(mx2, off, 64));
    float e2 = (lane < C1_) ? __expf(cv - mx2) : 0.f;
    float s2 = e2;
#pragma unroll
    for (int off = 32; off; off >>= 1) s2 += __shfl_xor(s2, off, 64);
    float p2 = e2 / s2;
    float scm = 0.7f * p1 + 0.3f * p2;
    bool active = (lane < C1_);
    float thr = 0.f;
    for (int r = 0; r < 5; ++r) {
      float v = active ? scm : -3.0e38f;
      int idx = lane;
#pragma unroll
      for (int off = 32; off; off >>= 1) {
        float ov = __shfl_xor(v, off, 64);
        int oi = __shfl_xor(idx, off, 64);
        if (ov > v || (ov == v && oi < idx)) { v = ov; idx = oi; }
      }
      thr = v;
      if (lane == idx) active = false;
    }
    float kept = (lane < C1_ && scm >= thr) ? scm : 0.f;
    float mx3 = (lane < C1_) ? kept : -3.0e38f;
#pragma unroll
    for (int off = 32; off; off >>= 1) mx3 = fmaxf(mx3, __shfl_xor(mx3, off, 64));
    float e3 = (lane < C1_) ? __expf(kept - mx3) : 0.f;
    float s3 = e3;
#pragma unroll
    for (int off = 32; off; off >>= 1) s3 += __shfl_xor(s3, off, 64);
    if (lane < C1_) attTp[((long)(b * 54) + lane + 2) * 128 + s] = e3 / s3;
  }
}

// ------------------------------------------------------------------
// G[b,s,n] -> bf16 transposed into Gt[b][n+2][s]
// ------------------------------------------------------------------
__global__ __launch_bounds__(256) void g_kernel(
    const float* __restrict__ E, const float* __restrict__ t2,
    const float* __restrict__ w1s, const float* __restrict__ w2s,
    short* __restrict__ Gt)
{
  const int s = blockIdx.x, b = blockIdx.y;
  __shared__ float sE[M_], s1[M_], s2[M_];
  const int tid = threadIdx.x;
  const long base = (long)(b * S_ + s) * M_;
  for (int m = tid; m < M_; m += 256) { sE[m] = E[base + m]; s1[m] = w1s[m]; s2[m] = w2s[m]; }
  __syncthreads();
  for (int n = tid; n < M_; n += 256) {
    float a = sE[n];
    float c = t2[base + n];
    float num = 0.f, den = 0.f;
#pragma unroll 4
    for (int m = 0; m < M_; ++m) {
      float z = fmaf(s1[m], a, s2[m] * c);
      float u = __expf(2.f * z);
      float th = 1.f - 2.f / (u + 1.f);
      float e = __expf(th);
      num = fmaf(sE[m], e, num);
      den += e;
    }
    Gt[((long)(b * 292) + 2 + n) * 128 + s] = f2bf(num / den);
  }
}

// ------------------------------------------------------------------
// Unified tap-GEMM conv v3: BM=128 (M_rep=2/wave), split-array LDS B
// (two 64-short-row arrays -> R4's zero-conflict geometry).
// C1: BN=144 (ROWS=148), grid (2,50,4). C2: BN=48 (ROWS=52), grid (3,25,4).
// ------------------------------------------------------------------
template<bool C1>
__global__ __launch_bounds__(256) void conv_tap3(
    const short* __restrict__ wq,
    const short* __restrict__ act,
    const float* __restrict__ attp,
    const float* __restrict__ bias,
    short* __restrict__ y1t,
    float* __restrict__ y2)
{
  constexpr int NREP = C1 ? 9 : 3;
  constexpr int ROWS = C1 ? 148 : 52;
  const int b = blockIdx.z;
  const int hrow = blockIdx.y;
  const int w0 = blockIdx.x * (C1 ? 144 : 48);
  __shared__ __attribute__((aligned(16))) short Bs[2][ROWS * 64];
  const int tid = threadIdx.x;
  const int wave = tid >> 6, lane = tid & 63;
  const int lr = lane & 15, kq = lane >> 4;
  f32x4 acc[2][NREP] = {};

  for (int dh = 0; dh < 5; ++dh) {
    if (dh) __syncthreads();
    if constexpr (C1) {
      const short* src = act + ((long)(b * 292) + w0) * 128;
      const float* arow = attp + ((long)(b * 54) + hrow + dh) * 128;
      for (int u = tid; u < ROWS * 16; u += 256) {
        int row = u >> 4, c = u & 15;
        bf16x8 v = *(const bf16x8*)&src[row * 128 + c * 8];
        float4 a0 = *(const float4*)&arow[c * 8];
        float4 a1 = *(const float4*)&arow[c * 8 + 4];
        union { unsigned u4[4]; bf16x8 v; } pk;
        pk.u4[0] = cvt_pk_bf16(bf2f(v[0]) * a0.x, bf2f(v[1]) * a0.y);
        pk.u4[1] = cvt_pk_bf16(bf2f(v[2]) * a0.z, bf2f(v[3]) * a0.w);
        pk.u4[2] = cvt_pk_bf16(bf2f(v[4]) * a1.x, bf2f(v[5]) * a1.y);
        pk.u4[3] = cvt_pk_bf16(bf2f(v[6]) * a1.z, bf2f(v[7]) * a1.w);
        *(bf16x8*)&Bs[c >> 3][row * 64 + (((c & 7) ^ (row & 7)) * 8)] = pk.v;
      }
    } else {
      const short* src = act + (((long)(b * 29) + hrow + dh) * 148 + w0) * 128;
      for (int u = tid; u < ROWS * 16; u += 256) {
        int row = u >> 4, c = u & 15;
        bf16x8 v = *(const bf16x8*)&src[row * 128 + c * 8];
        *(bf16x8*)&Bs[c >> 3][row * 64 + (((c & 7) ^ (row & 7)) * 8)] = v;
      }
    }
    __syncthreads();
    for (int dw = 0; dw < 5; ++dw) {
      const int tap = dh * 5 + dw;
#pragma unroll
      for (int ks = 0; ks < 4; ++ks) {
        const int ch = ks * 4 + kq;
        const long abase = ((long)(tap * 16 + ch)) * 128 + wave * 32 + lr;
        bf16x8 af0 = *(const bf16x8*)&wq[abase * 8];
        bf16x8 af1 = *(const bf16x8*)&wq[(abase + 16) * 8];
        const int arr = ch >> 3, cc = ch & 7;
#pragma unroll
        for (int ni = 0; ni < NREP; ++ni) {
          const int row = lr + ni * 16 + dw;
          bf16x8 bfr = *(const bf16x8*)&Bs[arr][row * 64 + ((cc ^ (row & 7)) * 8)];
          acc[0][ni] = __builtin_amdgcn_mfma_f32_16x16x32_bf16(af0, bfr, acc[0][ni], 0, 0, 0);
          acc[1][ni] = __builtin_amdgcn_mfma_f32_16x16x32_bf16(af1, bfr, acc[1][ni], 0, 0, 0);
        }
      }
    }
  }
#pragma unroll
  for (int mi = 0; mi < 2; ++mi) {
    const int og = wave * 32 + mi * 16 + kq * 4;
    if constexpr (C1) {
#pragma unroll
      for (int ni = 0; ni < NREP; ++ni) {
        int wg = w0 + ni * 16 + lr;
        short4v pk;
#pragma unroll
        for (int r = 0; r < 4; ++r)
          pk[r] = f2bf(fmaxf(acc[mi][ni][r] + bias[og + r], 0.f));
        *(short4v*)&y1t[(((long)(b * 50) + hrow) * 288 + wg) * 128 + og] = pk;
      }
    } else {
#pragma unroll
      for (int ni = 0; ni < NREP; ++ni) {
        int wg = w0 + ni * 16 + lr;
#pragma unroll
        for (int r = 0; r < 4; ++r)
          y2[((long)(b * 128) + og + r) * 3600 + hrow * 144 + wg] =
              fmaxf(acc[mi][ni][r] + bias[og + r], 0.f);
      }
    }
  }
}

// ------------------------------------------------------------------
__global__ void pool_t(const short* __restrict__ y1t, short* __restrict__ x2t)
{
  int idx = blockIdx.x * 256 + threadIdx.x;
  if (idx >= B_ * HP_ * WP_ * 16) return;
  int c8 = idx & 15; int t = idx >> 4;
  int wp = t % WP_; t /= WP_;
  int hp = t % HP_; int b = t / HP_;
  const short* base = y1t + (((long)(b * 50 + 2 * hp) * 288) + 2 * wp) * 128 + c8 * 8;
  bf16x8 v00 = *(const bf16x8*)&base[0];
  bf16x8 v01 = *(const bf16x8*)&base[128];
  bf16x8 v10 = *(const bf16x8*)&base[288 * 128];
  bf16x8 v11 = *(const bf16x8*)&base[288 * 128 + 128];
  bf16x8 r;
#pragma unroll
  for (int e = 0; e < 8; ++e)
    r[e] = f2bf(fmaxf(fmaxf(bf2f(v00[e]), bf2f(v01[e])), fmaxf(bf2f(v10[e]), bf2f(v11[e]))));
  *(bf16x8*)&x2t[(((long)(b * 29) + hp + 2) * 148 + wp + 2) * 128 + c8 * 8] = r;
}

// ------------------------------------------------------------------
__global__ __launch_bounds__(64) void ln_kernel(float* __restrict__ y2,
                                                const float* __restrict__ g,
                                                const float* __restrict__ bb)
{
  float* p = y2 + (long)blockIdx.x * WP_;
  const int lane = threadIdx.x;
  float v[3]; float s = 0.f, ss = 0.f;
#pragma unroll
  for (int q = 0; q < 3; ++q) {
    int wp = lane + q * 64;
    float x = (wp < WP_) ? p[wp] : 0.f;
    v[q] = x; s += x; ss = fmaf(x, x, ss);
  }
#pragma unroll
  for (int off = 32; off; off >>= 1) { s += __shfl_xor(s, off, 64); ss += __shfl_xor(ss, off, 64); }
  float mu = s * (1.f / (float)WP_);
  float var = ss * (1.f / (float)WP_) - mu * mu;
  float inv = rsqrtf(var + 1e-5f);
#pragma unroll
  for (int q = 0; q < 3; ++q) {
    int wp = lane + q * 64;
    if (wp < WP_) p[wp] = (v[q] - mu) * inv * g[wp] + bb[wp];
  }
}

// mean over hp -> split bf16 zb[512][256] (pad zeroed by memset)
__global__ void meanhp_kernel(const float* __restrict__ y2, short* __restrict__ zb)
{
  int idx = blockIdx.x * 256 + threadIdx.x;
  if (idx >= B_ * S_ * WP_) return;
  int wp = idx % WP_; int t = idx / WP_;
  const float* p = y2 + (long)t * HP_ * WP_ + wp;
  float s = 0.f;
  for (int hp = 0; hp < HP_; ++hp) s += p[hp * WP_];
  float v = s * (1.f / (float)HP_);
  short h = f2bf(v);
  zb[(long)t * 256 + wp] = h;
  zb[131072 + (long)t * 256 + wp] = f2bf(v - bf2f(h));
}

__global__ void maskout_kernel(float* __restrict__ out, const int* __restrict__ ml,
                               const int* __restrict__ ign)
{
  int idx = blockIdx.x * 256 + threadIdx.x;
  if (idx >= B_ * S_ * NOUT_) return;
  if (ign[0] == 0) return;
  if (ml[idx / NOUT_] <= 0) out[idx] = 0.f;
}

// ------------------------------------------------------------------
extern "C" void kernel_launch(void* const* d_in, const int* in_sizes, int n_in,
                              void* d_out, int out_size, void* d_ws, size_t ws_size,
                              hipStream_t stream)
{
  const float* bert = (const float*)d_in[0];
  const float* mem  = (const float*)d_in[1];
  const int*   ml   = (const int*)d_in[2];
  const float* cw   = (const float*)d_in[3];
  const int*   ign  = (const int*)d_in[4];
  const float* W1   = (const float*)d_in[6];
  const float* b1l  = (const float*)d_in[7];
  const float* sent = (const float*)d_in[8];
  const float* w1m  = (const float*)d_in[9];
  const float* w2m  = (const float*)d_in[10];
  const float* c1w  = (const float*)d_in[11];
  const float* c1b  = (const float*)d_in[12];
  const float* c2w  = (const float*)d_in[13];
  const float* c2b  = (const float*)d_in[14];
  const float* lng  = (const float*)d_in[15];
  const float* lnb  = (const float*)d_in[16];
  const float* Wo   = (const float*)d_in[17];
  const float* bo   = (const float*)d_in[18];
  float* out = (float*)d_out;

  float* ws    = (float*)d_ws;
  float* eb    = ws;                    // 147456
  float* ebb   = eb + 147456;           // 1152
  float* E     = ebb + 1152;            // 147456
  float* t2    = E + 147456;            // 147456
  float* attTp = t2 + 147456;           // 27648
  float* w1s   = attTp + 27648;         // 288
  float* w2s   = w1s + 288;             // 288
  float* y2    = w2s + 288;             // 1843200
  short* Gt    = (short*)(y2 + 1843200);    // 149504
  short* w1p   = Gt + 149504;               // 409600
  short* w2p   = w1p + 409600;              // 409600
  short* y1t   = w2p + 409600;              // 7372800
  short* x2t   = y1t + 7372800;             // 2197504
  short* bertb = x2t + 2197504;             // 786432
  short* w1b   = bertb + 786432;            // 442368
  short* wob   = w1b + 442368;              // 153600
  short* ebt   = wob + 153600;              // 294912
  short* Eb    = ebt + 294912;              // 393216
  short* pb    = Eb + 393216;               // 884736
  short* zb    = pb + 884736;               // 262144
  // total ~37 MB

  dim3 blk(256);

  hipMemsetAsync(Gt, 0, (size_t)149504 * 2, stream);
  hipMemsetAsync(x2t, 0, (size_t)2197504 * 2, stream);
  hipMemsetAsync(attTp, 0, (size_t)27648 * 4, stream);
  hipMemsetAsync(Eb, 0, (size_t)393216 * 2, stream);
  hipMemsetAsync(pb, 0, (size_t)884736 * 2, stream);
  hipMemsetAsync(zb, 0, (size_t)262144 * 2, stream);

  cast_pad_split<<<dim3(1536), blk, 0, stream>>>(bert, bertb, 393216L, 512, 768, 768);
  cast_pad_split<<<dim3(864), blk, 0, stream>>>(W1, w1b, 221184L, 288, 768, 768);
  cast_pad_split<<<dim3(300), blk, 0, stream>>>(Wo, wob, 76800L, 300, 144, 256);
  wperm_kernel<<<dim3(1600), blk, 0, stream>>>(c1w, w1p);
  wperm_kernel<<<dim3(1600), blk, 0, stream>>>(c2w, w2p);
  wsum_kernel<<<dim3(5), dim3(64), 0, stream>>>(w1m, w2m, w1s, w2s);

  // eb = bert @ W1^T + b1  [512x288] K=768; emits f32 eb + split ebt
  gemm_split<1><<<dim3(5, 8, 1), blk, 0, stream>>>(
      bertb, w1b, b1l, eb, ebt, 512, 288, 12,
      0L, 768, 393216L, 0L, 768, 221184L, 0L, 288, 0L, 0, 147456L);

  ebbar_kernel<<<dim3(4), dim3(256), 0, stream>>>(eb, ebb);

  score_kernel<<<dim3(S_, B_), blk, 0, stream>>>(mem, sent, ebb, cw, ml, E, Eb, attTp);

  // P_b = eb_b^T @ eb_b  [288x288] K=128 -> split pb
  gemm_split<2><<<dim3(5, 5, 4), blk, 0, stream>>>(
      ebt, ebt, (const float*)nullptr, (float*)nullptr, pb, 288, 288, 2,
      (long)288 * 128, 128, 147456L, (long)288 * 128, 128, 147456L,
      0L, 0, (long)288 * 384, 384, 442368L);

  // t2 = E @ P  [128x288] K=384(pad)
  gemm_split<0><<<dim3(5, 2, 4), blk, 0, stream>>>(
      Eb, pb, (const float*)nullptr, t2, (short*)nullptr, 128, 288, 6,
      (long)128 * 384, 384, 196608L, (long)288 * 384, 384, 442368L,
      (long)128 * 288, 288, 0L, 0, 0L);

  g_kernel<<<dim3(S_, B_), blk, 0, stream>>>(E, t2, w1s, w2s, Gt);

  // conv1: BM=128, grid (2 wtiles, 50 h, 4 b)
  conv_tap3<true><<<dim3(2, 50, 4), blk, 0, stream>>>(w1p, Gt, attTp, c1b, y1t, (float*)nullptr);

  pool_t<<<dim3((B_ * HP_ * WP_ * 16 + 255) / 256), blk, 0, stream>>>(y1t, x2t);

  // conv2: BM=128, BN=48, grid (3 wtiles, 25 hp, 4 b)
  conv_tap3<false><<<dim3(3, 25, 4), blk, 0, stream>>>(w2p, x2t, (const float*)nullptr, c2b,
                                                       (short*)nullptr, y2);

  ln_kernel<<<dim3(B_ * S_ * HP_), dim3(64), 0, stream>>>(y2, lng, lnb);

  meanhp_kernel<<<dim3((B_ * S_ * WP_ + 255) / 256), blk, 0, stream>>>(y2, zb);

  // out = z @ W_out^T + b_out  [512x300] K=256(pad)
  gemm_split<0><<<dim3(5, 8, 1), blk, 0, stream>>>(
      zb, wob, bo, out, (short*)nullptr, 512, 300, 4,
      0L, 256, 131072L, 0L, 256, 76800L, 0L, 300, 0L, 0, 0L);

  maskout_kernel<<<dim3((B_ * S_ * NOUT_ + 255) / 256), blk, 0, stream>>>(out, ml, ign);
}

// Round 9
// 269.212 us; speedup vs baseline: 4.7194x; 1.1928x over previous
//
#include <hip/hip_runtime.h>

#define B_    4
#define S_    128
#define BERT_ 768
#define C_    49
#define C1_   50
#define M_    288
#define HP_   25
#define WP_   144
#define NOUT_ 300

typedef short bf16x8 __attribute__((ext_vector_type(8)));
typedef short short4v __attribute__((ext_vector_type(4)));
typedef float f32x4 __attribute__((ext_vector_type(4)));

static __device__ __forceinline__ short f2bf(float f) {
  unsigned u = __float_as_uint(f);
  unsigned r = (u + 0x7fffu + ((u >> 16) & 1u)) >> 16;
  return (short)r;
}
static __device__ __forceinline__ float bf2f(short v) {
  return __uint_as_float(((unsigned)(unsigned short)v) << 16);
}
static __device__ __forceinline__ unsigned cvt_pk_bf16(float lo, float hi) {
  unsigned r;
  asm("v_cvt_pk_bf16_f32 %0, %1, %2" : "=v"(r) : "v"(lo), "v"(hi));
  return r;
}

// ------------------------------------------------------------------
// cast f32 [R][Ks] -> split bf16 (hi,lo) [R][Kd], zero pad cols [Ks,Kd)
// ------------------------------------------------------------------
__global__ void cast_pad_split(const float* __restrict__ src, short* __restrict__ dst,
                               long loOff, int R, int Ks, int Kd)
{
  int idx = blockIdx.x * 256 + threadIdx.x;
  if (idx >= R * Kd) return;
  int k = idx % Kd, r = idx / Kd;
  short h = 0, l = 0;
  if (k < Ks) {
    float v = src[(long)r * Ks + k];
    h = f2bf(v);
    l = f2bf(v - bf2f(h));
  }
  dst[idx] = h;
  dst[idx + loOff] = l;
}

// ------------------------------------------------------------------
// split-bf16 MFMA GEMM. Out[i,j] = sum_k A[i,k]*B[j,k] (+bias)
// ------------------------------------------------------------------
template<int OMODE>
__global__ __launch_bounds__(256) void gemm_split(
    const short* __restrict__ A, const short* __restrict__ Bm,
    const float* __restrict__ bias,
    float* __restrict__ Outf, short* __restrict__ Outb,
    int Mr, int Nc, int KH,
    long aB, int aP, long aLo,
    long bB, int bP, long bLo,
    long oB, int oP,
    long obB, int obP, long obLo)
{
  const int z = blockIdx.z;
  const int i0 = blockIdx.y * 64, j0 = blockIdx.x * 64;
  __shared__ __attribute__((aligned(16))) short As[2][64 * 64];
  __shared__ __attribute__((aligned(16))) short Bs[2][64 * 64];
  const int tid = threadIdx.x;
  const int wave = tid >> 6, lane = tid & 63;
  const int lr = lane & 15, kq = lane >> 4;
  f32x4 acc[4] = {};
  const short* Ab = A + z * aB;
  const short* Bb = Bm + z * bB;
  const bf16x8 vz = {0, 0, 0, 0, 0, 0, 0, 0};
  for (int kh = 0; kh < KH; ++kh) {
    if (kh) __syncthreads();
    for (int u = tid; u < 512; u += 256) {
      int row = u >> 3, c = u & 7;
      int gi = i0 + row;
      const short* src = &Ab[(long)gi * aP + kh * 64 + c * 8];
      bf16x8 vh = (gi < Mr) ? *(const bf16x8*)src : vz;
      bf16x8 vl = (gi < Mr) ? *(const bf16x8*)(src + aLo) : vz;
      int dst = row * 64 + ((c ^ (row & 7)) * 8);
      *(bf16x8*)&As[0][dst] = vh;
      *(bf16x8*)&As[1][dst] = vl;
    }
    for (int u = tid; u < 512; u += 256) {
      int row = u >> 3, c = u & 7;
      int gj = j0 + row;
      const short* src = &Bb[(long)gj * bP + kh * 64 + c * 8];
      bf16x8 vh = (gj < Nc) ? *(const bf16x8*)src : vz;
      bf16x8 vl = (gj < Nc) ? *(const bf16x8*)(src + bLo) : vz;
      int dst = row * 64 + ((c ^ (row & 7)) * 8);
      *(bf16x8*)&Bs[0][dst] = vh;
      *(bf16x8*)&Bs[1][dst] = vl;
    }
    __syncthreads();
#pragma unroll
    for (int ks = 0; ks < 2; ++ks) {
      const int ch = ks * 4 + kq;
      const int ar = wave * 16 + lr;
      const int ao = ar * 64 + ((ch ^ (ar & 7)) * 8);
      bf16x8 ah = *(const bf16x8*)&As[0][ao];
      bf16x8 al = *(const bf16x8*)&As[1][ao];
#pragma unroll
      for (int ni = 0; ni < 4; ++ni) {
        const int br = ni * 16 + lr;
        const int bo2 = br * 64 + ((ch ^ (br & 7)) * 8);
        bf16x8 bh = *(const bf16x8*)&Bs[0][bo2];
        bf16x8 bl = *(const bf16x8*)&Bs[1][bo2];
        acc[ni] = __builtin_amdgcn_mfma_f32_16x16x32_bf16(ah, bh, acc[ni], 0, 0, 0);
        acc[ni] = __builtin_amdgcn_mfma_f32_16x16x32_bf16(ah, bl, acc[ni], 0, 0, 0);
        acc[ni] = __builtin_amdgcn_mfma_f32_16x16x32_bf16(al, bh, acc[ni], 0, 0, 0);
      }
    }
  }
#pragma unroll
  for (int ni = 0; ni < 4; ++ni) {
    int jg = j0 + ni * 16 + lr;
    if (jg >= Nc) continue;
#pragma unroll
    for (int r = 0; r < 4; ++r) {
      int ig = i0 + wave * 16 + kq * 4 + r;
      if (ig >= Mr) continue;
      float v = acc[ni][r];
      if (bias) v += bias[jg];
      if constexpr (OMODE == 0 || OMODE == 1)
        Outf[z * oB + (long)ig * oP + jg] = v;
      if constexpr (OMODE == 1) {
        long o = ((long)((ig >> 7) * 288 + jg)) * 128 + (ig & 127);
        short h = f2bf(v);
        Outb[o] = h;
        Outb[o + obLo] = f2bf(v - bf2f(h));
      }
      if constexpr (OMODE == 2) {
        long o = z * obB + (long)ig * obP + jg;
        short h = f2bf(v);
        Outb[o] = h;
        Outb[o + obLo] = f2bf(v - bf2f(h));
      }
    }
  }
}

// ------------------------------------------------------------------
__global__ void wsum_kernel(const float* __restrict__ w1, const float* __restrict__ w2,
                            float* __restrict__ w1s, float* __restrict__ w2s)
{
  int m = blockIdx.x * 64 + threadIdx.x;
  if (m >= M_) return;
  float a = 0.f, b = 0.f;
  for (int c = 0; c < C1_; ++c) { a += w1[m * C1_ + c]; b += w2[m * C1_ + c]; }
  w1s[m] = a; w2s[m] = b;
}

__global__ void ebbar_kernel(const float* __restrict__ eb, float* __restrict__ ebb)
{
  int b = blockIdx.x;
  for (int m = threadIdx.x; m < M_; m += blockDim.x) {
    float s = 0.f;
    for (int t = 0; t < S_; ++t) s += eb[((long)(b * S_ + t)) * M_ + m];
    ebb[b * M_ + m] = s * (1.f / (float)S_);
  }
}

// ------------------------------------------------------------------
// wq[((tap*16 + chq)*128 + o)*8 + e] = bf16(w[(o*128 + chq*8+e)*25 + tap])
// ------------------------------------------------------------------
__global__ void wperm_kernel(const float* __restrict__ w, short* __restrict__ wq)
{
  int idx = blockIdx.x * 256 + threadIdx.x;
  if (idx >= 25 * 128 * 128) return;
  int e = idx & 7; int t = idx >> 3;
  int o = t & 127; t >>= 7;
  int chq = t & 15; int tap = t >> 4;
  int ch = chq * 8 + e;
  wq[idx] = f2bf(w[((long)(o * 128 + ch)) * 25 + tap]);
}

// ------------------------------------------------------------------
// fused per-(b,s): E (f32 + split bf16 padded), scores, softmaxes, top-5, att
// ------------------------------------------------------------------
__global__ __launch_bounds__(256) void score_kernel(
    const float* __restrict__ mem, const float* __restrict__ sentinel,
    const float* __restrict__ ebbar, const float* __restrict__ cw,
    const int* __restrict__ ml, float* __restrict__ E, short* __restrict__ Eb,
    float* __restrict__ attTp)
{
  const int s = blockIdx.x, b = blockIdx.y;
  const int tid = threadIdx.x, wave = tid >> 6, lane = tid & 63;
  __shared__ float sEb[M_];
  __shared__ float sE[4][M_];
  __shared__ float sScore[C1_];
  for (int m = tid; m < M_; m += 256) sEb[m] = ebbar[b * M_ + m];
  __syncthreads();

  const float* base = mem + ((long)(b * S_ + s)) * C_ * M_;
  float Ereg[5] = {0.f, 0.f, 0.f, 0.f, 0.f};
  for (int jj = wave; jj < C_; jj += 4) {
    const float* row = base + (long)jj * M_;
    float d = 0.f;
#pragma unroll
    for (int q = 0; q < 5; ++q) {
      int m = lane + q * 64;
      if (m < M_) { float v = row[m]; Ereg[q] += v; d = fmaf(v, sEb[m], d); }
    }
#pragma unroll
    for (int off = 32; off; off >>= 1) d += __shfl_down(d, off, 64);
    if (lane == 0) sScore[jj + 1] = d;
  }
#pragma unroll
  for (int q = 0; q < 5; ++q) { int m = lane + q * 64; if (m < M_) sE[wave][m] = Ereg[q]; }
  __syncthreads();

  if (wave == 0) {
    float d0 = 0.f;
    for (int m = lane; m < M_; m += 64) d0 = fmaf(sentinel[m], sEb[m], d0);
#pragma unroll
    for (int off = 32; off; off >>= 1) d0 += __shfl_down(d0, off, 64);
    if (lane == 0) sScore[0] = d0;
  }
  for (int m = tid; m < M_; m += 256) {
    float ev = sentinel[m] + sE[0][m] + sE[1][m] + sE[2][m] + sE[3][m];
    E[((long)(b * S_ + s)) * M_ + m] = ev;
    short h = f2bf(ev);
    Eb[((long)(b * S_ + s)) * 384 + m] = h;
    Eb[196608 + ((long)(b * S_ + s)) * 384 + m] = f2bf(ev - bf2f(h));
  }
  __syncthreads();

  if (wave == 0) {
    const int mlv = ml[b * S_ + s];
    float sc = (lane < C1_) ? sScore[lane] : 0.f;
    if (lane < C1_ && mlv < lane) sc -= 1e6f;
    float mx = (lane < C1_) ? sc : -3.0e38f;
#pragma unroll
    for (int off = 32; off; off >>= 1) mx = fmaxf(mx, __shfl_xor(mx, off, 64));
    float e1 = (lane < C1_) ? __expf(sc - mx) : 0.f;
    float s1 = e1;
#pragma unroll
    for (int off = 32; off; off >>= 1) s1 += __shfl_xor(s1, off, 64);
    float p1 = e1 / s1;
    float cv = 0.f;
    if (lane >= 1 && lane < C1_) cv = cw[((long)(b * S_ + s)) * C_ + lane - 1];
    float mx2 = (lane < C1_) ? cv : -3.0e38f;
#pragma unroll
    for (int off = 32; off; off >>= 1) mx2 = fmaxf(mx2, __shfl_xor(mx2, off, 64));
    float e2 = (lane < C1_) ? __expf(cv - mx2) : 0.f;
    float s2 = e2;
#pragma unroll
    for (int off = 32; off; off >>= 1) s2 += __shfl_xor(s2, off, 64);
    float p2 = e2 / s2;
    float scm = 0.7f * p1 + 0.3f * p2;
    bool active = (lane < C1_);
    float thr = 0.f;
    for (int r = 0; r < 5; ++r) {
      float v = active ? scm : -3.0e38f;
      int idx = lane;
#pragma unroll
      for (int off = 32; off; off >>= 1) {
        float ov = __shfl_xor(v, off, 64);
        int oi = __shfl_xor(idx, off, 64);
        if (ov > v || (ov == v && oi < idx)) { v = ov; idx = oi; }
      }
      thr = v;
      if (lane == idx) active = false;
    }
    float kept = (lane < C1_ && scm >= thr) ? scm : 0.f;
    float mx3 = (lane < C1_) ? kept : -3.0e38f;
#pragma unroll
    for (int off = 32; off; off >>= 1) mx3 = fmaxf(mx3, __shfl_xor(mx3, off, 64));
    float e3 = (lane < C1_) ? __expf(kept - mx3) : 0.f;
    float s3 = e3;
#pragma unroll
    for (int off = 32; off; off >>= 1) s3 += __shfl_xor(s3, off, 64);
    if (lane < C1_) attTp[((long)(b * 54) + lane + 2) * 128 + s] = e3 / s3;
  }
}

// ------------------------------------------------------------------
// G[b,s,n] -> bf16 transposed into Gt[b][n+2][s]
// ------------------------------------------------------------------
__global__ __launch_bounds__(256) void g_kernel(
    const float* __restrict__ E, const float* __restrict__ t2,
    const float* __restrict__ w1s, const float* __restrict__ w2s,
    short* __restrict__ Gt)
{
  const int s = blockIdx.x, b = blockIdx.y;
  __shared__ float sE[M_], s1[M_], s2[M_];
  const int tid = threadIdx.x;
  const long base = (long)(b * S_ + s) * M_;
  for (int m = tid; m < M_; m += 256) { sE[m] = E[base + m]; s1[m] = w1s[m]; s2[m] = w2s[m]; }
  __syncthreads();
  for (int n = tid; n < M_; n += 256) {
    float a = sE[n];
    float c = t2[base + n];
    float num = 0.f, den = 0.f;
#pragma unroll 4
    for (int m = 0; m < M_; ++m) {
      float z = fmaf(s1[m], a, s2[m] * c);
      float u = __expf(2.f * z);
      float th = 1.f - 2.f / (u + 1.f);
      float e = __expf(th);
      num = fmaf(sE[m], e, num);
      den += e;
    }
    Gt[((long)(b * 292) + 2 + n) * 128 + s] = f2bf(num / den);
  }
}

// ------------------------------------------------------------------
// conv1 stage A: AWq[(b*50+h)*80 + c][o][8] = sum_dh w1q[(dh*5+dw)*16+chq][o][8]
//                 * att[b][i=chq*8+e][h+dh-2]   (c = dw*16+chq)
// grid (2 halves of c, 50 h, 4 b)
// ------------------------------------------------------------------
__global__ __launch_bounds__(256) void conv1_aw(
    const short* __restrict__ w1q, const float* __restrict__ attp,
    short* __restrict__ AWq)
{
  const int b = blockIdx.z, h = blockIdx.y, half = blockIdx.x;
  __shared__ float sAtt[5][128];
  const int tid = threadIdx.x;
  for (int u = tid; u < 640; u += 256)
    sAtt[u >> 7][u & 127] = attp[((long)(b * 54) + h + (u >> 7)) * 128 + (u & 127)];
  __syncthreads();
  const long obase = ((long)(b * 50 + h) * 80) * 1024;
  for (int u = tid; u < 5120; u += 256) {
    int c = half * 40 + (u >> 7);
    int o = u & 127;
    int dw = c / 16, chq = c & 15;
    float acc[8] = {};
#pragma unroll
    for (int dh = 0; dh < 5; ++dh) {
      bf16x8 wv = *(const bf16x8*)&w1q[(((long)((dh * 5 + dw) * 16 + chq)) * 128 + o) * 8];
      const float* ar = &sAtt[dh][chq * 8];
#pragma unroll
      for (int e = 0; e < 8; ++e) acc[e] = fmaf(bf2f(wv[e]), ar[e], acc[e]);
    }
    union { unsigned u4[4]; bf16x8 v; } pk;
    pk.u4[0] = cvt_pk_bf16(acc[0], acc[1]);
    pk.u4[1] = cvt_pk_bf16(acc[2], acc[3]);
    pk.u4[2] = cvt_pk_bf16(acc[4], acc[5]);
    pk.u4[3] = cvt_pk_bf16(acc[6], acc[7]);
    *(bf16x8*)&AWq[obase + (long)c * 1024 + o * 8] = pk.v;
  }
}

// ------------------------------------------------------------------
// conv1 stage B: per (b,h) GEMM over K=640 (dw,i). BM=128, BN=144.
// B (Gt rows) staged ONCE; A-frags from AWq global (coalesced, L2-hot).
// grid (2 wtiles, 50 h, 4 b)
// ------------------------------------------------------------------
__global__ __launch_bounds__(256) void conv1_mfma(
    const short* __restrict__ AWq, const short* __restrict__ Gt,
    const float* __restrict__ bias, short* __restrict__ y1t)
{
  const int b = blockIdx.z, hrow = blockIdx.y;
  const int w0 = blockIdx.x * 144;
  __shared__ __attribute__((aligned(16))) short Bs[2][148 * 64];
  const int tid = threadIdx.x;
  const int wave = tid >> 6, lane = tid & 63;
  const int lr = lane & 15, kq = lane >> 4;
  f32x4 acc[2][9] = {};

  const short* src = Gt + ((long)(b * 292) + w0) * 128;
  for (int u = tid; u < 2368; u += 256) {
    int row = u >> 4, c = u & 15;
    bf16x8 v = *(const bf16x8*)&src[row * 128 + c * 8];
    *(bf16x8*)&Bs[c >> 3][row * 64 + (((c & 7) ^ (row & 7)) * 8)] = v;
  }
  __syncthreads();

  const long awb = (long)(b * 50 + hrow) * 80;
  for (int dw = 0; dw < 5; ++dw) {
#pragma unroll
    for (int ks = 0; ks < 4; ++ks) {
      const int ch = ks * 4 + kq;
      const long abase = (awb + dw * 16 + ch) * 128 + wave * 32 + lr;
      bf16x8 af0 = *(const bf16x8*)&AWq[abase * 8];
      bf16x8 af1 = *(const bf16x8*)&AWq[(abase + 16) * 8];
      const int arr = ch >> 3, cc = ch & 7;
#pragma unroll
      for (int ni = 0; ni < 9; ++ni) {
        const int row = lr + ni * 16 + dw;
        bf16x8 bfr = *(const bf16x8*)&Bs[arr][row * 64 + ((cc ^ (row & 7)) * 8)];
        acc[0][ni] = __builtin_amdgcn_mfma_f32_16x16x32_bf16(af0, bfr, acc[0][ni], 0, 0, 0);
        acc[1][ni] = __builtin_amdgcn_mfma_f32_16x16x32_bf16(af1, bfr, acc[1][ni], 0, 0, 0);
      }
    }
  }
#pragma unroll
  for (int mi = 0; mi < 2; ++mi) {
    const int og = wave * 32 + mi * 16 + kq * 4;
#pragma unroll
    for (int ni = 0; ni < 9; ++ni) {
      int wg = w0 + ni * 16 + lr;
      short4v pk;
#pragma unroll
      for (int r = 0; r < 4; ++r)
        pk[r] = f2bf(fmaxf(acc[mi][ni][r] + bias[og + r], 0.f));
      *(short4v*)&y1t[(((long)(b * 50) + hrow) * 288 + wg) * 128 + og] = pk;
    }
  }
}

// ------------------------------------------------------------------
// conv2 tap-GEMM (R8's conv_tap3<false>): BM=128, BN=48
// ------------------------------------------------------------------
__global__ __launch_bounds__(256) void conv2_tap(
    const short* __restrict__ wq,
    const short* __restrict__ act,
    const float* __restrict__ bias,
    float* __restrict__ y2)
{
  constexpr int NREP = 3;
  constexpr int ROWS = 52;
  const int b = blockIdx.z;
  const int hrow = blockIdx.y;
  const int w0 = blockIdx.x * 48;
  __shared__ __attribute__((aligned(16))) short Bs[2][ROWS * 64];
  const int tid = threadIdx.x;
  const int wave = tid >> 6, lane = tid & 63;
  const int lr = lane & 15, kq = lane >> 4;
  f32x4 acc[2][NREP] = {};

  for (int dh = 0; dh < 5; ++dh) {
    if (dh) __syncthreads();
    const short* src = act + (((long)(b * 29) + hrow + dh) * 148 + w0) * 128;
    for (int u = tid; u < ROWS * 16; u += 256) {
      int row = u >> 4, c = u & 15;
      bf16x8 v = *(const bf16x8*)&src[row * 128 + c * 8];
      *(bf16x8*)&Bs[c >> 3][row * 64 + (((c & 7) ^ (row & 7)) * 8)] = v;
    }
    __syncthreads();
    for (int dw = 0; dw < 5; ++dw) {
      const int tap = dh * 5 + dw;
#pragma unroll
      for (int ks = 0; ks < 4; ++ks) {
        const int ch = ks * 4 + kq;
        const long abase = ((long)(tap * 16 + ch)) * 128 + wave * 32 + lr;
        bf16x8 af0 = *(const bf16x8*)&wq[abase * 8];
        bf16x8 af1 = *(const bf16x8*)&wq[(abase + 16) * 8];
        const int arr = ch >> 3, cc = ch & 7;
#pragma unroll
        for (int ni = 0; ni < NREP; ++ni) {
          const int row = lr + ni * 16 + dw;
          bf16x8 bfr = *(const bf16x8*)&Bs[arr][row * 64 + ((cc ^ (row & 7)) * 8)];
          acc[0][ni] = __builtin_amdgcn_mfma_f32_16x16x32_bf16(af0, bfr, acc[0][ni], 0, 0, 0);
          acc[1][ni] = __builtin_amdgcn_mfma_f32_16x16x32_bf16(af1, bfr, acc[1][ni], 0, 0, 0);
        }
      }
    }
  }
#pragma unroll
  for (int mi = 0; mi < 2; ++mi) {
    const int og = wave * 32 + mi * 16 + kq * 4;
#pragma unroll
    for (int ni = 0; ni < NREP; ++ni) {
      int wg = w0 + ni * 16 + lr;
#pragma unroll
      for (int r = 0; r < 4; ++r)
        y2[((long)(b * 128) + og + r) * 3600 + hrow * 144 + wg] =
            fmaxf(acc[mi][ni][r] + bias[og + r], 0.f);
    }
  }
}

// ------------------------------------------------------------------
__global__ void pool_t(const short* __restrict__ y1t, short* __restrict__ x2t)
{
  int idx = blockIdx.x * 256 + threadIdx.x;
  if (idx >= B_ * HP_ * WP_ * 16) return;
  int c8 = idx & 15; int t = idx >> 4;
  int wp = t % WP_; t /= WP_;
  int hp = t % HP_; int b = t / HP_;
  const short* base = y1t + (((long)(b * 50 + 2 * hp) * 288) + 2 * wp) * 128 + c8 * 8;
  bf16x8 v00 = *(const bf16x8*)&base[0];
  bf16x8 v01 = *(const bf16x8*)&base[128];
  bf16x8 v10 = *(const bf16x8*)&base[288 * 128];
  bf16x8 v11 = *(const bf16x8*)&base[288 * 128 + 128];
  bf16x8 r;
#pragma unroll
  for (int e = 0; e < 8; ++e)
    r[e] = f2bf(fmaxf(fmaxf(bf2f(v00[e]), bf2f(v01[e])), fmaxf(bf2f(v10[e]), bf2f(v11[e]))));
  *(bf16x8*)&x2t[(((long)(b * 29) + hp + 2) * 148 + wp + 2) * 128 + c8 * 8] = r;
}

// ------------------------------------------------------------------
__global__ __launch_bounds__(64) void ln_kernel(float* __restrict__ y2,
                                                const float* __restrict__ g,
                                                const float* __restrict__ bb)
{
  float* p = y2 + (long)blockIdx.x * WP_;
  const int lane = threadIdx.x;
  float v[3]; float s = 0.f, ss = 0.f;
#pragma unroll
  for (int q = 0; q < 3; ++q) {
    int wp = lane + q * 64;
    float x = (wp < WP_) ? p[wp] : 0.f;
    v[q] = x; s += x; ss = fmaf(x, x, ss);
  }
#pragma unroll
  for (int off = 32; off; off >>= 1) { s += __shfl_xor(s, off, 64); ss += __shfl_xor(ss, off, 64); }
  float mu = s * (1.f / (float)WP_);
  float var = ss * (1.f / (float)WP_) - mu * mu;
  float inv = rsqrtf(var + 1e-5f);
#pragma unroll
  for (int q = 0; q < 3; ++q) {
    int wp = lane + q * 64;
    if (wp < WP_) p[wp] = (v[q] - mu) * inv * g[wp] + bb[wp];
  }
}

// mean over hp -> split bf16 zb[512][256] (pad zeroed by memset)
__global__ void meanhp_kernel(const float* __restrict__ y2, short* __restrict__ zb)
{
  int idx = blockIdx.x * 256 + threadIdx.x;
  if (idx >= B_ * S_ * WP_) return;
  int wp = idx % WP_; int t = idx / WP_;
  const float* p = y2 + (long)t * HP_ * WP_ + wp;
  float s = 0.f;
  for (int hp = 0; hp < HP_; ++hp) s += p[hp * WP_];
  float v = s * (1.f / (float)HP_);
  short h = f2bf(v);
  zb[(long)t * 256 + wp] = h;
  zb[131072 + (long)t * 256 + wp] = f2bf(v - bf2f(h));
}

__global__ void maskout_kernel(float* __restrict__ out, const int* __restrict__ ml,
                               const int* __restrict__ ign)
{
  int idx = blockIdx.x * 256 + threadIdx.x;
  if (idx >= B_ * S_ * NOUT_) return;
  if (ign[0] == 0) return;
  if (ml[idx / NOUT_] <= 0) out[idx] = 0.f;
}

// ------------------------------------------------------------------
extern "C" void kernel_launch(void* const* d_in, const int* in_sizes, int n_in,
                              void* d_out, int out_size, void* d_ws, size_t ws_size,
                              hipStream_t stream)
{
  const float* bert = (const float*)d_in[0];
  const float* mem  = (const float*)d_in[1];
  const int*   ml   = (const int*)d_in[2];
  const float* cw   = (const float*)d_in[3];
  const int*   ign  = (const int*)d_in[4];
  const float* W1   = (const float*)d_in[6];
  const float* b1l  = (const float*)d_in[7];
  const float* sent = (const float*)d_in[8];
  const float* w1m  = (const float*)d_in[9];
  const float* w2m  = (const float*)d_in[10];
  const float* c1w  = (const float*)d_in[11];
  const float* c1b  = (const float*)d_in[12];
  const float* c2w  = (const float*)d_in[13];
  const float* c2b  = (const float*)d_in[14];
  const float* lng  = (const float*)d_in[15];
  const float* lnb  = (const float*)d_in[16];
  const float* Wo   = (const float*)d_in[17];
  const float* bo   = (const float*)d_in[18];
  float* out = (float*)d_out;

  // ---- A-region (persistent) ----
  // zero-region first (one memset): Gt, x2t, zb, attTp
  short* Gt    = (short*)d_ws;             // 149504
  short* x2t   = Gt + 149504;              // 2197504
  short* zb    = x2t + 2197504;            // 262144
  float* attTp = (float*)(zb + 262144);    // 27648 f32
  float* w1s   = attTp + 27648;            // 288
  float* w2s   = w1s + 288;                // 288
  float* ebb   = w2s + 288;                // 1152
  short* wob   = (short*)(ebb + 1152);     // 153600
  short* w1p   = wob + 153600;             // 409600
  short* w2p   = w1p + 409600;             // 409600
  short* y1t   = w2p + 409600;             // 7372800
  // ---- pool X (32768000 B), lifetime-disjoint phases ----
  short* poolX = y1t + 7372800;
  // phase 1 (dead before conv1_aw):
  short* bertb = poolX;                    // 786432 (hi+lo)
  short* w1b   = bertb + 786432;           // 442368
  short* ebt   = w1b + 442368;             // 294912
  short* Eb    = ebt + 294912;             // 393216
  short* pb    = Eb + 393216;              // 884736
  float* ebf   = (float*)(pb + 884736);    // 147456 f32
  float* E     = ebf + 147456;             // 147456
  float* t2    = E + 147456;               // 147456
  // phase 2: AWq (32768000 B); phase 2b: y2 f32 (7372800 B) after AW dead
  short* AWq   = poolX;
  float* y2    = (float*)poolX;
  // total ws ≈ 54.8 MB

  dim3 blk(256);

  // two memsets: zero-region, and Eb+pb pads inside pool X
  hipMemsetAsync(Gt, 0, (size_t)5328896, stream);
  hipMemsetAsync(Eb, 0, (size_t)(393216 + 884736) * 2, stream);

  cast_pad_split<<<dim3(1536), blk, 0, stream>>>(bert, bertb, 393216L, 512, 768, 768);
  cast_pad_split<<<dim3(864), blk, 0, stream>>>(W1, w1b, 221184L, 288, 768, 768);
  cast_pad_split<<<dim3(300), blk, 0, stream>>>(Wo, wob, 76800L, 300, 144, 256);
  wperm_kernel<<<dim3(1600), blk, 0, stream>>>(c1w, w1p);
  wperm_kernel<<<dim3(1600), blk, 0, stream>>>(c2w, w2p);
  wsum_kernel<<<dim3(5), dim3(64), 0, stream>>>(w1m, w2m, w1s, w2s);

  // eb = bert @ W1^T + b1  [512x288] K=768; emits f32 ebf + split ebt
  gemm_split<1><<<dim3(5, 8, 1), blk, 0, stream>>>(
      bertb, w1b, b1l, ebf, ebt, 512, 288, 12,
      0L, 768, 393216L, 0L, 768, 221184L, 0L, 288, 0L, 0, 147456L);

  ebbar_kernel<<<dim3(4), dim3(256), 0, stream>>>(ebf, ebb);

  score_kernel<<<dim3(S_, B_), blk, 0, stream>>>(mem, sent, ebb, cw, ml, E, Eb, attTp);

  // P_b = eb_b^T @ eb_b  [288x288] K=128 -> split pb
  gemm_split<2><<<dim3(5, 5, 4), blk, 0, stream>>>(
      ebt, ebt, (const float*)nullptr, (float*)nullptr, pb, 288, 288, 2,
      (long)288 * 128, 128, 147456L, (long)288 * 128, 128, 147456L,
      0L, 0, (long)288 * 384, 384, 442368L);

  // t2 = E @ P  [128x288] K=384(pad)
  gemm_split<0><<<dim3(5, 2, 4), blk, 0, stream>>>(
      Eb, pb, (const float*)nullptr, t2, (short*)nullptr, 128, 288, 6,
      (long)128 * 384, 384, 196608L, (long)288 * 384, 384, 442368L,
      (long)128 * 288, 288, 0L, 0, 0L);

  g_kernel<<<dim3(S_, B_), blk, 0, stream>>>(E, t2, w1s, w2s, Gt);

  // conv1: stage A (dh pre-contraction) then K=640 GEMM
  conv1_aw<<<dim3(2, 50, 4), blk, 0, stream>>>(w1p, attTp, AWq);
  conv1_mfma<<<dim3(2, 50, 4), blk, 0, stream>>>(AWq, Gt, c1b, y1t);

  pool_t<<<dim3((B_ * HP_ * WP_ * 16 + 255) / 256), blk, 0, stream>>>(y1t, x2t);

  // conv2: BM=128, BN=48, grid (3 wtiles, 25 hp, 4 b)
  conv2_tap<<<dim3(3, 25, 4), blk, 0, stream>>>(w2p, x2t, c2b, y2);

  ln_kernel<<<dim3(B_ * S_ * HP_), dim3(64), 0, stream>>>(y2, lng, lnb);

  meanhp_kernel<<<dim3((B_ * S_ * WP_ + 255) / 256), blk, 0, stream>>>(y2, zb);

  // out = z @ W_out^T + b_out  [512x300] K=256(pad)
  gemm_split<0><<<dim3(5, 8, 1), blk, 0, stream>>>(
      zb, wob, bo, out, (short*)nullptr, 512, 300, 4,
      0L, 256, 131072L, 0L, 256, 76800L, 0L, 300, 0L, 0, 0L);

  maskout_kernel<<<dim3((B_ * S_ * NOUT_ + 255) / 256), blk, 0, stream>>>(out, ml, ign);
}

// Round 10
// 256.860 us; speedup vs baseline: 4.9463x; 1.0481x over previous
//
#include <hip/hip_runtime.h>

#define B_    4
#define S_    128
#define BERT_ 768
#define C_    49
#define C1_   50
#define M_    288
#define HP_   25
#define WP_   144
#define NOUT_ 300

typedef short bf16x8 __attribute__((ext_vector_type(8)));
typedef short short4v __attribute__((ext_vector_type(4)));
typedef float f32x4 __attribute__((ext_vector_type(4)));

static __device__ __forceinline__ short f2bf(float f) {
  unsigned u = __float_as_uint(f);
  unsigned r = (u + 0x7fffu + ((u >> 16) & 1u)) >> 16;
  return (short)r;
}
static __device__ __forceinline__ float bf2f(short v) {
  return __uint_as_float(((unsigned)(unsigned short)v) << 16);
}
static __device__ __forceinline__ unsigned cvt_pk_bf16(float lo, float hi) {
  unsigned r;
  asm("v_cvt_pk_bf16_f32 %0, %1, %2" : "=v"(r) : "v"(lo), "v"(hi));
  return r;
}

// ------------------------------------------------------------------
// cast f32 [R][Ks] -> split bf16 (hi,lo) [R][Kd], zero pad cols [Ks,Kd)
// ------------------------------------------------------------------
__global__ void cast_pad_split(const float* __restrict__ src, short* __restrict__ dst,
                               long loOff, int R, int Ks, int Kd)
{
  int idx = blockIdx.x * 256 + threadIdx.x;
  if (idx >= R * Kd) return;
  int k = idx % Kd, r = idx / Kd;
  short h = 0, l = 0;
  if (k < Ks) {
    float v = src[(long)r * Ks + k];
    h = f2bf(v);
    l = f2bf(v - bf2f(h));
  }
  dst[idx] = h;
  dst[idx + loOff] = l;
}

// ------------------------------------------------------------------
// split-bf16 MFMA GEMM. Out[i,j] = sum_k A[i,k]*B[j,k] (+bias)
// ------------------------------------------------------------------
template<int OMODE>
__global__ __launch_bounds__(256) void gemm_split(
    const short* __restrict__ A, const short* __restrict__ Bm,
    const float* __restrict__ bias,
    float* __restrict__ Outf, short* __restrict__ Outb,
    int Mr, int Nc, int KH,
    long aB, int aP, long aLo,
    long bB, int bP, long bLo,
    long oB, int oP,
    long obB, int obP, long obLo)
{
  const int z = blockIdx.z;
  const int i0 = blockIdx.y * 64, j0 = blockIdx.x * 64;
  __shared__ __attribute__((aligned(16))) short As[2][64 * 64];
  __shared__ __attribute__((aligned(16))) short Bs[2][64 * 64];
  const int tid = threadIdx.x;
  const int wave = tid >> 6, lane = tid & 63;
  const int lr = lane & 15, kq = lane >> 4;
  f32x4 acc[4] = {};
  const short* Ab = A + z * aB;
  const short* Bb = Bm + z * bB;
  const bf16x8 vz = {0, 0, 0, 0, 0, 0, 0, 0};
  for (int kh = 0; kh < KH; ++kh) {
    if (kh) __syncthreads();
    for (int u = tid; u < 512; u += 256) {
      int row = u >> 3, c = u & 7;
      int gi = i0 + row;
      const short* src = &Ab[(long)gi * aP + kh * 64 + c * 8];
      bf16x8 vh = (gi < Mr) ? *(const bf16x8*)src : vz;
      bf16x8 vl = (gi < Mr) ? *(const bf16x8*)(src + aLo) : vz;
      int dst = row * 64 + ((c ^ (row & 7)) * 8);
      *(bf16x8*)&As[0][dst] = vh;
      *(bf16x8*)&As[1][dst] = vl;
    }
    for (int u = tid; u < 512; u += 256) {
      int row = u >> 3, c = u & 7;
      int gj = j0 + row;
      const short* src = &Bb[(long)gj * bP + kh * 64 + c * 8];
      bf16x8 vh = (gj < Nc) ? *(const bf16x8*)src : vz;
      bf16x8 vl = (gj < Nc) ? *(const bf16x8*)(src + bLo) : vz;
      int dst = row * 64 + ((c ^ (row & 7)) * 8);
      *(bf16x8*)&Bs[0][dst] = vh;
      *(bf16x8*)&Bs[1][dst] = vl;
    }
    __syncthreads();
#pragma unroll
    for (int ks = 0; ks < 2; ++ks) {
      const int ch = ks * 4 + kq;
      const int ar = wave * 16 + lr;
      const int ao = ar * 64 + ((ch ^ (ar & 7)) * 8);
      bf16x8 ah = *(const bf16x8*)&As[0][ao];
      bf16x8 al = *(const bf16x8*)&As[1][ao];
#pragma unroll
      for (int ni = 0; ni < 4; ++ni) {
        const int br = ni * 16 + lr;
        const int bo2 = br * 64 + ((ch ^ (br & 7)) * 8);
        bf16x8 bh = *(const bf16x8*)&Bs[0][bo2];
        bf16x8 bl = *(const bf16x8*)&Bs[1][bo2];
        acc[ni] = __builtin_amdgcn_mfma_f32_16x16x32_bf16(ah, bh, acc[ni], 0, 0, 0);
        acc[ni] = __builtin_amdgcn_mfma_f32_16x16x32_bf16(ah, bl, acc[ni], 0, 0, 0);
        acc[ni] = __builtin_amdgcn_mfma_f32_16x16x32_bf16(al, bh, acc[ni], 0, 0, 0);
      }
    }
  }
#pragma unroll
  for (int ni = 0; ni < 4; ++ni) {
    int jg = j0 + ni * 16 + lr;
    if (jg >= Nc) continue;
#pragma unroll
    for (int r = 0; r < 4; ++r) {
      int ig = i0 + wave * 16 + kq * 4 + r;
      if (ig >= Mr) continue;
      float v = acc[ni][r];
      if (bias) v += bias[jg];
      if constexpr (OMODE == 0 || OMODE == 1)
        Outf[z * oB + (long)ig * oP + jg] = v;
      if constexpr (OMODE == 1) {
        long o = ((long)((ig >> 7) * 288 + jg)) * 128 + (ig & 127);
        short h = f2bf(v);
        Outb[o] = h;
        Outb[o + obLo] = f2bf(v - bf2f(h));
      }
      if constexpr (OMODE == 2) {
        long o = z * obB + (long)ig * obP + jg;
        short h = f2bf(v);
        Outb[o] = h;
        Outb[o + obLo] = f2bf(v - bf2f(h));
      }
    }
  }
}

// ------------------------------------------------------------------
__global__ void wsum_kernel(const float* __restrict__ w1, const float* __restrict__ w2,
                            float* __restrict__ w1s, float* __restrict__ w2s)
{
  int m = blockIdx.x * 64 + threadIdx.x;
  if (m >= M_) return;
  float a = 0.f, b = 0.f;
  for (int c = 0; c < C1_; ++c) { a += w1[m * C1_ + c]; b += w2[m * C1_ + c]; }
  w1s[m] = a; w2s[m] = b;
}

__global__ void ebbar_kernel(const float* __restrict__ eb, float* __restrict__ ebb)
{
  int b = blockIdx.x;
  for (int m = threadIdx.x; m < M_; m += blockDim.x) {
    float s = 0.f;
    for (int t = 0; t < S_; ++t) s += eb[((long)(b * S_ + t)) * M_ + m];
    ebb[b * M_ + m] = s * (1.f / (float)S_);
  }
}

// ------------------------------------------------------------------
// wq[((tap*16 + chq)*128 + o)*8 + e] = bf16(w[(o*128 + chq*8+e)*25 + tap])
// ------------------------------------------------------------------
__global__ void wperm_kernel(const float* __restrict__ w, short* __restrict__ wq)
{
  int idx = blockIdx.x * 256 + threadIdx.x;
  if (idx >= 25 * 128 * 128) return;
  int e = idx & 7; int t = idx >> 3;
  int o = t & 127; t >>= 7;
  int chq = t & 15; int tap = t >> 4;
  int ch = chq * 8 + e;
  wq[idx] = f2bf(w[((long)(o * 128 + ch)) * 25 + tap]);
}

// ------------------------------------------------------------------
// fused per-(b,s): E (f32 + split bf16 padded), scores, softmaxes, top-5, att
// ------------------------------------------------------------------
__global__ __launch_bounds__(256) void score_kernel(
    const float* __restrict__ mem, const float* __restrict__ sentinel,
    const float* __restrict__ ebbar, const float* __restrict__ cw,
    const int* __restrict__ ml, float* __restrict__ E, short* __restrict__ Eb,
    float* __restrict__ attTp)
{
  const int s = blockIdx.x, b = blockIdx.y;
  const int tid = threadIdx.x, wave = tid >> 6, lane = tid & 63;
  __shared__ float sEb[M_];
  __shared__ float sE[4][M_];
  __shared__ float sScore[C1_];
  for (int m = tid; m < M_; m += 256) sEb[m] = ebbar[b * M_ + m];
  __syncthreads();

  const float* base = mem + ((long)(b * S_ + s)) * C_ * M_;
  float Ereg[5] = {0.f, 0.f, 0.f, 0.f, 0.f};
  for (int jj = wave; jj < C_; jj += 4) {
    const float* row = base + (long)jj * M_;
    float d = 0.f;
#pragma unroll
    for (int q = 0; q < 5; ++q) {
      int m = lane + q * 64;
      if (m < M_) { float v = row[m]; Ereg[q] += v; d = fmaf(v, sEb[m], d); }
    }
#pragma unroll
    for (int off = 32; off; off >>= 1) d += __shfl_down(d, off, 64);
    if (lane == 0) sScore[jj + 1] = d;
  }
#pragma unroll
  for (int q = 0; q < 5; ++q) { int m = lane + q * 64; if (m < M_) sE[wave][m] = Ereg[q]; }
  __syncthreads();

  if (wave == 0) {
    float d0 = 0.f;
    for (int m = lane; m < M_; m += 64) d0 = fmaf(sentinel[m], sEb[m], d0);
#pragma unroll
    for (int off = 32; off; off >>= 1) d0 += __shfl_down(d0, off, 64);
    if (lane == 0) sScore[0] = d0;
  }
  for (int m = tid; m < M_; m += 256) {
    float ev = sentinel[m] + sE[0][m] + sE[1][m] + sE[2][m] + sE[3][m];
    E[((long)(b * S_ + s)) * M_ + m] = ev;
    short h = f2bf(ev);
    Eb[((long)(b * S_ + s)) * 384 + m] = h;
    Eb[196608 + ((long)(b * S_ + s)) * 384 + m] = f2bf(ev - bf2f(h));
  }
  __syncthreads();

  if (wave == 0) {
    const int mlv = ml[b * S_ + s];
    float sc = (lane < C1_) ? sScore[lane] : 0.f;
    if (lane < C1_ && mlv < lane) sc -= 1e6f;
    float mx = (lane < C1_) ? sc : -3.0e38f;
#pragma unroll
    for (int off = 32; off; off >>= 1) mx = fmaxf(mx, __shfl_xor(mx, off, 64));
    float e1 = (lane < C1_) ? __expf(sc - mx) : 0.f;
    float s1 = e1;
#pragma unroll
    for (int off = 32; off; off >>= 1) s1 += __shfl_xor(s1, off, 64);
    float p1 = e1 / s1;
    float cv = 0.f;
    if (lane >= 1 && lane < C1_) cv = cw[((long)(b * S_ + s)) * C_ + lane - 1];
    float mx2 = (lane < C1_) ? cv : -3.0e38f;
#pragma unroll
    for (int off = 32; off; off >>= 1) mx2 = fmaxf(mx2, __shfl_xor(mx2, off, 64));
    float e2 = (lane < C1_) ? __expf(cv - mx2) : 0.f;
    float s2 = e2;
#pragma unroll
    for (int off = 32; off; off >>= 1) s2 += __shfl_xor(s2, off, 64);
    float p2 = e2 / s2;
    float scm = 0.7f * p1 + 0.3f * p2;
    bool active = (lane < C1_);
    float thr = 0.f;
    for (int r = 0; r < 5; ++r) {
      float v = active ? scm : -3.0e38f;
      int idx = lane;
#pragma unroll
      for (int off = 32; off; off >>= 1) {
        float ov = __shfl_xor(v, off, 64);
        int oi = __shfl_xor(idx, off, 64);
        if (ov > v || (ov == v && oi < idx)) { v = ov; idx = oi; }
      }
      thr = v;
      if (lane == idx) active = false;
    }
    float kept = (lane < C1_ && scm >= thr) ? scm : 0.f;
    float mx3 = (lane < C1_) ? kept : -3.0e38f;
#pragma unroll
    for (int off = 32; off; off >>= 1) mx3 = fmaxf(mx3, __shfl_xor(mx3, off, 64));
    float e3 = (lane < C1_) ? __expf(kept - mx3) : 0.f;
    float s3 = e3;
#pragma unroll
    for (int off = 32; off; off >>= 1) s3 += __shfl_xor(s3, off, 64);
    if (lane < C1_) attTp[((long)(b * 54) + lane + 2) * 128 + s] = e3 / s3;
  }
}

// ------------------------------------------------------------------
// G[b,s,n] -> bf16 transposed into Gt[b][n+2][s]
// Balanced: 576 threads, thread t = (n = t>>1, m-half = t&1), 144 m each;
// halves combined via shfl_xor(1) (intra-wave since 64 | 576).
// ------------------------------------------------------------------
__global__ __launch_bounds__(576) void g_kernel(
    const float* __restrict__ E, const float* __restrict__ t2,
    const float* __restrict__ w1s, const float* __restrict__ w2s,
    short* __restrict__ Gt)
{
  const int s = blockIdx.x, b = blockIdx.y;
  __shared__ float sE[M_], s1[M_], s2[M_];
  const int tid = threadIdx.x;
  const long base = (long)(b * S_ + s) * M_;
  for (int m = tid; m < M_; m += 576) { sE[m] = E[base + m]; s1[m] = w1s[m]; s2[m] = w2s[m]; }
  __syncthreads();
  const int n = tid >> 1, half = tid & 1;
  const float a = sE[n];
  const float c = t2[base + n];
  float num = 0.f, den = 0.f;
  const int m0 = half * 144;
#pragma unroll 4
  for (int mm = 0; mm < 144; ++mm) {
    int m = m0 + mm;
    float z = fmaf(s1[m], a, s2[m] * c);
    float u = __expf(2.f * z);
    float th = 1.f - 2.f / (u + 1.f);
    float e = __expf(th);
    num = fmaf(sE[m], e, num);
    den += e;
  }
  num += __shfl_xor(num, 1, 64);
  den += __shfl_xor(den, 1, 64);
  if (half == 0)
    Gt[((long)(b * 292) + 2 + n) * 128 + s] = f2bf(num / den);
}

// ------------------------------------------------------------------
// conv1 stage A: AWq[(b*50+h)*80 + c][o][8] = sum_dh w1q[(dh*5+dw)*16+chq][o][8]
//                 * att[b][i=chq*8+e][h+dh-2]   (c = dw*16+chq)
// ------------------------------------------------------------------
__global__ __launch_bounds__(256) void conv1_aw(
    const short* __restrict__ w1q, const float* __restrict__ attp,
    short* __restrict__ AWq)
{
  const int b = blockIdx.z, h = blockIdx.y, half = blockIdx.x;
  __shared__ float sAtt[5][128];
  const int tid = threadIdx.x;
  for (int u = tid; u < 640; u += 256)
    sAtt[u >> 7][u & 127] = attp[((long)(b * 54) + h + (u >> 7)) * 128 + (u & 127)];
  __syncthreads();
  const long obase = ((long)(b * 50 + h) * 80) * 1024;
  for (int u = tid; u < 5120; u += 256) {
    int c = half * 40 + (u >> 7);
    int o = u & 127;
    int dw = c / 16, chq = c & 15;
    float acc[8] = {};
#pragma unroll
    for (int dh = 0; dh < 5; ++dh) {
      bf16x8 wv = *(const bf16x8*)&w1q[(((long)((dh * 5 + dw) * 16 + chq)) * 128 + o) * 8];
      const float* ar = &sAtt[dh][chq * 8];
#pragma unroll
      for (int e = 0; e < 8; ++e) acc[e] = fmaf(bf2f(wv[e]), ar[e], acc[e]);
    }
    union { unsigned u4[4]; bf16x8 v; } pk;
    pk.u4[0] = cvt_pk_bf16(acc[0], acc[1]);
    pk.u4[1] = cvt_pk_bf16(acc[2], acc[3]);
    pk.u4[2] = cvt_pk_bf16(acc[4], acc[5]);
    pk.u4[3] = cvt_pk_bf16(acc[6], acc[7]);
    *(bf16x8*)&AWq[obase + (long)c * 1024 + o * 8] = pk.v;
  }
}

// ------------------------------------------------------------------
// conv1 stage B: per (b,h) GEMM over K=640 (dw,i). BM=128, BN=144.
// ------------------------------------------------------------------
__global__ __launch_bounds__(256) void conv1_mfma(
    const short* __restrict__ AWq, const short* __restrict__ Gt,
    const float* __restrict__ bias, short* __restrict__ y1t)
{
  const int b = blockIdx.z, hrow = blockIdx.y;
  const int w0 = blockIdx.x * 144;
  __shared__ __attribute__((aligned(16))) short Bs[2][148 * 64];
  const int tid = threadIdx.x;
  const int wave = tid >> 6, lane = tid & 63;
  const int lr = lane & 15, kq = lane >> 4;
  f32x4 acc[2][9] = {};

  const short* src = Gt + ((long)(b * 292) + w0) * 128;
  for (int u = tid; u < 2368; u += 256) {
    int row = u >> 4, c = u & 15;
    bf16x8 v = *(const bf16x8*)&src[row * 128 + c * 8];
    *(bf16x8*)&Bs[c >> 3][row * 64 + (((c & 7) ^ (row & 7)) * 8)] = v;
  }
  __syncthreads();

  const long awb = (long)(b * 50 + hrow) * 80;
  for (int dw = 0; dw < 5; ++dw) {
#pragma unroll
    for (int ks = 0; ks < 4; ++ks) {
      const int ch = ks * 4 + kq;
      const long abase = (awb + dw * 16 + ch) * 128 + wave * 32 + lr;
      bf16x8 af0 = *(const bf16x8*)&AWq[abase * 8];
      bf16x8 af1 = *(const bf16x8*)&AWq[(abase + 16) * 8];
      const int arr = ch >> 3, cc = ch & 7;
#pragma unroll
      for (int ni = 0; ni < 9; ++ni) {
        const int row = lr + ni * 16 + dw;
        bf16x8 bfr = *(const bf16x8*)&Bs[arr][row * 64 + ((cc ^ (row & 7)) * 8)];
        acc[0][ni] = __builtin_amdgcn_mfma_f32_16x16x32_bf16(af0, bfr, acc[0][ni], 0, 0, 0);
        acc[1][ni] = __builtin_amdgcn_mfma_f32_16x16x32_bf16(af1, bfr, acc[1][ni], 0, 0, 0);
      }
    }
  }
#pragma unroll
  for (int mi = 0; mi < 2; ++mi) {
    const int og = wave * 32 + mi * 16 + kq * 4;
#pragma unroll
    for (int ni = 0; ni < 9; ++ni) {
      int wg = w0 + ni * 16 + lr;
      short4v pk;
#pragma unroll
      for (int r = 0; r < 4; ++r)
        pk[r] = f2bf(fmaxf(acc[mi][ni][r] + bias[og + r], 0.f));
      *(short4v*)&y1t[(((long)(b * 50) + hrow) * 288 + wg) * 128 + og] = pk;
    }
  }
}

// ------------------------------------------------------------------
// conv2 tap-GEMM: BM=128, BN=48
// ------------------------------------------------------------------
__global__ __launch_bounds__(256) void conv2_tap(
    const short* __restrict__ wq,
    const short* __restrict__ act,
    const float* __restrict__ bias,
    float* __restrict__ y2)
{
  constexpr int NREP = 3;
  constexpr int ROWS = 52;
  const int b = blockIdx.z;
  const int hrow = blockIdx.y;
  const int w0 = blockIdx.x * 48;
  __shared__ __attribute__((aligned(16))) short Bs[2][ROWS * 64];
  const int tid = threadIdx.x;
  const int wave = tid >> 6, lane = tid & 63;
  const int lr = lane & 15, kq = lane >> 4;
  f32x4 acc[2][NREP] = {};

  for (int dh = 0; dh < 5; ++dh) {
    if (dh) __syncthreads();
    const short* src = act + (((long)(b * 29) + hrow + dh) * 148 + w0) * 128;
    for (int u = tid; u < ROWS * 16; u += 256) {
      int row = u >> 4, c = u & 15;
      bf16x8 v = *(const bf16x8*)&src[row * 128 + c * 8];
      *(bf16x8*)&Bs[c >> 3][row * 64 + (((c & 7) ^ (row & 7)) * 8)] = v;
    }
    __syncthreads();
    for (int dw = 0; dw < 5; ++dw) {
      const int tap = dh * 5 + dw;
#pragma unroll
      for (int ks = 0; ks < 4; ++ks) {
        const int ch = ks * 4 + kq;
        const long abase = ((long)(tap * 16 + ch)) * 128 + wave * 32 + lr;
        bf16x8 af0 = *(const bf16x8*)&wq[abase * 8];
        bf16x8 af1 = *(const bf16x8*)&wq[(abase + 16) * 8];
        const int arr = ch >> 3, cc = ch & 7;
#pragma unroll
        for (int ni = 0; ni < NREP; ++ni) {
          const int row = lr + ni * 16 + dw;
          bf16x8 bfr = *(const bf16x8*)&Bs[arr][row * 64 + ((cc ^ (row & 7)) * 8)];
          acc[0][ni] = __builtin_amdgcn_mfma_f32_16x16x32_bf16(af0, bfr, acc[0][ni], 0, 0, 0);
          acc[1][ni] = __builtin_amdgcn_mfma_f32_16x16x32_bf16(af1, bfr, acc[1][ni], 0, 0, 0);
        }
      }
    }
  }
#pragma unroll
  for (int mi = 0; mi < 2; ++mi) {
    const int og = wave * 32 + mi * 16 + kq * 4;
#pragma unroll
    for (int ni = 0; ni < NREP; ++ni) {
      int wg = w0 + ni * 16 + lr;
#pragma unroll
      for (int r = 0; r < 4; ++r)
        y2[((long)(b * 128) + og + r) * 3600 + hrow * 144 + wg] =
            fmaxf(acc[mi][ni][r] + bias[og + r], 0.f);
    }
  }
}

// ------------------------------------------------------------------
__global__ void pool_t(const short* __restrict__ y1t, short* __restrict__ x2t)
{
  int idx = blockIdx.x * 256 + threadIdx.x;
  if (idx >= B_ * HP_ * WP_ * 16) return;
  int c8 = idx & 15; int t = idx >> 4;
  int wp = t % WP_; t /= WP_;
  int hp = t % HP_; int b = t / HP_;
  const short* base = y1t + (((long)(b * 50 + 2 * hp) * 288) + 2 * wp) * 128 + c8 * 8;
  bf16x8 v00 = *(const bf16x8*)&base[0];
  bf16x8 v01 = *(const bf16x8*)&base[128];
  bf16x8 v10 = *(const bf16x8*)&base[288 * 128];
  bf16x8 v11 = *(const bf16x8*)&base[288 * 128 + 128];
  bf16x8 r;
#pragma unroll
  for (int e = 0; e < 8; ++e)
    r[e] = f2bf(fmaxf(fmaxf(bf2f(v00[e]), bf2f(v01[e])), fmaxf(bf2f(v10[e]), bf2f(v11[e]))));
  *(bf16x8*)&x2t[(((long)(b * 29) + hp + 2) * 148 + wp + 2) * 128 + c8 * 8] = r;
}

// ------------------------------------------------------------------
__global__ __launch_bounds__(64) void ln_kernel(float* __restrict__ y2,
                                                const float* __restrict__ g,
                                                const float* __restrict__ bb)
{
  float* p = y2 + (long)blockIdx.x * WP_;
  const int lane = threadIdx.x;
  float v[3]; float s = 0.f, ss = 0.f;
#pragma unroll
  for (int q = 0; q < 3; ++q) {
    int wp = lane + q * 64;
    float x = (wp < WP_) ? p[wp] : 0.f;
    v[q] = x; s += x; ss = fmaf(x, x, ss);
  }
#pragma unroll
  for (int off = 32; off; off >>= 1) { s += __shfl_xor(s, off, 64); ss += __shfl_xor(ss, off, 64); }
  float mu = s * (1.f / (float)WP_);
  float var = ss * (1.f / (float)WP_) - mu * mu;
  float inv = rsqrtf(var + 1e-5f);
#pragma unroll
  for (int q = 0; q < 3; ++q) {
    int wp = lane + q * 64;
    if (wp < WP_) p[wp] = (v[q] - mu) * inv * g[wp] + bb[wp];
  }
}

// mean over hp -> split bf16 zb[512][256] (pad zeroed by memset)
__global__ void meanhp_kernel(const float* __restrict__ y2, short* __restrict__ zb)
{
  int idx = blockIdx.x * 256 + threadIdx.x;
  if (idx >= B_ * S_ * WP_) return;
  int wp = idx % WP_; int t = idx / WP_;
  const float* p = y2 + (long)t * HP_ * WP_ + wp;
  float s = 0.f;
  for (int hp = 0; hp < HP_; ++hp) s += p[hp * WP_];
  float v = s * (1.f / (float)HP_);
  short h = f2bf(v);
  zb[(long)t * 256 + wp] = h;
  zb[131072 + (long)t * 256 + wp] = f2bf(v - bf2f(h));
}

__global__ void maskout_kernel(float* __restrict__ out, const int* __restrict__ ml,
                               const int* __restrict__ ign)
{
  int idx = blockIdx.x * 256 + threadIdx.x;
  if (idx >= B_ * S_ * NOUT_) return;
  if (ign[0] == 0) return;
  if (ml[idx / NOUT_] <= 0) out[idx] = 0.f;
}

// ------------------------------------------------------------------
extern "C" void kernel_launch(void* const* d_in, const int* in_sizes, int n_in,
                              void* d_out, int out_size, void* d_ws, size_t ws_size,
                              hipStream_t stream)
{
  const float* bert = (const float*)d_in[0];
  const float* mem  = (const float*)d_in[1];
  const int*   ml   = (const int*)d_in[2];
  const float* cw   = (const float*)d_in[3];
  const int*   ign  = (const int*)d_in[4];
  const float* W1   = (const float*)d_in[6];
  const float* b1l  = (const float*)d_in[7];
  const float* sent = (const float*)d_in[8];
  const float* w1m  = (const float*)d_in[9];
  const float* w2m  = (const float*)d_in[10];
  const float* c1w  = (const float*)d_in[11];
  const float* c1b  = (const float*)d_in[12];
  const float* c2w  = (const float*)d_in[13];
  const float* c2b  = (const float*)d_in[14];
  const float* lng  = (const float*)d_in[15];
  const float* lnb  = (const float*)d_in[16];
  const float* Wo   = (const float*)d_in[17];
  const float* bo   = (const float*)d_in[18];
  float* out = (float*)d_out;

  // ---- A-region (persistent) ----
  short* Gt    = (short*)d_ws;             // 149504
  short* x2t   = Gt + 149504;              // 2197504
  short* zb    = x2t + 2197504;            // 262144
  float* attTp = (float*)(zb + 262144);    // 27648 f32
  float* w1s   = attTp + 27648;            // 288
  float* w2s   = w1s + 288;                // 288
  float* ebb   = w2s + 288;                // 1152
  short* wob   = (short*)(ebb + 1152);     // 153600
  short* w1p   = wob + 153600;             // 409600
  short* w2p   = w1p + 409600;             // 409600
  short* y1t   = w2p + 409600;             // 7372800
  // ---- pool X, lifetime-disjoint phases ----
  short* poolX = y1t + 7372800;
  short* bertb = poolX;                    // 786432 (hi+lo)
  short* w1b   = bertb + 786432;           // 442368
  short* ebt   = w1b + 442368;             // 294912
  short* Eb    = ebt + 294912;             // 393216
  short* pb    = Eb + 393216;              // 884736
  float* ebf   = (float*)(pb + 884736);    // 147456 f32
  float* E     = ebf + 147456;             // 147456
  float* t2    = E + 147456;               // 147456
  short* AWq   = poolX;                    // phase 2
  float* y2    = (float*)poolX;            // phase 2b

  dim3 blk(256);

  hipMemsetAsync(Gt, 0, (size_t)5328896, stream);
  hipMemsetAsync(Eb, 0, (size_t)(393216 + 884736) * 2, stream);

  cast_pad_split<<<dim3(1536), blk, 0, stream>>>(bert, bertb, 393216L, 512, 768, 768);
  cast_pad_split<<<dim3(864), blk, 0, stream>>>(W1, w1b, 221184L, 288, 768, 768);
  cast_pad_split<<<dim3(300), blk, 0, stream>>>(Wo, wob, 76800L, 300, 144, 256);
  wperm_kernel<<<dim3(1600), blk, 0, stream>>>(c1w, w1p);
  wperm_kernel<<<dim3(1600), blk, 0, stream>>>(c2w, w2p);
  wsum_kernel<<<dim3(5), dim3(64), 0, stream>>>(w1m, w2m, w1s, w2s);

  // eb = bert @ W1^T + b1  [512x288] K=768; emits f32 ebf + split ebt
  gemm_split<1><<<dim3(5, 8, 1), blk, 0, stream>>>(
      bertb, w1b, b1l, ebf, ebt, 512, 288, 12,
      0L, 768, 393216L, 0L, 768, 221184L, 0L, 288, 0L, 0, 147456L);

  ebbar_kernel<<<dim3(4), dim3(256), 0, stream>>>(ebf, ebb);

  score_kernel<<<dim3(S_, B_), blk, 0, stream>>>(mem, sent, ebb, cw, ml, E, Eb, attTp);

  // P_b = eb_b^T @ eb_b  [288x288] K=128 -> split pb
  gemm_split<2><<<dim3(5, 5, 4), blk, 0, stream>>>(
      ebt, ebt, (const float*)nullptr, (float*)nullptr, pb, 288, 288, 2,
      (long)288 * 128, 128, 147456L, (long)288 * 128, 128, 147456L,
      0L, 0, (long)288 * 384, 384, 442368L);

  // t2 = E @ P  [128x288] K=384(pad)
  gemm_split<0><<<dim3(5, 2, 4), blk, 0, stream>>>(
      Eb, pb, (const float*)nullptr, t2, (short*)nullptr, 128, 288, 6,
      (long)128 * 384, 384, 196608L, (long)288 * 384, 384, 442368L,
      (long)128 * 288, 288, 0L, 0, 0L);

  // balanced g_kernel: 576 threads, (n, m-half) per thread
  g_kernel<<<dim3(S_, B_), dim3(576), 0, stream>>>(E, t2, w1s, w2s, Gt);

  conv1_aw<<<dim3(2, 50, 4), blk, 0, stream>>>(w1p, attTp, AWq);
  conv1_mfma<<<dim3(2, 50, 4), blk, 0, stream>>>(AWq, Gt, c1b, y1t);

  pool_t<<<dim3((B_ * HP_ * WP_ * 16 + 255) / 256), blk, 0, stream>>>(y1t, x2t);

  conv2_tap<<<dim3(3, 25, 4), blk, 0, stream>>>(w2p, x2t, c2b, y2);

  ln_kernel<<<dim3(B_ * S_ * HP_), dim3(64), 0, stream>>>(y2, lng, lnb);

  meanhp_kernel<<<dim3((B_ * S_ * WP_ + 255) / 256), blk, 0, stream>>>(y2, zb);

  // out = z @ W_out^T + b_out  [512x300] K=256(pad)
  gemm_split<0><<<dim3(5, 8, 1), blk, 0, stream>>>(
      zb, wob, bo, out, (short*)nullptr, 512, 300, 4,
      0L, 256, 131072L, 0L, 256, 76800L, 0L, 300, 0L, 0, 0L);

  maskout_kernel<<<dim3((B_ * S_ * NOUT_ + 255) / 256), blk, 0, stream>>>(out, ml, ign);
}

// Round 11
// 243.776 us; speedup vs baseline: 5.2118x; 1.0537x over previous
//
#include <hip/hip_runtime.h>

#define B_    4
#define S_    128
#define BERT_ 768
#define C_    49
#define C1_   50
#define M_    288
#define HP_   25
#define WP_   144
#define NOUT_ 300

typedef short bf16x8 __attribute__((ext_vector_type(8)));
typedef short short4v __attribute__((ext_vector_type(4)));
typedef float f32x4 __attribute__((ext_vector_type(4)));

static __device__ __forceinline__ short f2bf(float f) {
  unsigned u = __float_as_uint(f);
  unsigned r = (u + 0x7fffu + ((u >> 16) & 1u)) >> 16;
  return (short)r;
}
static __device__ __forceinline__ float bf2f(short v) {
  return __uint_as_float(((unsigned)(unsigned short)v) << 16);
}
static __device__ __forceinline__ unsigned cvt_pk_bf16(float lo, float hi) {
  unsigned r;
  asm("v_cvt_pk_bf16_f32 %0, %1, %2" : "=v"(r) : "v"(lo), "v"(hi));
  return r;
}

// ------------------------------------------------------------------
// fused prep: casts (bert, W1, Wo), wperm (c1w, c2w), wsum — 1 launch
// ------------------------------------------------------------------
static __device__ __forceinline__ void cast_body(const float* src, short* dst,
                                                 long loOff, int R, int Ks, int Kd, int idx)
{
  if (idx >= R * Kd) return;
  int k = idx % Kd, r = idx / Kd;
  short h = 0, l = 0;
  if (k < Ks) {
    float v = src[(long)r * Ks + k];
    h = f2bf(v);
    l = f2bf(v - bf2f(h));
  }
  dst[idx] = h;
  dst[idx + loOff] = l;
}
static __device__ __forceinline__ void wperm_body(const float* w, short* wq, int idx)
{
  if (idx >= 25 * 128 * 128) return;
  int e = idx & 7; int t = idx >> 3;
  int o = t & 127; t >>= 7;
  int chq = t & 15; int tap = t >> 4;
  int ch = chq * 8 + e;
  wq[idx] = f2bf(w[((long)(o * 128 + ch)) * 25 + tap]);
}
__global__ __launch_bounds__(256) void prep_kernel(
    const float* __restrict__ bert, short* __restrict__ bertb,
    const float* __restrict__ W1, short* __restrict__ w1b,
    const float* __restrict__ Wo, short* __restrict__ wob,
    const float* __restrict__ c1w, short* __restrict__ w1p,
    const float* __restrict__ c2w, short* __restrict__ w2p,
    const float* __restrict__ w1m, const float* __restrict__ w2m,
    float* __restrict__ w1s, float* __restrict__ w2s)
{
  const int g = blockIdx.x, tid = threadIdx.x;
  if (g < 1536)       cast_body(bert, bertb, 393216L, 512, 768, 768, g * 256 + tid);
  else if (g < 2400)  cast_body(W1, w1b, 221184L, 288, 768, 768, (g - 1536) * 256 + tid);
  else if (g < 2700)  cast_body(Wo, wob, 76800L, 300, 144, 256, (g - 2400) * 256 + tid);
  else if (g < 4300)  wperm_body(c1w, w1p, (g - 2700) * 256 + tid);
  else if (g < 5900)  wperm_body(c2w, w2p, (g - 4300) * 256 + tid);
  else {
    int m = (g - 5900) * 256 + tid;
    if (m < M_) {
      float a = 0.f, b = 0.f;
      for (int c = 0; c < C1_; ++c) { a += w1m[m * C1_ + c]; b += w2m[m * C1_ + c]; }
      w1s[m] = a; w2s[m] = b;
    }
  }
}

// ------------------------------------------------------------------
// split-bf16 MFMA GEMM. Out[i,j] = sum_k A[i,k]*B[j,k] (+bias)
// ------------------------------------------------------------------
template<int OMODE>
__global__ __launch_bounds__(256) void gemm_split(
    const short* __restrict__ A, const short* __restrict__ Bm,
    const float* __restrict__ bias,
    float* __restrict__ Outf, short* __restrict__ Outb,
    int Mr, int Nc, int KH,
    long aB, int aP, long aLo,
    long bB, int bP, long bLo,
    long oB, int oP,
    long obB, int obP, long obLo)
{
  const int z = blockIdx.z;
  const int i0 = blockIdx.y * 64, j0 = blockIdx.x * 64;
  __shared__ __attribute__((aligned(16))) short As[2][64 * 64];
  __shared__ __attribute__((aligned(16))) short Bs[2][64 * 64];
  const int tid = threadIdx.x;
  const int wave = tid >> 6, lane = tid & 63;
  const int lr = lane & 15, kq = lane >> 4;
  f32x4 acc[4] = {};
  const short* Ab = A + z * aB;
  const short* Bb = Bm + z * bB;
  const bf16x8 vz = {0, 0, 0, 0, 0, 0, 0, 0};
  for (int kh = 0; kh < KH; ++kh) {
    if (kh) __syncthreads();
    for (int u = tid; u < 512; u += 256) {
      int row = u >> 3, c = u & 7;
      int gi = i0 + row;
      const short* src = &Ab[(long)gi * aP + kh * 64 + c * 8];
      bf16x8 vh = (gi < Mr) ? *(const bf16x8*)src : vz;
      bf16x8 vl = (gi < Mr) ? *(const bf16x8*)(src + aLo) : vz;
      int dst = row * 64 + ((c ^ (row & 7)) * 8);
      *(bf16x8*)&As[0][dst] = vh;
      *(bf16x8*)&As[1][dst] = vl;
    }
    for (int u = tid; u < 512; u += 256) {
      int row = u >> 3, c = u & 7;
      int gj = j0 + row;
      const short* src = &Bb[(long)gj * bP + kh * 64 + c * 8];
      bf16x8 vh = (gj < Nc) ? *(const bf16x8*)src : vz;
      bf16x8 vl = (gj < Nc) ? *(const bf16x8*)(src + bLo) : vz;
      int dst = row * 64 + ((c ^ (row & 7)) * 8);
      *(bf16x8*)&Bs[0][dst] = vh;
      *(bf16x8*)&Bs[1][dst] = vl;
    }
    __syncthreads();
#pragma unroll
    for (int ks = 0; ks < 2; ++ks) {
      const int ch = ks * 4 + kq;
      const int ar = wave * 16 + lr;
      const int ao = ar * 64 + ((ch ^ (ar & 7)) * 8);
      bf16x8 ah = *(const bf16x8*)&As[0][ao];
      bf16x8 al = *(const bf16x8*)&As[1][ao];
#pragma unroll
      for (int ni = 0; ni < 4; ++ni) {
        const int br = ni * 16 + lr;
        const int bo2 = br * 64 + ((ch ^ (br & 7)) * 8);
        bf16x8 bh = *(const bf16x8*)&Bs[0][bo2];
        bf16x8 bl = *(const bf16x8*)&Bs[1][bo2];
        acc[ni] = __builtin_amdgcn_mfma_f32_16x16x32_bf16(ah, bh, acc[ni], 0, 0, 0);
        acc[ni] = __builtin_amdgcn_mfma_f32_16x16x32_bf16(ah, bl, acc[ni], 0, 0, 0);
        acc[ni] = __builtin_amdgcn_mfma_f32_16x16x32_bf16(al, bh, acc[ni], 0, 0, 0);
      }
    }
  }
#pragma unroll
  for (int ni = 0; ni < 4; ++ni) {
    int jg = j0 + ni * 16 + lr;
    if (jg >= Nc) continue;
#pragma unroll
    for (int r = 0; r < 4; ++r) {
      int ig = i0 + wave * 16 + kq * 4 + r;
      if (ig >= Mr) continue;
      float v = acc[ni][r];
      if (bias) v += bias[jg];
      if constexpr (OMODE == 0 || OMODE == 1)
        Outf[z * oB + (long)ig * oP + jg] = v;
      if constexpr (OMODE == 1) {
        long o = ((long)((ig >> 7) * 288 + jg)) * 128 + (ig & 127);
        short h = f2bf(v);
        Outb[o] = h;
        Outb[o + obLo] = f2bf(v - bf2f(h));
      }
      if constexpr (OMODE == 2) {
        long o = z * obB + (long)ig * obP + jg;
        short h = f2bf(v);
        Outb[o] = h;
        Outb[o + obLo] = f2bf(v - bf2f(h));
      }
    }
  }
}

// ------------------------------------------------------------------
__global__ void ebbar_kernel(const float* __restrict__ eb, float* __restrict__ ebb)
{
  int b = blockIdx.x;
  for (int m = threadIdx.x; m < M_; m += blockDim.x) {
    float s = 0.f;
    for (int t = 0; t < S_; ++t) s += eb[((long)(b * S_ + t)) * M_ + m];
    ebb[b * M_ + m] = s * (1.f / (float)S_);
  }
}

// ------------------------------------------------------------------
// fused per-(b,s): E (f32 + split bf16 padded), scores, softmaxes, top-5, att
// ------------------------------------------------------------------
__global__ __launch_bounds__(256) void score_kernel(
    const float* __restrict__ mem, const float* __restrict__ sentinel,
    const float* __restrict__ ebbar, const float* __restrict__ cw,
    const int* __restrict__ ml, float* __restrict__ E, short* __restrict__ Eb,
    float* __restrict__ attTp)
{
  const int s = blockIdx.x, b = blockIdx.y;
  const int tid = threadIdx.x, wave = tid >> 6, lane = tid & 63;
  __shared__ float sEb[M_];
  __shared__ float sE[4][M_];
  __shared__ float sScore[C1_];
  for (int m = tid; m < M_; m += 256) sEb[m] = ebbar[b * M_ + m];
  __syncthreads();

  const float* base = mem + ((long)(b * S_ + s)) * C_ * M_;
  float Ereg[5] = {0.f, 0.f, 0.f, 0.f, 0.f};
  for (int jj = wave; jj < C_; jj += 4) {
    const float* row = base + (long)jj * M_;
    float d = 0.f;
#pragma unroll
    for (int q = 0; q < 5; ++q) {
      int m = lane + q * 64;
      if (m < M_) { float v = row[m]; Ereg[q] += v; d = fmaf(v, sEb[m], d); }
    }
#pragma unroll
    for (int off = 32; off; off >>= 1) d += __shfl_down(d, off, 64);
    if (lane == 0) sScore[jj + 1] = d;
  }
#pragma unroll
  for (int q = 0; q < 5; ++q) { int m = lane + q * 64; if (m < M_) sE[wave][m] = Ereg[q]; }
  __syncthreads();

  if (wave == 0) {
    float d0 = 0.f;
    for (int m = lane; m < M_; m += 64) d0 = fmaf(sentinel[m], sEb[m], d0);
#pragma unroll
    for (int off = 32; off; off >>= 1) d0 += __shfl_down(d0, off, 64);
    if (lane == 0) sScore[0] = d0;
  }
  for (int m = tid; m < M_; m += 256) {
    float ev = sentinel[m] + sE[0][m] + sE[1][m] + sE[2][m] + sE[3][m];
    E[((long)(b * S_ + s)) * M_ + m] = ev;
    short h = f2bf(ev);
    Eb[((long)(b * S_ + s)) * 384 + m] = h;
    Eb[196608 + ((long)(b * S_ + s)) * 384 + m] = f2bf(ev - bf2f(h));
  }
  __syncthreads();

  if (wave == 0) {
    const int mlv = ml[b * S_ + s];
    float sc = (lane < C1_) ? sScore[lane] : 0.f;
    if (lane < C1_ && mlv < lane) sc -= 1e6f;
    float mx = (lane < C1_) ? sc : -3.0e38f;
#pragma unroll
    for (int off = 32; off; off >>= 1) mx = fmaxf(mx, __shfl_xor(mx, off, 64));
    float e1 = (lane < C1_) ? __expf(sc - mx) : 0.f;
    float s1 = e1;
#pragma unroll
    for (int off = 32; off; off >>= 1) s1 += __shfl_xor(s1, off, 64);
    float p1 = e1 / s1;
    float cv = 0.f;
    if (lane >= 1 && lane < C1_) cv = cw[((long)(b * S_ + s)) * C_ + lane - 1];
    float mx2 = (lane < C1_) ? cv : -3.0e38f;
#pragma unroll
    for (int off = 32; off; off >>= 1) mx2 = fmaxf(mx2, __shfl_xor(mx2, off, 64));
    float e2 = (lane < C1_) ? __expf(cv - mx2) : 0.f;
    float s2 = e2;
#pragma unroll
    for (int off = 32; off; off >>= 1) s2 += __shfl_xor(s2, off, 64);
    float p2 = e2 / s2;
    float scm = 0.7f * p1 + 0.3f * p2;
    bool active = (lane < C1_);
    float thr = 0.f;
    for (int r = 0; r < 5; ++r) {
      float v = active ? scm : -3.0e38f;
      int idx = lane;
#pragma unroll
      for (int off = 32; off; off >>= 1) {
        float ov = __shfl_xor(v, off, 64);
        int oi = __shfl_xor(idx, off, 64);
        if (ov > v || (ov == v && oi < idx)) { v = ov; idx = oi; }
      }
      thr = v;
      if (lane == idx) active = false;
    }
    float kept = (lane < C1_ && scm >= thr) ? scm : 0.f;
    float mx3 = (lane < C1_) ? kept : -3.0e38f;
#pragma unroll
    for (int off = 32; off; off >>= 1) mx3 = fmaxf(mx3, __shfl_xor(mx3, off, 64));
    float e3 = (lane < C1_) ? __expf(kept - mx3) : 0.f;
    float s3 = e3;
#pragma unroll
    for (int off = 32; off; off >>= 1) s3 += __shfl_xor(s3, off, 64);
    if (lane < C1_) attTp[((long)(b * 54) + lane + 2) * 128 + s] = e3 / s3;
  }
}

// ------------------------------------------------------------------
// G[b,s,n] -> bf16 transposed into Gt[b][n+2][s]  (balanced 576-thread)
// ------------------------------------------------------------------
__global__ __launch_bounds__(576) void g_kernel(
    const float* __restrict__ E, const float* __restrict__ t2,
    const float* __restrict__ w1s, const float* __restrict__ w2s,
    short* __restrict__ Gt)
{
  const int s = blockIdx.x, b = blockIdx.y;
  __shared__ float sE[M_], s1[M_], s2[M_];
  const int tid = threadIdx.x;
  const long base = (long)(b * S_ + s) * M_;
  for (int m = tid; m < M_; m += 576) { sE[m] = E[base + m]; s1[m] = w1s[m]; s2[m] = w2s[m]; }
  __syncthreads();
  const int n = tid >> 1, half = tid & 1;
  const float a = sE[n];
  const float c = t2[base + n];
  float num = 0.f, den = 0.f;
  const int m0 = half * 144;
#pragma unroll 4
  for (int mm = 0; mm < 144; ++mm) {
    int m = m0 + mm;
    float z = fmaf(s1[m], a, s2[m] * c);
    float u = __expf(2.f * z);
    float th = 1.f - 2.f / (u + 1.f);
    float e = __expf(th);
    num = fmaf(sE[m], e, num);
    den += e;
  }
  num += __shfl_xor(num, 1, 64);
  den += __shfl_xor(den, 1, 64);
  if (half == 0)
    Gt[((long)(b * 292) + 2 + n) * 128 + s] = f2bf(num / den);
}

// ------------------------------------------------------------------
// conv1 stage A: AWq = dh-contraction of w1 with att (per b,h)
// ------------------------------------------------------------------
__global__ __launch_bounds__(256) void conv1_aw(
    const short* __restrict__ w1q, const float* __restrict__ attp,
    short* __restrict__ AWq)
{
  const int b = blockIdx.z, h = blockIdx.y, half = blockIdx.x;
  __shared__ float sAtt[5][128];
  const int tid = threadIdx.x;
  for (int u = tid; u < 640; u += 256)
    sAtt[u >> 7][u & 127] = attp[((long)(b * 54) + h + (u >> 7)) * 128 + (u & 127)];
  __syncthreads();
  const long obase = ((long)(b * 50 + h) * 80) * 1024;
  for (int u = tid; u < 5120; u += 256) {
    int c = half * 40 + (u >> 7);
    int o = u & 127;
    int dw = c / 16, chq = c & 15;
    float acc[8] = {};
#pragma unroll
    for (int dh = 0; dh < 5; ++dh) {
      bf16x8 wv = *(const bf16x8*)&w1q[(((long)((dh * 5 + dw) * 16 + chq)) * 128 + o) * 8];
      const float* ar = &sAtt[dh][chq * 8];
#pragma unroll
      for (int e = 0; e < 8; ++e) acc[e] = fmaf(bf2f(wv[e]), ar[e], acc[e]);
    }
    union { unsigned u4[4]; bf16x8 v; } pk;
    pk.u4[0] = cvt_pk_bf16(acc[0], acc[1]);
    pk.u4[1] = cvt_pk_bf16(acc[2], acc[3]);
    pk.u4[2] = cvt_pk_bf16(acc[4], acc[5]);
    pk.u4[3] = cvt_pk_bf16(acc[6], acc[7]);
    *(bf16x8*)&AWq[obase + (long)c * 1024 + o * 8] = pk.v;
  }
}

// ------------------------------------------------------------------
// conv1 stage B: per (b,h) GEMM over K=640 (dw,i). BM=128, BN=144.
// ------------------------------------------------------------------
__global__ __launch_bounds__(256) void conv1_mfma(
    const short* __restrict__ AWq, const short* __restrict__ Gt,
    const float* __restrict__ bias, short* __restrict__ y1t)
{
  const int b = blockIdx.z, hrow = blockIdx.y;
  const int w0 = blockIdx.x * 144;
  __shared__ __attribute__((aligned(16))) short Bs[2][148 * 64];
  const int tid = threadIdx.x;
  const int wave = tid >> 6, lane = tid & 63;
  const int lr = lane & 15, kq = lane >> 4;
  f32x4 acc[2][9] = {};

  const short* src = Gt + ((long)(b * 292) + w0) * 128;
  for (int u = tid; u < 2368; u += 256) {
    int row = u >> 4, c = u & 15;
    bf16x8 v = *(const bf16x8*)&src[row * 128 + c * 8];
    *(bf16x8*)&Bs[c >> 3][row * 64 + (((c & 7) ^ (row & 7)) * 8)] = v;
  }
  __syncthreads();

  const long awb = (long)(b * 50 + hrow) * 80;
  for (int dw = 0; dw < 5; ++dw) {
#pragma unroll
    for (int ks = 0; ks < 4; ++ks) {
      const int ch = ks * 4 + kq;
      const long abase = (awb + dw * 16 + ch) * 128 + wave * 32 + lr;
      bf16x8 af0 = *(const bf16x8*)&AWq[abase * 8];
      bf16x8 af1 = *(const bf16x8*)&AWq[(abase + 16) * 8];
      const int arr = ch >> 3, cc = ch & 7;
#pragma unroll
      for (int ni = 0; ni < 9; ++ni) {
        const int row = lr + ni * 16 + dw;
        bf16x8 bfr = *(const bf16x8*)&Bs[arr][row * 64 + ((cc ^ (row & 7)) * 8)];
        acc[0][ni] = __builtin_amdgcn_mfma_f32_16x16x32_bf16(af0, bfr, acc[0][ni], 0, 0, 0);
        acc[1][ni] = __builtin_amdgcn_mfma_f32_16x16x32_bf16(af1, bfr, acc[1][ni], 0, 0, 0);
      }
    }
  }
#pragma unroll
  for (int mi = 0; mi < 2; ++mi) {
    const int og = wave * 32 + mi * 16 + kq * 4;
#pragma unroll
    for (int ni = 0; ni < 9; ++ni) {
      int wg = w0 + ni * 16 + lr;
      short4v pk;
#pragma unroll
      for (int r = 0; r < 4; ++r)
        pk[r] = f2bf(fmaxf(acc[mi][ni][r] + bias[og + r], 0.f));
      *(short4v*)&y1t[(((long)(b * 50) + hrow) * 288 + wg) * 128 + og] = pk;
    }
  }
}

// ------------------------------------------------------------------
// conv2 tap-GEMM v2: BM=128, BN=48, double-buffered async B staging.
// dh+1's B-tile loads issue BEFORE dh's MFMAs; LDS write after.
// ------------------------------------------------------------------
__global__ __launch_bounds__(256) void conv2_tap(
    const short* __restrict__ wq,
    const short* __restrict__ act,
    const float* __restrict__ bias,
    float* __restrict__ y2)
{
  constexpr int NREP = 3;
  constexpr int ROWS = 52;
  const int b = blockIdx.z;
  const int hrow = blockIdx.y;
  const int w0 = blockIdx.x * 48;
  __shared__ __attribute__((aligned(16))) short Bs[2][2][ROWS * 64];
  const int tid = threadIdx.x;
  const int wave = tid >> 6, lane = tid & 63;
  const int lr = lane & 15, kq = lane >> 4;
  f32x4 acc[2][NREP] = {};

  // stage dh=0 directly
  {
    const short* src = act + (((long)(b * 29) + hrow) * 148 + w0) * 128;
    for (int u = tid; u < ROWS * 16; u += 256) {
      int row = u >> 4, c = u & 15;
      bf16x8 v = *(const bf16x8*)&src[row * 128 + c * 8];
      *(bf16x8*)&Bs[0][c >> 3][row * 64 + (((c & 7) ^ (row & 7)) * 8)] = v;
    }
  }
  __syncthreads();

  for (int dh = 0; dh < 5; ++dh) {
    const int cur = dh & 1;
    // ---- issue dh+1 B loads into regs (latency hides under MFMAs)
    bf16x8 r0, r1, r2, r3;
    if (dh < 4) {
      const short* src = act + (((long)(b * 29) + hrow + dh + 1) * 148 + w0) * 128;
      { int u = tid;        r0 = *(const bf16x8*)&src[(u >> 4) * 128 + (u & 15) * 8]; }
      { int u = tid + 256;  r1 = *(const bf16x8*)&src[(u >> 4) * 128 + (u & 15) * 8]; }
      { int u = tid + 512;  r2 = *(const bf16x8*)&src[(u >> 4) * 128 + (u & 15) * 8]; }
      if (tid < 64) { int u = tid + 768; r3 = *(const bf16x8*)&src[(u >> 4) * 128 + (u & 15) * 8]; }
    }
    // ---- MFMA phase on Bs[cur] (dw fully unrolled -> A loads hoist)
#pragma unroll
    for (int dw = 0; dw < 5; ++dw) {
      const int tap = dh * 5 + dw;
#pragma unroll
      for (int ks = 0; ks < 4; ++ks) {
        const int ch = ks * 4 + kq;
        const long abase = ((long)(tap * 16 + ch)) * 128 + wave * 32 + lr;
        bf16x8 af0 = *(const bf16x8*)&wq[abase * 8];
        bf16x8 af1 = *(const bf16x8*)&wq[(abase + 16) * 8];
        const int arr = ch >> 3, cc = ch & 7;
#pragma unroll
        for (int ni = 0; ni < NREP; ++ni) {
          const int row = lr + ni * 16 + dw;
          bf16x8 bfr = *(const bf16x8*)&Bs[cur][arr][row * 64 + ((cc ^ (row & 7)) * 8)];
          acc[0][ni] = __builtin_amdgcn_mfma_f32_16x16x32_bf16(af0, bfr, acc[0][ni], 0, 0, 0);
          acc[1][ni] = __builtin_amdgcn_mfma_f32_16x16x32_bf16(af1, bfr, acc[1][ni], 0, 0, 0);
        }
      }
    }
    // ---- write prefetched tile to Bs[cur^1], barrier
    if (dh < 4) {
      { int u = tid;       int row = u >> 4, c = u & 15;
        *(bf16x8*)&Bs[cur ^ 1][c >> 3][row * 64 + (((c & 7) ^ (row & 7)) * 8)] = r0; }
      { int u = tid + 256; int row = u >> 4, c = u & 15;
        *(bf16x8*)&Bs[cur ^ 1][c >> 3][row * 64 + (((c & 7) ^ (row & 7)) * 8)] = r1; }
      { int u = tid + 512; int row = u >> 4, c = u & 15;
        *(bf16x8*)&Bs[cur ^ 1][c >> 3][row * 64 + (((c & 7) ^ (row & 7)) * 8)] = r2; }
      if (tid < 64) { int u = tid + 768; int row = u >> 4, c = u & 15;
        *(bf16x8*)&Bs[cur ^ 1][c >> 3][row * 64 + (((c & 7) ^ (row & 7)) * 8)] = r3; }
      __syncthreads();
    }
  }
#pragma unroll
  for (int mi = 0; mi < 2; ++mi) {
    const int og = wave * 32 + mi * 16 + kq * 4;
#pragma unroll
    for (int ni = 0; ni < NREP; ++ni) {
      int wg = w0 + ni * 16 + lr;
#pragma unroll
      for (int r = 0; r < 4; ++r)
        y2[((long)(b * 128) + og + r) * 3600 + hrow * 144 + wg] =
            fmaxf(acc[mi][ni][r] + bias[og + r], 0.f);
    }
  }
}

// ------------------------------------------------------------------
__global__ void pool_t(const short* __restrict__ y1t, short* __restrict__ x2t)
{
  int idx = blockIdx.x * 256 + threadIdx.x;
  if (idx >= B_ * HP_ * WP_ * 16) return;
  int c8 = idx & 15; int t = idx >> 4;
  int wp = t % WP_; t /= WP_;
  int hp = t % HP_; int b = t / HP_;
  const short* base = y1t + (((long)(b * 50 + 2 * hp) * 288) + 2 * wp) * 128 + c8 * 8;
  bf16x8 v00 = *(const bf16x8*)&base[0];
  bf16x8 v01 = *(const bf16x8*)&base[128];
  bf16x8 v10 = *(const bf16x8*)&base[288 * 128];
  bf16x8 v11 = *(const bf16x8*)&base[288 * 128 + 128];
  bf16x8 r;
#pragma unroll
  for (int e = 0; e < 8; ++e)
    r[e] = f2bf(fmaxf(fmaxf(bf2f(v00[e]), bf2f(v01[e])), fmaxf(bf2f(v10[e]), bf2f(v11[e]))));
  *(bf16x8*)&x2t[(((long)(b * 29) + hp + 2) * 148 + wp + 2) * 128 + c8 * 8] = r;
}

// ------------------------------------------------------------------
__global__ __launch_bounds__(64) void ln_kernel(float* __restrict__ y2,
                                                const float* __restrict__ g,
                                                const float* __restrict__ bb)
{
  float* p = y2 + (long)blockIdx.x * WP_;
  const int lane = threadIdx.x;
  float v[3]; float s = 0.f, ss = 0.f;
#pragma unroll
  for (int q = 0; q < 3; ++q) {
    int wp = lane + q * 64;
    float x = (wp < WP_) ? p[wp] : 0.f;
    v[q] = x; s += x; ss = fmaf(x, x, ss);
  }
#pragma unroll
  for (int off = 32; off; off >>= 1) { s += __shfl_xor(s, off, 64); ss += __shfl_xor(ss, off, 64); }
  float mu = s * (1.f / (float)WP_);
  float var = ss * (1.f / (float)WP_) - mu * mu;
  float inv = rsqrtf(var + 1e-5f);
#pragma unroll
  for (int q = 0; q < 3; ++q) {
    int wp = lane + q * 64;
    if (wp < WP_) p[wp] = (v[q] - mu) * inv * g[wp] + bb[wp];
  }
}

// mean over hp -> split bf16 zb[512][256] (pad zeroed by memset)
__global__ void meanhp_kernel(const float* __restrict__ y2, short* __restrict__ zb)
{
  int idx = blockIdx.x * 256 + threadIdx.x;
  if (idx >= B_ * S_ * WP_) return;
  int wp = idx % WP_; int t = idx / WP_;
  const float* p = y2 + (long)t * HP_ * WP_ + wp;
  float s = 0.f;
  for (int hp = 0; hp < HP_; ++hp) s += p[hp * WP_];
  float v = s * (1.f / (float)HP_);
  short h = f2bf(v);
  zb[(long)t * 256 + wp] = h;
  zb[131072 + (long)t * 256 + wp] = f2bf(v - bf2f(h));
}

__global__ void maskout_kernel(float* __restrict__ out, const int* __restrict__ ml,
                               const int* __restrict__ ign)
{
  int idx = blockIdx.x * 256 + threadIdx.x;
  if (idx >= B_ * S_ * NOUT_) return;
  if (ign[0] == 0) return;
  if (ml[idx / NOUT_] <= 0) out[idx] = 0.f;
}

// ------------------------------------------------------------------
extern "C" void kernel_launch(void* const* d_in, const int* in_sizes, int n_in,
                              void* d_out, int out_size, void* d_ws, size_t ws_size,
                              hipStream_t stream)
{
  const float* bert = (const float*)d_in[0];
  const float* mem  = (const float*)d_in[1];
  const int*   ml   = (const int*)d_in[2];
  const float* cw   = (const float*)d_in[3];
  const int*   ign  = (const int*)d_in[4];
  const float* W1   = (const float*)d_in[6];
  const float* b1l  = (const float*)d_in[7];
  const float* sent = (const float*)d_in[8];
  const float* w1m  = (const float*)d_in[9];
  const float* w2m  = (const float*)d_in[10];
  const float* c1w  = (const float*)d_in[11];
  const float* c1b  = (const float*)d_in[12];
  const float* c2w  = (const float*)d_in[13];
  const float* c2b  = (const float*)d_in[14];
  const float* lng  = (const float*)d_in[15];
  const float* lnb  = (const float*)d_in[16];
  const float* Wo   = (const float*)d_in[17];
  const float* bo   = (const float*)d_in[18];
  float* out = (float*)d_out;

  // ---- A-region (persistent) ----
  short* Gt    = (short*)d_ws;             // 149504
  short* x2t   = Gt + 149504;              // 2197504
  short* zb    = x2t + 2197504;            // 262144
  float* attTp = (float*)(zb + 262144);    // 27648 f32
  float* w1s   = attTp + 27648;            // 288
  float* w2s   = w1s + 288;                // 288
  float* ebb   = w2s + 288;                // 1152
  short* wob   = (short*)(ebb + 1152);     // 153600
  short* w1p   = wob + 153600;             // 409600
  short* w2p   = w1p + 409600;             // 409600
  short* y1t   = w2p + 409600;             // 7372800
  // ---- pool X, lifetime-disjoint phases ----
  short* poolX = y1t + 7372800;
  short* bertb = poolX;                    // 786432 (hi+lo)
  short* w1b   = bertb + 786432;           // 442368
  short* ebt   = w1b + 442368;             // 294912
  short* Eb    = ebt + 294912;             // 393216
  short* pb    = Eb + 393216;              // 884736
  float* ebf   = (float*)(pb + 884736);    // 147456 f32
  float* E     = ebf + 147456;             // 147456
  float* t2    = E + 147456;               // 147456
  short* AWq   = poolX;                    // phase 2
  float* y2    = (float*)poolX;            // phase 2b

  dim3 blk(256);

  hipMemsetAsync(Gt, 0, (size_t)5328896, stream);
  hipMemsetAsync(Eb, 0, (size_t)(393216 + 884736) * 2, stream);

  // fused prep: casts + wperms + wsum in one launch
  prep_kernel<<<dim3(5902), blk, 0, stream>>>(
      bert, bertb, W1, w1b, Wo, wob, c1w, w1p, c2w, w2p, w1m, w2m, w1s, w2s);

  // eb = bert @ W1^T + b1  [512x288] K=768; emits f32 ebf + split ebt
  gemm_split<1><<<dim3(5, 8, 1), blk, 0, stream>>>(
      bertb, w1b, b1l, ebf, ebt, 512, 288, 12,
      0L, 768, 393216L, 0L, 768, 221184L, 0L, 288, 0L, 0, 147456L);

  ebbar_kernel<<<dim3(4), dim3(256), 0, stream>>>(ebf, ebb);

  score_kernel<<<dim3(S_, B_), blk, 0, stream>>>(mem, sent, ebb, cw, ml, E, Eb, attTp);

  // P_b = eb_b^T @ eb_b  [288x288] K=128 -> split pb
  gemm_split<2><<<dim3(5, 5, 4), blk, 0, stream>>>(
      ebt, ebt, (const float*)nullptr, (float*)nullptr, pb, 288, 288, 2,
      (long)288 * 128, 128, 147456L, (long)288 * 128, 128, 147456L,
      0L, 0, (long)288 * 384, 384, 442368L);

  // t2 = E @ P  [128x288] K=384(pad)
  gemm_split<0><<<dim3(5, 2, 4), blk, 0, stream>>>(
      Eb, pb, (const float*)nullptr, t2, (short*)nullptr, 128, 288, 6,
      (long)128 * 384, 384, 196608L, (long)288 * 384, 384, 442368L,
      (long)128 * 288, 288, 0L, 0, 0L);

  // balanced g_kernel: 576 threads, (n, m-half) per thread
  g_kernel<<<dim3(S_, B_), dim3(576), 0, stream>>>(E, t2, w1s, w2s, Gt);

  conv1_aw<<<dim3(2, 50, 4), blk, 0, stream>>>(w1p, attTp, AWq);
  conv1_mfma<<<dim3(2, 50, 4), blk, 0, stream>>>(AWq, Gt, c1b, y1t);

  pool_t<<<dim3((B_ * HP_ * WP_ * 16 + 255) / 256), blk, 0, stream>>>(y1t, x2t);

  conv2_tap<<<dim3(3, 25, 4), blk, 0, stream>>>(w2p, x2t, c2b, y2);

  ln_kernel<<<dim3(B_ * S_ * HP_), dim3(64), 0, stream>>>(y2, lng, lnb);

  meanhp_kernel<<<dim3((B_ * S_ * WP_ + 255) / 256), blk, 0, stream>>>(y2, zb);

  // out = z @ W_out^T + b_out  [512x300] K=256(pad)
  gemm_split<0><<<dim3(5, 8, 1), blk, 0, stream>>>(
      zb, wob, bo, out, (short*)nullptr, 512, 300, 4,
      0L, 256, 131072L, 0L, 256, 76800L, 0L, 300, 0L, 0, 0L);

  maskout_kernel<<<dim3((B_ * S_ * NOUT_ + 255) / 256), blk, 0, stream>>>(out, ml, ign);
}